// Round 5
// baseline (778.367 us; speedup 1.0000x reference)
//
#include <hip/hip_runtime.h>
#include <math.h>

#define G 8
#define N0 16384
#define NEDGE (G*N0*8)      // 1048576
#define C 128
#define EPS_FA 0.1f
#define SMAX 2048

// ---------------- zero pooled ----------------
__global__ void k_zero_pooled(float* __restrict__ pooled) {
    int i = blockIdx.x * 256 + threadIdx.x;
    if (i < G * 384) pooled[i] = 0.0f;
}

// ---------------- layer-0 deg/score via LDS histogram ----------------
// 64 blocks; block b: edges [b*16384,(b+1)*16384), graph b>>3.
// packed word: deg in [15:0], score in [31:16]; per-block count <= 16384 -> no carry.
__global__ void __launch_bounds__(256) k_hist0(const int* __restrict__ ei,
                                               unsigned int* __restrict__ bh) {
    __shared__ unsigned int h[N0];
    int t = threadIdx.x;
    for (int i = t; i < N0; i += 256) h[i] = 0;
    __syncthreads();
    int base = blockIdx.x * 16384;
    int gbase = (blockIdx.x >> 3) * N0;
    for (int i = t; i < 16384; i += 256) {
        int s = ei[base + i] - gbase;
        int d = ei[NEDGE + base + i] - gbase;
        atomicAdd(&h[d], 1u);
        atomicAdd(&h[s], 0x10000u);
    }
    __syncthreads();
    unsigned int* o = bh + (size_t)blockIdx.x * N0;
    for (int i = t; i < N0; i += 256) o[i] = h[i];
}

// sum 8 per-graph block-histograms -> degI, score
__global__ void k_sumdeg(const unsigned int* __restrict__ bh, int* __restrict__ degI,
                         int* __restrict__ score, int shift, int n) {
    int i = blockIdx.x * 256 + threadIdx.x;
    if (i >= n) return;
    int bins = 1 << shift;
    int g = i >> shift, u = i & (bins - 1);
    const unsigned int* p = bh + ((size_t)(g * 8) << shift) + u;
    int ad = 0, as = 0;
    for (int b = 0; b < 8; b++) {
        unsigned int w = p[(size_t)b * bins];
        ad += (int)(w & 0xFFFFu); as += (int)(w >> 16);
    }
    degI[i] = ad; score[i] = as;
}

// ---------------- layer-0 attention dots ----------------
__global__ void k_alar(const float* __restrict__ cur,
                       const float* __restrict__ attl, const float* __restrict__ attr,
                       float* __restrict__ al, float* __restrict__ ar, int n) {
    int wid  = (blockIdx.x * blockDim.x + threadIdx.x) >> 6;
    int lane = threadIdx.x & 63;
    if (wid >= n) return;
    float2 v  = ((const float2*)(cur + (size_t)wid * C))[lane];
    float2 l2 = ((const float2*)attl)[lane];
    float2 r2 = ((const float2*)attr)[lane];
    float sl = v.x * l2.x + v.y * l2.y;
    float sr = v.x * r2.x + v.y * r2.y;
    for (int o = 32; o >= 1; o >>= 1) { sl += __shfl_xor(sl, o); sr += __shfl_xor(sr, o); }
    if (lane == 0) { al[wid] = sl; ar[wid] = sr; }
}

// ---------------- prefix scan: degI -> rowptr (exclusive) ----------------
__global__ void __launch_bounds__(256) k_scan1(const int* __restrict__ degI,
                                               int* __restrict__ rowptr,
                                               int* __restrict__ bsum) {
    __shared__ int part[256];
    int t = threadIdx.x;
    int base = blockIdx.x * 2048 + t * 8;
    int v[8]; int s = 0;
    for (int i = 0; i < 8; i++) { v[i] = degI[base + i]; s += v[i]; }
    part[t] = s; __syncthreads();
    for (int o = 1; o < 256; o <<= 1) {
        int val = part[t];
        int add = (t >= o) ? part[t - o] : 0;
        __syncthreads();
        part[t] = val + add;
        __syncthreads();
    }
    int run = (t == 0) ? 0 : part[t - 1];
    if (t == 255) bsum[blockIdx.x] = part[255];
    for (int i = 0; i < 8; i++) { rowptr[base + i] = run; run += v[i]; }
}

__global__ void k_scan2(int* __restrict__ bsum, int nb) {
    if (threadIdx.x == 0 && blockIdx.x == 0) {
        int acc = 0;
        for (int i = 0; i < nb; i++) { int v = bsum[i]; bsum[i] = acc; acc += v; }
    }
}

// scan3 + selfco + keep/nmap zero (fused per-node pass)
__global__ void k_scan3s(int* __restrict__ rowptr, int* __restrict__ cursor,
                         const int* __restrict__ bsum, const int* __restrict__ degI,
                         const float* __restrict__ al, const float* __restrict__ ar,
                         float* __restrict__ dinv, float* __restrict__ selfco,
                         unsigned char* __restrict__ keep, int* __restrict__ nmap, int n) {
    int i = blockIdx.x * 256 + threadIdx.x;
    if (i >= n) return;
    int v = rowptr[i] + bsum[i >> 11];
    rowptr[i] = v; cursor[i] = v;
    float d  = (float)degI[i] + 1.0f;
    float di = rsqrtf(d);
    dinv[i]   = di;
    selfco[i] = di * di * tanhf(al[i] + ar[i]);
    keep[i] = 0; nmap[i] = 0;
}

// ---------------- fill CSR: packed (src, coef) records ----------------
__global__ void k_fill(const int* __restrict__ src, const int* __restrict__ dst,
                       const unsigned char* __restrict__ em,
                       const float* __restrict__ dinv, const float* __restrict__ al,
                       const float* __restrict__ ar,
                       int* __restrict__ cursor, int2* __restrict__ edges) {
    int e = blockIdx.x * 256 + threadIdx.x;
    if (e >= NEDGE) return;
    if (em && !em[e]) return;
    int s = src[e], d = dst[e];
    float cf = dinv[s] * dinv[d] * tanhf(al[d] + ar[s]);
    int pos = atomicAdd(&cursor[d], 1);
    edges[pos] = make_int2(s, __float_as_int(cf));
}

// ---------------- CSR gather messages: half-wave per dst node, XCD swizzle ----
__global__ void __launch_bounds__(256) k_msg_csr(
        const int* __restrict__ rowptr, const int* __restrict__ degI,
        const int2* __restrict__ edges,
        const float* __restrict__ cur, const float* __restrict__ x,
        const int* __restrict__ oidx, const float* __restrict__ selfco,
        float* __restrict__ h, int npg) {
    int g    = blockIdx.x & 7;
    int ib   = blockIdx.x >> 3;
    int sub  = threadIdx.x >> 5;
    int lane = threadIdx.x & 31;
    int v = g * npg + ib * 8 + sub;
    int rs = rowptr[v], deg = degI[v];
    float ax = 0.0f, ay = 0.0f, az = 0.0f, aw = 0.0f;
    for (int j = 0; j < deg; j++) {
        int2 er = edges[rs + j];
        float cf = __int_as_float(er.y);
        float4 t = ((const float4*)(cur + (size_t)er.x * C))[lane];
        ax += cf * t.x; ay += cf * t.y; az += cf * t.z; aw += cf * t.w;
    }
    int o = oidx ? oidx[v] : v;
    float4 cv = ((const float4*)(cur + (size_t)v * C))[lane];
    float4 xv = ((const float4*)(x   + (size_t)o * C))[lane];
    float sc = selfco[v];
    float4 r;
    r.x = fmaxf(ax + sc * cv.x + EPS_FA * xv.x, 0.0f);
    r.y = fmaxf(ay + sc * cv.y + EPS_FA * xv.y, 0.0f);
    r.z = fmaxf(az + sc * cv.z + EPS_FA * xv.z, 0.0f);
    r.w = fmaxf(aw + sc * cv.w + EPS_FA * xv.w, 0.0f);
    ((float4*)(h + (size_t)v * C))[lane] = r;
}

// ---------------- per-graph max pool ----------------
__global__ void k_pool(const float* __restrict__ h, float* __restrict__ pooled,
                       int npg, int layer) {
    int g = blockIdx.x, chunk = blockIdx.y, c = threadIdx.x;
    int r0 = chunk * 256;
    float m = 0.0f;
    const float* base = h + ((size_t)g * npg + r0) * C + c;
    for (int r = 0; r < 256; r++) m = fmaxf(m, base[(size_t)r * C]);
    atomicMax((unsigned int*)&pooled[g * 384 + layer * 128 + c], __float_as_uint(m));
}

// ---------------- parallel exact stable top-k ----------------
__global__ void __launch_bounds__(256) k_hist(const int* __restrict__ score, int npg, int nb,
                                              int* __restrict__ blockhist) {
    __shared__ int lh[SMAX];
    int g = blockIdx.x / nb, b = blockIdx.x % nb, t = threadIdx.x;
    for (int s = t; s < SMAX; s += 256) lh[s] = 0;
    __syncthreads();
    int s = score[g * npg + b * 256 + t];
    if (s > SMAX - 1) s = SMAX - 1;
    atomicAdd(&lh[s], 1);
    __syncthreads();
    int* outp = blockhist + ((size_t)g * nb + b) * SMAX;
    for (int i = t; i < SMAX; i += 256) outp[i] = lh[i];
}

__global__ void k_binprefix(int* __restrict__ blockhist, int* __restrict__ hist, int nb) {
    int g = blockIdx.x >> 3;
    int s = (blockIdx.x & 7) * 256 + threadIdx.x;
    int* base = blockhist + (size_t)g * nb * SMAX + s;
    int acc = 0;
    for (int b = 0; b < nb; b++) {
        int v = base[(size_t)b * SMAX];
        base[(size_t)b * SMAX] = acc;
        acc += v;
    }
    hist[g * SMAX + s] = acc;
}

__global__ void __launch_bounds__(256) k_basepos(const int* __restrict__ hist,
                                                 int* __restrict__ basepos) {
    __shared__ int part[256];
    int g = blockIdx.x, t = threadIdx.x;
    const int* hg = hist + g * SMAX;
    int* bp = basepos + g * SMAX;
    int v[8]; int s = 0;
    for (int i = 0; i < 8; i++) { v[i] = hg[SMAX - 1 - (t * 8 + i)]; s += v[i]; }
    part[t] = s; __syncthreads();
    for (int o = 1; o < 256; o <<= 1) {
        int val = part[t];
        int add = (t >= o) ? part[t - o] : 0;
        __syncthreads();
        part[t] = val + add;
        __syncthreads();
    }
    int run = (t == 0) ? 0 : part[t - 1];
    for (int i = 0; i < 8; i++) { bp[SMAX - 1 - (t * 8 + i)] = run; run += v[i]; }
}

__global__ void __launch_bounds__(256) k_rank(const int* __restrict__ score,
                                              const int* __restrict__ blockhist,
                                              const int* __restrict__ basepos,
                                              int npg, int nb, int k,
                                              unsigned char* __restrict__ keep,
                                              int* __restrict__ nmap, int* __restrict__ perm) {
    __shared__ int cs[256];
    int g = blockIdx.x / nb, b = blockIdx.x % nb, t = threadIdx.x;
    int v = b * 256 + t;
    int s = score[g * npg + v];
    if (s > SMAX - 1) s = SMAX - 1;
    cs[t] = s;
    __syncthreads();
    int cnt = 0;
    for (int u = 0; u < t; u++) cnt += (cs[u] == s);
    int pos = basepos[g * SMAX + s]
            + blockhist[((size_t)g * nb + b) * SMAX + s]
            + cnt;
    if (pos < k) {
        int vg = g * npg + v;
        int nid = g * k + pos;
        keep[vg] = 1; nmap[vg] = nid; perm[nid] = vg;
    }
}

// ---------------- gather kept nodes + next-layer al/ar ----------------
__global__ void k_gather_alar(const float* __restrict__ h, const int* __restrict__ perm,
                              const int* __restrict__ oidx,
                              const float* __restrict__ attlN, const float* __restrict__ attrN,
                              float* __restrict__ curN, int* __restrict__ oidxN,
                              float* __restrict__ al, float* __restrict__ ar, int m) {
    int i = blockIdx.x * 256 + threadIdx.x;
    if (i >= m * 32) return;
    int j = i >> 5, c4 = i & 31;
    int p = perm[j];
    float4 v = ((const float4*)(h + (size_t)p * C))[c4];
    ((float4*)(curN + (size_t)j * C))[c4] = v;
    float4 l4 = ((const float4*)attlN)[c4];
    float4 r4 = ((const float4*)attrN)[c4];
    float sl = v.x * l4.x + v.y * l4.y + v.z * l4.z + v.w * l4.w;
    float sr = v.x * r4.x + v.y * r4.y + v.z * r4.z + v.w * r4.w;
    for (int o = 16; o >= 1; o >>= 1) { sl += __shfl_xor(sl, o); sr += __shfl_xor(sr, o); }
    if (c4 == 0) {
        al[j] = sl; ar[j] = sr;
        oidxN[j] = oidx ? oidx[p] : p;
    }
}

// ---------------- remap edges + next-layer deg/score LDS histogram ----------------
// 64 blocks; block b: edges [b*16384,(b+1)*16384), graph b>>3; bins kN<=8192
__global__ void __launch_bounds__(256) k_remap_hist(
        const int* __restrict__ inS, const int* __restrict__ inD,
        const unsigned char* __restrict__ inEm,
        int* __restrict__ src, int* __restrict__ dst, unsigned char* __restrict__ em,
        const unsigned char* __restrict__ keep, const int* __restrict__ nmap,
        unsigned int* __restrict__ bh, int kN) {
    __shared__ unsigned int h[8192];
    int t = threadIdx.x;
    for (int i = t; i < kN; i += 256) h[i] = 0;
    __syncthreads();
    int base = blockIdx.x * 16384;
    int gb = (blockIdx.x >> 3) * kN;
    for (int i = t; i < 16384; i += 256) {
        int e = base + i;
        int s = inS[e], d = inD[e];
        bool ok = (!inEm || inEm[e]) && keep[s] && keep[d];
        if (ok) {
            int ns = nmap[s], nd = nmap[d];
            src[e] = ns; dst[e] = nd; em[e] = 1;
            atomicAdd(&h[nd - gb], 1u);
            atomicAdd(&h[ns - gb], 0x10000u);
        } else { src[e] = 0; dst[e] = 0; em[e] = 0; }
    }
    __syncthreads();
    unsigned int* o = bh + (size_t)blockIdx.x * kN;
    for (int i = t; i < kN; i += 256) o[i] = h[i];
}

// ---------------- GRU + final linears ----------------
__global__ void __launch_bounds__(256) k_tail(const float* __restrict__ pooled,
        const float* __restrict__ wih, const float* __restrict__ bih,
        const float* __restrict__ bhh, const float* __restrict__ wfin,
        const float* __restrict__ bfin, const float* __restrict__ wroot,
        const float* __restrict__ broot, const float* __restrict__ rootv,
        const float* __restrict__ alphap, float* __restrict__ out) {
    int g = blockIdx.x, t = threadIdx.x;
    __shared__ float fused[384];
    __shared__ float gi[768];
    __shared__ float hg[256];
    for (int j = t; j < 384; j += 256) fused[j] = pooled[g * 384 + j];
    __syncthreads();
    for (int r = t; r < 768; r += 256) {
        float s = bih[r];
        const float* w = wih + (size_t)r * 384;
        for (int j = 0; j < 384; j++) s += w[j] * fused[j];
        gi[r] = s;
    }
    __syncthreads();
    if (t < 256) {
        float r  = 1.0f / (1.0f + expf(-(gi[t]       + bhh[t])));
        float z  = 1.0f / (1.0f + expf(-(gi[256 + t] + bhh[256 + t])));
        float nc = tanhf(gi[512 + t] + r * bhh[512 + t]);
        hg[t] = (1.0f - z) * nc;
    }
    __syncthreads();
    if (t < 128) {
        float o = bfin[t];
        const float* w = wfin + (size_t)t * 256;
        for (int j = 0; j < 256; j++) o += w[j] * hg[j];
        float re = broot[t];
        const float* wr = wroot + (size_t)t * 128;
        const float* rg = rootv + (size_t)g * 128;
        for (int j = 0; j < 128; j++) re += wr[j] * rg[j];
        float a = alphap[0];
        out[g * 128 + t] = a * o + (1.0f - a) * re;
    }
}

extern "C" void kernel_launch(void* const* d_in, const int* in_sizes, int n_in,
                              void* d_out, int out_size, void* d_ws, size_t ws_size,
                              hipStream_t stream) {
    const float* x      = (const float*)d_in[0];
    const int*   ei     = (const int*)d_in[1];
    const float* rootv  = (const float*)d_in[3];
    const float* att_l  = (const float*)d_in[4];
    const float* att_r  = (const float*)d_in[5];
    const float* w_ih   = (const float*)d_in[6];
    const float* b_ih   = (const float*)d_in[8];
    const float* b_hh   = (const float*)d_in[9];
    const float* w_fin  = (const float*)d_in[10];
    const float* b_fin  = (const float*)d_in[11];
    const float* w_root = (const float*)d_in[12];
    const float* b_root = (const float*)d_in[13];
    const float* alphap = (const float*)d_in[14];
    float* out = (float*)d_out;

    char* wsb = (char*)d_ws;
    size_t off = 0;
    auto alloc = [&](size_t bytes) -> char* {
        char* p = wsb + off; off += (bytes + 255) & ~(size_t)255; return p;
    };
    float* bufH   = (float*)alloc((size_t)131072 * C * 4);
    float* bufC   = (float*)alloc((size_t)65536  * C * 4);
    int*   srcA   = (int*)alloc((size_t)NEDGE * 4);
    int*   dstA   = (int*)alloc((size_t)NEDGE * 4);
    unsigned char* emask = (unsigned char*)alloc(NEDGE);
    int2*  edges  = (int2*)alloc((size_t)NEDGE * 8);
    float* al     = (float*)alloc(131072 * 4);
    float* ar     = (float*)alloc(131072 * 4);
    float* dinv   = (float*)alloc(131072 * 4);
    float* selfco = (float*)alloc(131072 * 4);
    int*   degI   = (int*)alloc(131072 * 4);
    int*   score  = (int*)alloc(131072 * 4);
    int*   rowptr = (int*)alloc(131072 * 4);
    int*   cursor = (int*)alloc(131072 * 4);
    int*   bsum   = (int*)alloc(256 * 4);
    unsigned char* keep = (unsigned char*)alloc(131072);
    int*   nmap   = (int*)alloc(131072 * 4);
    int*   perm   = (int*)alloc(65536 * 4);
    int*   oidxA  = (int*)alloc(65536 * 4);
    int*   oidxB  = (int*)alloc(32768 * 4);
    float* pooled = (float*)alloc(G * 384 * 4);
    int*   blockhist = (int*)alloc((size_t)G * 64 * SMAX * 4);
    int*   histT  = (int*)alloc((size_t)G * SMAX * 4);
    int*   baseposT = (int*)alloc((size_t)G * SMAX * 4);
    unsigned int* bh = (unsigned int*)alloc((size_t)64 * N0 * 4);  // 4 MB packed deg|score

    k_zero_pooled<<<12, 256, 0, stream>>>(pooled);
    k_hist0<<<64, 256, 0, stream>>>(ei, bh);
    k_sumdeg<<<131072 / 256, 256, 0, stream>>>(bh, degI, score, 14, 131072);

    const int ns[3]   = {131072, 65536, 32768};
    const int npgs[3] = {16384, 8192, 4096};
    const int ks[3]   = {8192, 4096, 0};
    const int shifts[3] = {14, 13, 12};

    for (int l = 0; l < 3; l++) {
        int n = ns[l], npg = npgs[l], k = ks[l];
        const float* cur  = (l == 0) ? x : bufC;
        const int*   oidx = (l == 0) ? nullptr : (l == 1 ? oidxA : oidxB);
        int* oidxN        = (l == 0) ? oidxA : oidxB;
        const int* eS = (l == 0) ? ei : srcA;
        const int* eD = (l == 0) ? ei + NEDGE : dstA;
        const unsigned char* eM = (l == 0) ? nullptr : emask;

        if (l == 0)
            k_alar<<<n / 4, 256, 0, stream>>>(cur, att_l, att_r, al, ar, n);

        int nblk = n / 2048;
        k_scan1<<<nblk, 256, 0, stream>>>(degI, rowptr, bsum);
        k_scan2<<<1, 64, 0, stream>>>(bsum, nblk);
        k_scan3s<<<n / 256, 256, 0, stream>>>(rowptr, cursor, bsum, degI, al, ar,
                                              dinv, selfco, keep, nmap, n);

        k_fill<<<(NEDGE + 255) / 256, 256, 0, stream>>>(eS, eD, eM, dinv, al, ar,
                                                        cursor, edges);
        k_msg_csr<<<n / 8, 256, 0, stream>>>(rowptr, degI, edges, cur, x, oidx,
                                             selfco, bufH, npg);
        k_pool<<<dim3(G, npg / 256), 128, 0, stream>>>(bufH, pooled, npg, l);

        if (l < 2) {
            int nb = npg / 256;
            k_hist<<<G * nb, 256, 0, stream>>>(score, npg, nb, blockhist);
            k_binprefix<<<G * 8, 256, 0, stream>>>(blockhist, histT, nb);
            k_basepos<<<G, 256, 0, stream>>>(histT, baseposT);
            k_rank<<<G * nb, 256, 0, stream>>>(score, blockhist, baseposT, npg, nb, k,
                                               keep, nmap, perm);
            int m = G * k;
            k_gather_alar<<<(m * 32 + 255) / 256, 256, 0, stream>>>(
                bufH, perm, oidx, att_l + (l + 1) * C, att_r + (l + 1) * C,
                bufC, oidxN, al, ar, m);
            k_remap_hist<<<64, 256, 0, stream>>>(eS, eD, eM, srcA, dstA, emask,
                                                 keep, nmap, bh, k);
            k_sumdeg<<<(G * k + 255) / 256, 256, 0, stream>>>(bh, degI, score,
                                                              shifts[l + 1], G * k);
        }
    }

    k_tail<<<G, 256, 0, stream>>>(pooled, w_ih, b_ih, b_hh, w_fin, b_fin,
                                  w_root, b_root, rootv, alphap, out);
}

// Round 6
// 672.801 us; speedup vs baseline: 1.1569x; 1.1569x over previous
//
#include <hip/hip_runtime.h>
#include <math.h>

#define G 8
#define N0 16384
#define NEDGE (G*N0*8)      // 1048576
#define C 128
#define EPS_FA 0.1f
#define SMAX 2048

// ---------------- zero pooled ----------------
__global__ void k_zero_pooled(float* __restrict__ pooled) {
    int i = blockIdx.x * 256 + threadIdx.x;
    if (i < G * 384) pooled[i] = 0.0f;
}

// ---------------- layer-0 deg/score via LDS histogram ----------------
// 128 blocks; block b: edges [b*8192,(b+1)*8192), graph b>>4.
// packed word: deg in [15:0], score in [31:16]; per-block count <= 8192 -> no carry.
__global__ void __launch_bounds__(256) k_hist0(const int* __restrict__ ei,
                                               unsigned int* __restrict__ bh) {
    __shared__ unsigned int h[N0];
    int t = threadIdx.x;
    for (int i = t; i < N0; i += 256) h[i] = 0;
    __syncthreads();
    int base = blockIdx.x * 8192;
    int gbase = (blockIdx.x >> 4) * N0;
    for (int i = t; i < 8192; i += 256) {
        int s = ei[base + i] - gbase;
        int d = ei[NEDGE + base + i] - gbase;
        atomicAdd(&h[d], 1u);
        atomicAdd(&h[s], 0x10000u);
    }
    __syncthreads();
    unsigned int* o = bh + (size_t)blockIdx.x * N0;
    for (int i = t; i < N0; i += 256) o[i] = h[i];
}

// sum nsub per-graph block-histograms -> degI, score
__global__ void k_sumdeg(const unsigned int* __restrict__ bh, int* __restrict__ degI,
                         int* __restrict__ score, int shift, int nsub, int n) {
    int i = blockIdx.x * 256 + threadIdx.x;
    if (i >= n) return;
    int bins = 1 << shift;
    int g = i >> shift, u = i & (bins - 1);
    const unsigned int* p = bh + ((size_t)(g * nsub) << shift) + u;
    int ad = 0, as = 0;
    for (int b = 0; b < nsub; b++) {
        unsigned int w = p[(size_t)b * bins];
        ad += (int)(w & 0xFFFFu); as += (int)(w >> 16);
    }
    degI[i] = ad; score[i] = as;
}

// ---------------- layer-0 attention dots ----------------
__global__ void k_alar(const float* __restrict__ cur,
                       const float* __restrict__ attl, const float* __restrict__ attr,
                       float* __restrict__ al, float* __restrict__ ar, int n) {
    int wid  = (blockIdx.x * blockDim.x + threadIdx.x) >> 6;
    int lane = threadIdx.x & 63;
    if (wid >= n) return;
    float2 v  = ((const float2*)(cur + (size_t)wid * C))[lane];
    float2 l2 = ((const float2*)attl)[lane];
    float2 r2 = ((const float2*)attr)[lane];
    float sl = v.x * l2.x + v.y * l2.y;
    float sr = v.x * r2.x + v.y * r2.y;
    for (int o = 32; o >= 1; o >>= 1) { sl += __shfl_xor(sl, o); sr += __shfl_xor(sr, o); }
    if (lane == 0) { al[wid] = sl; ar[wid] = sr; }
}

// ---------------- prefix scan: degI -> per-chunk exclusive + raw chunk totals ----
__global__ void __launch_bounds__(256) k_scan1(const int* __restrict__ degI,
                                               int* __restrict__ rowptr,
                                               int* __restrict__ bsum) {
    __shared__ int part[256];
    int t = threadIdx.x;
    int base = blockIdx.x * 2048 + t * 8;
    int v[8]; int s = 0;
    for (int i = 0; i < 8; i++) { v[i] = degI[base + i]; s += v[i]; }
    part[t] = s; __syncthreads();
    for (int o = 1; o < 256; o <<= 1) {
        int val = part[t];
        int add = (t >= o) ? part[t - o] : 0;
        __syncthreads();
        part[t] = val + add;
        __syncthreads();
    }
    int run = (t == 0) ? 0 : part[t - 1];
    if (t == 255) bsum[blockIdx.x] = part[255];
    for (int i = 0; i < 8; i++) { rowptr[base + i] = run; run += v[i]; }
}

// scan3 (with inline bsum reduction) + selfco + keep/nmap zero
__global__ void k_scan3s(int* __restrict__ rowptr, int* __restrict__ cursor,
                         const int* __restrict__ bsum, const int* __restrict__ degI,
                         const float* __restrict__ al, const float* __restrict__ ar,
                         float* __restrict__ dinv, float* __restrict__ selfco,
                         unsigned char* __restrict__ keep, int* __restrict__ nmap, int n) {
    __shared__ int base_s;
    int t = threadIdx.x;
    if (t < 64) {
        int c = blockIdx.x >> 3;               // 2048-chunk id (8 blocks per chunk)
        int vv = (t < c) ? bsum[t] : 0;
        for (int o = 32; o >= 1; o >>= 1) vv += __shfl_xor(vv, o);
        if (t == 0) base_s = vv;
    }
    __syncthreads();
    int i = blockIdx.x * 256 + t;
    if (i >= n) return;
    int v = rowptr[i] + base_s;
    rowptr[i] = v; cursor[i] = v;
    float d  = (float)degI[i] + 1.0f;
    float di = rsqrtf(d);
    dinv[i]   = di;
    selfco[i] = di * di * tanhf(al[i] + ar[i]);
    keep[i] = 0; nmap[i] = 0;
}

// ---------------- fill CSR: packed (src, coef) records ----------------
__global__ void k_fill(const int* __restrict__ src, const int* __restrict__ dst,
                       const unsigned char* __restrict__ em,
                       const float* __restrict__ dinv, const float* __restrict__ al,
                       const float* __restrict__ ar,
                       int* __restrict__ cursor, int2* __restrict__ edges) {
    int e = blockIdx.x * 256 + threadIdx.x;
    if (e >= NEDGE) return;
    if (em && !em[e]) return;
    int s = src[e], d = dst[e];
    float cf = dinv[s] * dinv[d] * tanhf(al[d] + ar[s]);
    int pos = atomicAdd(&cursor[d], 1);
    edges[pos] = make_int2(s, __float_as_int(cf));
}

// ---------------- CSR gather messages + per-block pool partial ----------------
// half-wave per dst node, 8 nodes/block, XCD swizzle (blockIdx&7 = graph)
__global__ void __launch_bounds__(256) k_msg_csr(
        const int* __restrict__ rowptr, const int* __restrict__ degI,
        const int2* __restrict__ edges,
        const float* __restrict__ cur, const float* __restrict__ x,
        const int* __restrict__ oidx, const float* __restrict__ selfco,
        float* __restrict__ h, float* __restrict__ pb, int npg) {
    __shared__ float pm[8 * 128];
    int g    = blockIdx.x & 7;
    int ib   = blockIdx.x >> 3;
    int sub  = threadIdx.x >> 5;
    int lane = threadIdx.x & 31;
    int v = g * npg + ib * 8 + sub;
    int rs = rowptr[v], deg = degI[v];
    const long long* ep = (const long long*)(edges + rs);
    float ax = 0.0f, ay = 0.0f, az = 0.0f, aw = 0.0f;
    for (int j = 0; j < deg; j++) {
        long long w = __builtin_nontemporal_load(ep + j);
        int sidx = (int)(w & 0xFFFFFFFFll);
        float cf = __int_as_float((int)(w >> 32));
        float4 t = ((const float4*)(cur + (size_t)sidx * C))[lane];
        ax += cf * t.x; ay += cf * t.y; az += cf * t.z; aw += cf * t.w;
    }
    int o = oidx ? oidx[v] : v;
    float4 cv = ((const float4*)(cur + (size_t)v * C))[lane];
    float4 xv = ((const float4*)(x   + (size_t)o * C))[lane];
    float sc = selfco[v];
    float4 r;
    r.x = fmaxf(ax + sc * cv.x + EPS_FA * xv.x, 0.0f);
    r.y = fmaxf(ay + sc * cv.y + EPS_FA * xv.y, 0.0f);
    r.z = fmaxf(az + sc * cv.z + EPS_FA * xv.z, 0.0f);
    r.w = fmaxf(aw + sc * cv.w + EPS_FA * xv.w, 0.0f);
    ((float4*)(h + (size_t)v * C))[lane] = r;
    ((float4*)(pm + sub * 128))[lane] = r;
    __syncthreads();
    int t = threadIdx.x;
    if (t < 128) {
        float m = pm[t];
        for (int s = 1; s < 8; s++) m = fmaxf(m, pm[s * 128 + t]);
        pb[(size_t)blockIdx.x * 128 + t] = m;
    }
}

// reduce per-block partials -> pooled (per graph, per layer)
__global__ void k_poolred(const float* __restrict__ pb, float* __restrict__ pooled,
                          int rowsPerGraph, int layer) {
    int g = blockIdx.x, ch = blockIdx.y, t = threadIdx.x;
    int R = rowsPerGraph / gridDim.y;
    float m = 0.0f;
    for (int r = ch * R; r < (ch + 1) * R; r++)
        m = fmaxf(m, pb[(size_t)(g + 8 * r) * 128 + t]);
    atomicMax((unsigned int*)&pooled[g * 384 + layer * 128 + t], __float_as_uint(m));
}

// ---------------- parallel exact stable top-k ----------------
__global__ void __launch_bounds__(256) k_hist(const int* __restrict__ score, int npg, int nb,
                                              int* __restrict__ blockhist) {
    __shared__ int lh[SMAX];
    int g = blockIdx.x / nb, b = blockIdx.x % nb, t = threadIdx.x;
    for (int s = t; s < SMAX; s += 256) lh[s] = 0;
    __syncthreads();
    int s = score[g * npg + b * 256 + t];
    if (s > SMAX - 1) s = SMAX - 1;
    atomicAdd(&lh[s], 1);
    __syncthreads();
    int* outp = blockhist + ((size_t)g * nb + b) * SMAX;
    for (int i = t; i < SMAX; i += 256) outp[i] = lh[i];
}

// exclusive prefix across chunks per (g,s) via LDS tile; totals into hist
__global__ void __launch_bounds__(256) k_binprefix(int* __restrict__ blockhist,
                                                   int* __restrict__ hist, int nb) {
    __shared__ int tile[64 * 256];
    int g = blockIdx.x >> 3, ch = blockIdx.x & 7, t = threadIdx.x;
    int s0 = ch * 256;
    int* bg = blockhist + (size_t)g * nb * SMAX + s0;
    for (int b = 0; b < nb; b++) tile[b * 256 + t] = bg[(size_t)b * SMAX + t];
    __syncthreads();
    int acc = 0;
    for (int b = 0; b < nb; b++) {
        int v = tile[b * 256 + t];
        tile[b * 256 + t] = acc;
        acc += v;
    }
    __syncthreads();
    for (int b = 0; b < nb; b++) bg[(size_t)b * SMAX + t] = tile[b * 256 + t];
    hist[g * SMAX + s0 + t] = acc;
}

// rank (basepos derived in-block) -> keep/nmap/perm
__global__ void __launch_bounds__(256) k_rank(const int* __restrict__ score,
                                              const int* __restrict__ blockhist,
                                              const int* __restrict__ hist,
                                              int npg, int nb, int k,
                                              unsigned char* __restrict__ keep,
                                              int* __restrict__ nmap, int* __restrict__ perm) {
    __shared__ int bp[SMAX];
    __shared__ int part[256];
    __shared__ int cs[256];
    int g = blockIdx.x / nb, b = blockIdx.x % nb, t = threadIdx.x;
    // reverse exclusive scan of hist[g] -> bp (count of strictly-greater scores)
    const int* hg = hist + g * SMAX;
    int v[8]; int sm = 0;
    for (int i = 0; i < 8; i++) { v[i] = hg[SMAX - 1 - (t * 8 + i)]; sm += v[i]; }
    part[t] = sm; __syncthreads();
    for (int o = 1; o < 256; o <<= 1) {
        int val = part[t];
        int add = (t >= o) ? part[t - o] : 0;
        __syncthreads();
        part[t] = val + add;
        __syncthreads();
    }
    int run = (t == 0) ? 0 : part[t - 1];
    for (int i = 0; i < 8; i++) { bp[SMAX - 1 - (t * 8 + i)] = run; run += v[i]; }
    // local rank
    int vv = b * 256 + t;
    int s = score[g * npg + vv];
    if (s > SMAX - 1) s = SMAX - 1;
    cs[t] = s;
    __syncthreads();
    int cnt = 0;
    for (int u = 0; u < t; u++) cnt += (cs[u] == s);
    int pos = bp[s] + blockhist[((size_t)g * nb + b) * SMAX + s] + cnt;
    if (pos < k) {
        int vg = g * npg + vv;
        int nid = g * k + pos;
        keep[vg] = 1; nmap[vg] = nid; perm[nid] = vg;
    }
}

// ---------------- gather kept nodes + next-layer al/ar ----------------
__global__ void k_gather_alar(const float* __restrict__ h, const int* __restrict__ perm,
                              const int* __restrict__ oidx,
                              const float* __restrict__ attlN, const float* __restrict__ attrN,
                              float* __restrict__ curN, int* __restrict__ oidxN,
                              float* __restrict__ al, float* __restrict__ ar, int m) {
    int i = blockIdx.x * 256 + threadIdx.x;
    if (i >= m * 32) return;
    int j = i >> 5, c4 = i & 31;
    int p = perm[j];
    float4 v = ((const float4*)(h + (size_t)p * C))[c4];
    ((float4*)(curN + (size_t)j * C))[c4] = v;
    float4 l4 = ((const float4*)attlN)[c4];
    float4 r4 = ((const float4*)attrN)[c4];
    float sl = v.x * l4.x + v.y * l4.y + v.z * l4.z + v.w * l4.w;
    float sr = v.x * r4.x + v.y * r4.y + v.z * r4.z + v.w * r4.w;
    for (int o = 16; o >= 1; o >>= 1) { sl += __shfl_xor(sl, o); sr += __shfl_xor(sr, o); }
    if (c4 == 0) {
        al[j] = sl; ar[j] = sr;
        oidxN[j] = oidx ? oidx[p] : p;
    }
}

// ---------------- remap edges + next-layer deg/score LDS histogram ----------------
// 256 blocks; block b: slots [b*4096,(b+1)*4096), graph b>>5; bins kN<=8192
__global__ void __launch_bounds__(256) k_remap_hist(
        const int* __restrict__ inS, const int* __restrict__ inD,
        const unsigned char* __restrict__ inEm,
        int* __restrict__ src, int* __restrict__ dst, unsigned char* __restrict__ em,
        const unsigned char* __restrict__ keep, const int* __restrict__ nmap,
        unsigned int* __restrict__ bh, int kN) {
    __shared__ unsigned int h[8192];
    int t = threadIdx.x;
    for (int i = t; i < kN; i += 256) h[i] = 0;
    __syncthreads();
    int base = blockIdx.x * 4096;
    int gb = (blockIdx.x >> 5) * kN;
    for (int i = t; i < 4096; i += 256) {
        int e = base + i;
        int s = inS[e], d = inD[e];
        bool ok = (!inEm || inEm[e]) && keep[s] && keep[d];
        if (ok) {
            int ns = nmap[s], nd = nmap[d];
            src[e] = ns; dst[e] = nd; em[e] = 1;
            atomicAdd(&h[nd - gb], 1u);
            atomicAdd(&h[ns - gb], 0x10000u);
        } else { src[e] = 0; dst[e] = 0; em[e] = 0; }
    }
    __syncthreads();
    unsigned int* o = bh + (size_t)blockIdx.x * kN;
    for (int i = t; i < kN; i += 256) o[i] = h[i];
}

// ---------------- GRU + final linears ----------------
__global__ void __launch_bounds__(256) k_tail(const float* __restrict__ pooled,
        const float* __restrict__ wih, const float* __restrict__ bih,
        const float* __restrict__ bhh, const float* __restrict__ wfin,
        const float* __restrict__ bfin, const float* __restrict__ wroot,
        const float* __restrict__ broot, const float* __restrict__ rootv,
        const float* __restrict__ alphap, float* __restrict__ out) {
    int g = blockIdx.x, t = threadIdx.x;
    __shared__ float fused[384];
    __shared__ float gi[768];
    __shared__ float hg[256];
    for (int j = t; j < 384; j += 256) fused[j] = pooled[g * 384 + j];
    __syncthreads();
    for (int r = t; r < 768; r += 256) {
        float s = bih[r];
        const float* w = wih + (size_t)r * 384;
        for (int j = 0; j < 384; j++) s += w[j] * fused[j];
        gi[r] = s;
    }
    __syncthreads();
    if (t < 256) {
        float r  = 1.0f / (1.0f + expf(-(gi[t]       + bhh[t])));
        float z  = 1.0f / (1.0f + expf(-(gi[256 + t] + bhh[256 + t])));
        float nc = tanhf(gi[512 + t] + r * bhh[512 + t]);
        hg[t] = (1.0f - z) * nc;
    }
    __syncthreads();
    if (t < 128) {
        float o = bfin[t];
        const float* w = wfin + (size_t)t * 256;
        for (int j = 0; j < 256; j++) o += w[j] * hg[j];
        float re = broot[t];
        const float* wr = wroot + (size_t)t * 128;
        const float* rg = rootv + (size_t)g * 128;
        for (int j = 0; j < 128; j++) re += wr[j] * rg[j];
        float a = alphap[0];
        out[g * 128 + t] = a * o + (1.0f - a) * re;
    }
}

extern "C" void kernel_launch(void* const* d_in, const int* in_sizes, int n_in,
                              void* d_out, int out_size, void* d_ws, size_t ws_size,
                              hipStream_t stream) {
    const float* x      = (const float*)d_in[0];
    const int*   ei     = (const int*)d_in[1];
    const float* rootv  = (const float*)d_in[3];
    const float* att_l  = (const float*)d_in[4];
    const float* att_r  = (const float*)d_in[5];
    const float* w_ih   = (const float*)d_in[6];
    const float* b_ih   = (const float*)d_in[8];
    const float* b_hh   = (const float*)d_in[9];
    const float* w_fin  = (const float*)d_in[10];
    const float* b_fin  = (const float*)d_in[11];
    const float* w_root = (const float*)d_in[12];
    const float* b_root = (const float*)d_in[13];
    const float* alphap = (const float*)d_in[14];
    float* out = (float*)d_out;

    char* wsb = (char*)d_ws;
    size_t off = 0;
    auto alloc = [&](size_t bytes) -> char* {
        char* p = wsb + off; off += (bytes + 255) & ~(size_t)255; return p;
    };
    float* bufH   = (float*)alloc((size_t)131072 * C * 4);
    float* bufC   = (float*)alloc((size_t)65536  * C * 4);
    int*   srcA   = (int*)alloc((size_t)NEDGE * 4);
    int*   dstA   = (int*)alloc((size_t)NEDGE * 4);
    unsigned char* emask = (unsigned char*)alloc(NEDGE);
    int2*  edges  = (int2*)alloc((size_t)NEDGE * 8);
    float* al     = (float*)alloc(131072 * 4);
    float* ar     = (float*)alloc(131072 * 4);
    float* dinv   = (float*)alloc(131072 * 4);
    float* selfco = (float*)alloc(131072 * 4);
    int*   degI   = (int*)alloc(131072 * 4);
    int*   score  = (int*)alloc(131072 * 4);
    int*   rowptr = (int*)alloc(131072 * 4);
    int*   cursor = (int*)alloc(131072 * 4);
    int*   bsum   = (int*)alloc(256 * 4);
    unsigned char* keep = (unsigned char*)alloc(131072);
    int*   nmap   = (int*)alloc(131072 * 4);
    int*   perm   = (int*)alloc(65536 * 4);
    int*   oidxA  = (int*)alloc(65536 * 4);
    int*   oidxB  = (int*)alloc(32768 * 4);
    float* pooled = (float*)alloc(G * 384 * 4);
    int*   blockhist = (int*)alloc((size_t)G * 64 * SMAX * 4);  // 4 MB
    int*   histT  = (int*)alloc((size_t)G * SMAX * 4);
    // bh (8 MB) holds packed deg|score sub-histograms; pb (pool partials, <=8 MB)
    // aliases it — disjoint lifetimes within each layer.
    unsigned int* bh = (unsigned int*)alloc((size_t)128 * N0 * 4);
    float* pb = (float*)bh;

    k_zero_pooled<<<12, 256, 0, stream>>>(pooled);
    k_hist0<<<128, 256, 0, stream>>>(ei, bh);
    k_sumdeg<<<131072 / 256, 256, 0, stream>>>(bh, degI, score, 14, 16, 131072);

    const int ns[3]   = {131072, 65536, 32768};
    const int npgs[3] = {16384, 8192, 4096};
    const int ks[3]   = {8192, 4096, 0};
    const int shifts[3] = {14, 13, 12};

    for (int l = 0; l < 3; l++) {
        int n = ns[l], npg = npgs[l], k = ks[l];
        const float* cur  = (l == 0) ? x : bufC;
        const int*   oidx = (l == 0) ? nullptr : (l == 1 ? oidxA : oidxB);
        int* oidxN        = (l == 0) ? oidxA : oidxB;
        const int* eS = (l == 0) ? ei : srcA;
        const int* eD = (l == 0) ? ei + NEDGE : dstA;
        const unsigned char* eM = (l == 0) ? nullptr : emask;

        if (l == 0)
            k_alar<<<n / 4, 256, 0, stream>>>(cur, att_l, att_r, al, ar, n);

        int nblk = n / 2048;
        k_scan1<<<nblk, 256, 0, stream>>>(degI, rowptr, bsum);
        k_scan3s<<<n / 256, 256, 0, stream>>>(rowptr, cursor, bsum, degI, al, ar,
                                              dinv, selfco, keep, nmap, n);

        k_fill<<<(NEDGE + 255) / 256, 256, 0, stream>>>(eS, eD, eM, dinv, al, ar,
                                                        cursor, edges);
        k_msg_csr<<<n / 8, 256, 0, stream>>>(rowptr, degI, edges, cur, x, oidx,
                                             selfco, bufH, pb, npg);
        k_poolred<<<dim3(G, 8), 128, 0, stream>>>(pb, pooled, n / 64, l);

        if (l < 2) {
            int nb = npg / 256;
            k_hist<<<G * nb, 256, 0, stream>>>(score, npg, nb, blockhist);
            k_binprefix<<<G * 8, 256, 0, stream>>>(blockhist, histT, nb);
            k_rank<<<G * nb, 256, 0, stream>>>(score, blockhist, histT, npg, nb, k,
                                               keep, nmap, perm);
            int m = G * k;
            k_gather_alar<<<(m * 32 + 255) / 256, 256, 0, stream>>>(
                bufH, perm, oidx, att_l + (l + 1) * C, att_r + (l + 1) * C,
                bufC, oidxN, al, ar, m);
            k_remap_hist<<<256, 256, 0, stream>>>(eS, eD, eM, srcA, dstA, emask,
                                                  keep, nmap, bh, k);
            k_sumdeg<<<(G * k + 255) / 256, 256, 0, stream>>>(bh, degI, score,
                                                              shifts[l + 1], 32, G * k);
        }
    }

    k_tail<<<G, 256, 0, stream>>>(pooled, w_ih, b_ih, b_hh, w_fin, b_fin,
                                  w_root, b_root, rootv, alphap, out);
}

// Round 7
// 593.675 us; speedup vs baseline: 1.3111x; 1.1333x over previous
//
#include <hip/hip_runtime.h>
#include <math.h>

#define G 8
#define N0 16384
#define NEDGE (G*N0*8)      // 1048576
#define C 128
#define EPS_FA 0.1f
#define SMAX 2048

typedef unsigned short ushort_t;
typedef unsigned int uint_t;

__device__ inline ushort_t f2bf(float f) {
    uint_t u = __float_as_uint(f);
    uint_t r = (u + 0x7FFFu + ((u >> 16) & 1u)) >> 16;
    return (ushort_t)r;
}
__device__ inline uint_t pack2bf(float a, float b) {
    return (uint_t)f2bf(a) | ((uint_t)f2bf(b) << 16);
}
__device__ inline float bflo(uint_t w) { return __uint_as_float(w << 16); }
__device__ inline float bfhi(uint_t w) { return __uint_as_float(w & 0xFFFF0000u); }

// ---------------- zero pooled ----------------
__global__ void k_zero_pooled(float* __restrict__ pooled) {
    int i = blockIdx.x * 256 + threadIdx.x;
    if (i < G * 384) pooled[i] = 0.0f;
}

// ---------------- layer-0 deg/score via LDS histogram ----------------
// 128 blocks; block b: edges [b*8192,(b+1)*8192), graph b>>4.
__global__ void __launch_bounds__(256) k_hist0(const int* __restrict__ ei,
                                               unsigned int* __restrict__ bh) {
    __shared__ unsigned int h[N0];
    int t = threadIdx.x;
    for (int i = t; i < N0; i += 256) h[i] = 0;
    __syncthreads();
    int base = blockIdx.x * 8192;
    int gbase = (blockIdx.x >> 4) * N0;
    for (int i = t; i < 8192; i += 256) {
        int s = ei[base + i] - gbase;
        int d = ei[NEDGE + base + i] - gbase;
        atomicAdd(&h[d], 1u);
        atomicAdd(&h[s], 0x10000u);
    }
    __syncthreads();
    unsigned int* o = bh + (size_t)blockIdx.x * N0;
    for (int i = t; i < N0; i += 256) o[i] = h[i];
}

__global__ void k_sumdeg(const unsigned int* __restrict__ bh, int* __restrict__ degI,
                         int* __restrict__ score, int shift, int nsub, int n) {
    int i = blockIdx.x * 256 + threadIdx.x;
    if (i >= n) return;
    int bins = 1 << shift;
    int g = i >> shift, u = i & (bins - 1);
    const unsigned int* p = bh + ((size_t)(g * nsub) << shift) + u;
    int ad = 0, as = 0;
    for (int b = 0; b < nsub; b++) {
        unsigned int w = p[(size_t)b * bins];
        ad += (int)(w & 0xFFFFu); as += (int)(w >> 16);
    }
    degI[i] = ad; score[i] = as;
}

// ---------------- layer-0 attention dots + x -> bf16 conversion ----------------
__global__ void k_alar(const float* __restrict__ x,
                       const float* __restrict__ attl, const float* __restrict__ attr,
                       float* __restrict__ al, float* __restrict__ ar,
                       ushort_t* __restrict__ xb, int n) {
    int wid  = (blockIdx.x * blockDim.x + threadIdx.x) >> 6;
    int lane = threadIdx.x & 63;
    if (wid >= n) return;
    float2 v  = ((const float2*)(x + (size_t)wid * C))[lane];
    ((uint_t*)(xb + (size_t)wid * C))[lane] = pack2bf(v.x, v.y);
    float2 l2 = ((const float2*)attl)[lane];
    float2 r2 = ((const float2*)attr)[lane];
    float sl = v.x * l2.x + v.y * l2.y;
    float sr = v.x * r2.x + v.y * r2.y;
    for (int o = 32; o >= 1; o >>= 1) { sl += __shfl_xor(sl, o); sr += __shfl_xor(sr, o); }
    if (lane == 0) { al[wid] = sl; ar[wid] = sr; }
}

// ---------------- prefix scan: degI -> per-chunk exclusive + chunk totals ----
__global__ void __launch_bounds__(256) k_scan1(const int* __restrict__ degI,
                                               int* __restrict__ rowptr,
                                               int* __restrict__ bsum) {
    __shared__ int part[256];
    int t = threadIdx.x;
    int base = blockIdx.x * 2048 + t * 8;
    int v[8]; int s = 0;
    for (int i = 0; i < 8; i++) { v[i] = degI[base + i]; s += v[i]; }
    part[t] = s; __syncthreads();
    for (int o = 1; o < 256; o <<= 1) {
        int val = part[t];
        int add = (t >= o) ? part[t - o] : 0;
        __syncthreads();
        part[t] = val + add;
        __syncthreads();
    }
    int run = (t == 0) ? 0 : part[t - 1];
    if (t == 255) bsum[blockIdx.x] = part[255];
    for (int i = 0; i < 8; i++) { rowptr[base + i] = run; run += v[i]; }
}

// scan3 (inline bsum reduce) + selfco + keep/nmap zero
__global__ void k_scan3s(int* __restrict__ rowptr, int* __restrict__ cursor,
                         const int* __restrict__ bsum, const int* __restrict__ degI,
                         const float* __restrict__ al, const float* __restrict__ ar,
                         float* __restrict__ dinv, float* __restrict__ selfco,
                         unsigned char* __restrict__ keep, int* __restrict__ nmap, int n) {
    __shared__ int base_s;
    int t = threadIdx.x;
    if (t < 64) {
        int c = blockIdx.x >> 3;
        int vv = (t < c) ? bsum[t] : 0;
        for (int o = 32; o >= 1; o >>= 1) vv += __shfl_xor(vv, o);
        if (t == 0) base_s = vv;
    }
    __syncthreads();
    int i = blockIdx.x * 256 + t;
    if (i >= n) return;
    int v = rowptr[i] + base_s;
    rowptr[i] = v; cursor[i] = v;
    float d  = (float)degI[i] + 1.0f;
    float di = rsqrtf(d);
    dinv[i]   = di;
    selfco[i] = di * di * tanhf(al[i] + ar[i]);
    keep[i] = 0; nmap[i] = 0;
}

// ---------------- fill CSR: packed (src, coef) records ----------------
__global__ void k_fill(const int* __restrict__ src, const int* __restrict__ dst,
                       const unsigned char* __restrict__ em,
                       const float* __restrict__ dinv, const float* __restrict__ al,
                       const float* __restrict__ ar,
                       int* __restrict__ cursor, int2* __restrict__ edges) {
    int e = blockIdx.x * 256 + threadIdx.x;
    if (e >= NEDGE) return;
    if (em && !em[e]) return;
    int s = src[e], d = dst[e];
    float cf = dinv[s] * dinv[d] * tanhf(al[d] + ar[s]);
    int pos = atomicAdd(&cursor[d], 1);
    edges[pos] = make_int2(s, __float_as_int(cf));
}

// ---------------- CSR gather messages (bf16 rows) + per-block pool partial ----
// half-wave per dst node, 8 nodes/block, XCD swizzle (blockIdx&7 = graph)
__global__ void __launch_bounds__(256) k_msg_csr(
        const int* __restrict__ rowptr, const int* __restrict__ degI,
        const int2* __restrict__ edges,
        const ushort_t* __restrict__ cur, const ushort_t* __restrict__ xb,
        const int* __restrict__ oidx, const float* __restrict__ selfco,
        ushort_t* __restrict__ h, float* __restrict__ pb, int npg) {
    __shared__ float pm[8 * 128];
    int g    = blockIdx.x & 7;
    int ib   = blockIdx.x >> 3;
    int sub  = threadIdx.x >> 5;
    int lane = threadIdx.x & 31;
    int v = g * npg + ib * 8 + sub;
    int rs = rowptr[v], deg = degI[v];
    float a0 = 0.0f, a1 = 0.0f, a2 = 0.0f, a3 = 0.0f;
    for (int j0 = 0; j0 < deg; j0 += 32) {
        int cnt = deg - j0; if (cnt > 32) cnt = 32;
        int2 er = make_int2(0, 0);
        if (lane < cnt) er = edges[rs + j0 + lane];
        for (int j = 0; j < cnt; j++) {
            int sidx = __shfl(er.x, j, 32);
            float cf = __int_as_float(__shfl(er.y, j, 32));
            uint2 w = ((const uint2*)(cur + (size_t)sidx * C))[lane];
            a0 += cf * bflo(w.x); a1 += cf * bfhi(w.x);
            a2 += cf * bflo(w.y); a3 += cf * bfhi(w.y);
        }
    }
    int o = oidx ? oidx[v] : v;
    uint2 cw = ((const uint2*)(cur + (size_t)v * C))[lane];
    uint2 xw = ((const uint2*)(xb  + (size_t)o * C))[lane];
    float sc = selfco[v];
    float r0 = fmaxf(a0 + sc * bflo(cw.x) + EPS_FA * bflo(xw.x), 0.0f);
    float r1 = fmaxf(a1 + sc * bfhi(cw.x) + EPS_FA * bfhi(xw.x), 0.0f);
    float r2 = fmaxf(a2 + sc * bflo(cw.y) + EPS_FA * bflo(xw.y), 0.0f);
    float r3 = fmaxf(a3 + sc * bfhi(cw.y) + EPS_FA * bfhi(xw.y), 0.0f);
    uint2 hw; hw.x = pack2bf(r0, r1); hw.y = pack2bf(r2, r3);
    ((uint2*)(h + (size_t)v * C))[lane] = hw;
    float4 rr = make_float4(r0, r1, r2, r3);
    ((float4*)(pm + sub * 128))[lane] = rr;
    __syncthreads();
    int t = threadIdx.x;
    if (t < 128) {
        float m = pm[t];
        for (int s = 1; s < 8; s++) m = fmaxf(m, pm[s * 128 + t]);
        pb[(size_t)blockIdx.x * 128 + t] = m;
    }
}

// reduce per-block partials -> pooled
__global__ void k_poolred(const float* __restrict__ pb, float* __restrict__ pooled,
                          int rowsPerGraph, int layer) {
    int g = blockIdx.x, ch = blockIdx.y, t = threadIdx.x;
    int R = rowsPerGraph / gridDim.y;
    float m = 0.0f;
    for (int r = ch * R; r < (ch + 1) * R; r++)
        m = fmaxf(m, pb[(size_t)(g + 8 * r) * 128 + t]);
    atomicMax((unsigned int*)&pooled[g * 384 + layer * 128 + t], __float_as_uint(m));
}

// ---------------- parallel exact stable top-k ----------------
__global__ void __launch_bounds__(256) k_hist(const int* __restrict__ score, int npg, int nb,
                                              int* __restrict__ blockhist) {
    __shared__ int lh[SMAX];
    int g = blockIdx.x / nb, b = blockIdx.x % nb, t = threadIdx.x;
    for (int s = t; s < SMAX; s += 256) lh[s] = 0;
    __syncthreads();
    int s = score[g * npg + b * 256 + t];
    if (s > SMAX - 1) s = SMAX - 1;
    atomicAdd(&lh[s], 1);
    __syncthreads();
    int* outp = blockhist + ((size_t)g * nb + b) * SMAX;
    for (int i = t; i < SMAX; i += 256) outp[i] = lh[i];
}

__global__ void __launch_bounds__(256) k_binprefix(int* __restrict__ blockhist,
                                                   int* __restrict__ hist, int nb) {
    __shared__ int tile[64 * 256];
    int g = blockIdx.x >> 3, ch = blockIdx.x & 7, t = threadIdx.x;
    int s0 = ch * 256;
    int* bg = blockhist + (size_t)g * nb * SMAX + s0;
    for (int b = 0; b < nb; b++) tile[b * 256 + t] = bg[(size_t)b * SMAX + t];
    __syncthreads();
    int acc = 0;
    for (int b = 0; b < nb; b++) {
        int v = tile[b * 256 + t];
        tile[b * 256 + t] = acc;
        acc += v;
    }
    __syncthreads();
    for (int b = 0; b < nb; b++) bg[(size_t)b * SMAX + t] = tile[b * 256 + t];
    hist[g * SMAX + s0 + t] = acc;
}

__global__ void __launch_bounds__(256) k_rank(const int* __restrict__ score,
                                              const int* __restrict__ blockhist,
                                              const int* __restrict__ hist,
                                              int npg, int nb, int k,
                                              unsigned char* __restrict__ keep,
                                              int* __restrict__ nmap, int* __restrict__ perm) {
    __shared__ int bp[SMAX];
    __shared__ int part[256];
    __shared__ int cs[256];
    int g = blockIdx.x / nb, b = blockIdx.x % nb, t = threadIdx.x;
    const int* hg = hist + g * SMAX;
    int v[8]; int sm = 0;
    for (int i = 0; i < 8; i++) { v[i] = hg[SMAX - 1 - (t * 8 + i)]; sm += v[i]; }
    part[t] = sm; __syncthreads();
    for (int o = 1; o < 256; o <<= 1) {
        int val = part[t];
        int add = (t >= o) ? part[t - o] : 0;
        __syncthreads();
        part[t] = val + add;
        __syncthreads();
    }
    int run = (t == 0) ? 0 : part[t - 1];
    for (int i = 0; i < 8; i++) { bp[SMAX - 1 - (t * 8 + i)] = run; run += v[i]; }
    int vv = b * 256 + t;
    int s = score[g * npg + vv];
    if (s > SMAX - 1) s = SMAX - 1;
    cs[t] = s;
    __syncthreads();
    int cnt = 0;
    for (int u = 0; u < t; u++) cnt += (cs[u] == s);
    int pos = bp[s] + blockhist[((size_t)g * nb + b) * SMAX + s] + cnt;
    if (pos < k) {
        int vg = g * npg + vv;
        int nid = g * k + pos;
        keep[vg] = 1; nmap[vg] = nid; perm[nid] = vg;
    }
}

// ---------------- gather kept nodes (bf16) + next-layer al/ar ----------------
__global__ void k_gather_alar(const ushort_t* __restrict__ h, const int* __restrict__ perm,
                              const int* __restrict__ oidx,
                              const float* __restrict__ attlN, const float* __restrict__ attrN,
                              ushort_t* __restrict__ curN, int* __restrict__ oidxN,
                              float* __restrict__ al, float* __restrict__ ar, int m) {
    int i = blockIdx.x * 256 + threadIdx.x;
    if (i >= m * 32) return;
    int j = i >> 5, c4 = i & 31;
    int p = perm[j];
    uint2 w = ((const uint2*)(h + (size_t)p * C))[c4];
    ((uint2*)(curN + (size_t)j * C))[c4] = w;
    float f0 = bflo(w.x), f1 = bfhi(w.x), f2 = bflo(w.y), f3 = bfhi(w.y);
    float4 l4 = ((const float4*)attlN)[c4];
    float4 r4 = ((const float4*)attrN)[c4];
    float sl = f0 * l4.x + f1 * l4.y + f2 * l4.z + f3 * l4.w;
    float sr = f0 * r4.x + f1 * r4.y + f2 * r4.z + f3 * r4.w;
    for (int o = 16; o >= 1; o >>= 1) { sl += __shfl_xor(sl, o); sr += __shfl_xor(sr, o); }
    if (c4 == 0) {
        al[j] = sl; ar[j] = sr;
        oidxN[j] = oidx ? oidx[p] : p;
    }
}

// ---------------- remap edges + next-layer deg/score LDS histogram ----------------
__global__ void __launch_bounds__(256) k_remap_hist(
        const int* __restrict__ inS, const int* __restrict__ inD,
        const unsigned char* __restrict__ inEm,
        int* __restrict__ src, int* __restrict__ dst, unsigned char* __restrict__ em,
        const unsigned char* __restrict__ keep, const int* __restrict__ nmap,
        unsigned int* __restrict__ bh, int kN) {
    __shared__ unsigned int h[8192];
    int t = threadIdx.x;
    for (int i = t; i < kN; i += 256) h[i] = 0;
    __syncthreads();
    int base = blockIdx.x * 4096;
    int gb = (blockIdx.x >> 5) * kN;
    for (int i = t; i < 4096; i += 256) {
        int e = base + i;
        int s = inS[e], d = inD[e];
        bool ok = (!inEm || inEm[e]) && keep[s] && keep[d];
        if (ok) {
            int ns = nmap[s], nd = nmap[d];
            src[e] = ns; dst[e] = nd; em[e] = 1;
            atomicAdd(&h[nd - gb], 1u);
            atomicAdd(&h[ns - gb], 0x10000u);
        } else { src[e] = 0; dst[e] = 0; em[e] = 0; }
    }
    __syncthreads();
    unsigned int* o = bh + (size_t)blockIdx.x * kN;
    for (int i = t; i < kN; i += 256) o[i] = h[i];
}

// ---------------- GRU + final linears ----------------
__global__ void __launch_bounds__(256) k_tail(const float* __restrict__ pooled,
        const float* __restrict__ wih, const float* __restrict__ bih,
        const float* __restrict__ bhh, const float* __restrict__ wfin,
        const float* __restrict__ bfin, const float* __restrict__ wroot,
        const float* __restrict__ broot, const float* __restrict__ rootv,
        const float* __restrict__ alphap, float* __restrict__ out) {
    int g = blockIdx.x, t = threadIdx.x;
    __shared__ float fused[384];
    __shared__ float gi[768];
    __shared__ float hg[256];
    for (int j = t; j < 384; j += 256) fused[j] = pooled[g * 384 + j];
    __syncthreads();
    for (int r = t; r < 768; r += 256) {
        float s = bih[r];
        const float* w = wih + (size_t)r * 384;
        for (int j = 0; j < 384; j++) s += w[j] * fused[j];
        gi[r] = s;
    }
    __syncthreads();
    if (t < 256) {
        float r  = 1.0f / (1.0f + expf(-(gi[t]       + bhh[t])));
        float z  = 1.0f / (1.0f + expf(-(gi[256 + t] + bhh[256 + t])));
        float nc = tanhf(gi[512 + t] + r * bhh[512 + t]);
        hg[t] = (1.0f - z) * nc;
    }
    __syncthreads();
    if (t < 128) {
        float o = bfin[t];
        const float* w = wfin + (size_t)t * 256;
        for (int j = 0; j < 256; j++) o += w[j] * hg[j];
        float re = broot[t];
        const float* wr = wroot + (size_t)t * 128;
        const float* rg = rootv + (size_t)g * 128;
        for (int j = 0; j < 128; j++) re += wr[j] * rg[j];
        float a = alphap[0];
        out[g * 128 + t] = a * o + (1.0f - a) * re;
    }
}

extern "C" void kernel_launch(void* const* d_in, const int* in_sizes, int n_in,
                              void* d_out, int out_size, void* d_ws, size_t ws_size,
                              hipStream_t stream) {
    const float* x      = (const float*)d_in[0];
    const int*   ei     = (const int*)d_in[1];
    const float* rootv  = (const float*)d_in[3];
    const float* att_l  = (const float*)d_in[4];
    const float* att_r  = (const float*)d_in[5];
    const float* w_ih   = (const float*)d_in[6];
    const float* b_ih   = (const float*)d_in[8];
    const float* b_hh   = (const float*)d_in[9];
    const float* w_fin  = (const float*)d_in[10];
    const float* b_fin  = (const float*)d_in[11];
    const float* w_root = (const float*)d_in[12];
    const float* b_root = (const float*)d_in[13];
    const float* alphap = (const float*)d_in[14];
    float* out = (float*)d_out;

    char* wsb = (char*)d_ws;
    size_t off = 0;
    auto alloc = [&](size_t bytes) -> char* {
        char* p = wsb + off; off += (bytes + 255) & ~(size_t)255; return p;
    };
    ushort_t* xb   = (ushort_t*)alloc((size_t)131072 * C * 2);   // x in bf16
    ushort_t* bufH = (ushort_t*)alloc((size_t)131072 * C * 2);   // h in bf16
    ushort_t* bufC = (ushort_t*)alloc((size_t)65536  * C * 2);   // cur in bf16
    int*   srcA   = (int*)alloc((size_t)NEDGE * 4);
    int*   dstA   = (int*)alloc((size_t)NEDGE * 4);
    unsigned char* emask = (unsigned char*)alloc(NEDGE);
    int2*  edges  = (int2*)alloc((size_t)NEDGE * 8);
    float* al     = (float*)alloc(131072 * 4);
    float* ar     = (float*)alloc(131072 * 4);
    float* dinv   = (float*)alloc(131072 * 4);
    float* selfco = (float*)alloc(131072 * 4);
    int*   degI   = (int*)alloc(131072 * 4);
    int*   score  = (int*)alloc(131072 * 4);
    int*   rowptr = (int*)alloc(131072 * 4);
    int*   cursor = (int*)alloc(131072 * 4);
    int*   bsum   = (int*)alloc(256 * 4);
    unsigned char* keep = (unsigned char*)alloc(131072);
    int*   nmap   = (int*)alloc(131072 * 4);
    int*   perm   = (int*)alloc(65536 * 4);
    int*   oidxA  = (int*)alloc(65536 * 4);
    int*   oidxB  = (int*)alloc(32768 * 4);
    float* pooled = (float*)alloc(G * 384 * 4);
    int*   blockhist = (int*)alloc((size_t)G * 64 * SMAX * 4);
    int*   histT  = (int*)alloc((size_t)G * SMAX * 4);
    unsigned int* bh = (unsigned int*)alloc((size_t)128 * N0 * 4);  // 8 MB
    float* pb = (float*)bh;   // pool partials alias bh (disjoint lifetimes)

    k_zero_pooled<<<12, 256, 0, stream>>>(pooled);
    k_hist0<<<128, 256, 0, stream>>>(ei, bh);
    k_sumdeg<<<131072 / 256, 256, 0, stream>>>(bh, degI, score, 14, 16, 131072);

    const int ns[3]   = {131072, 65536, 32768};
    const int npgs[3] = {16384, 8192, 4096};
    const int ks[3]   = {8192, 4096, 0};
    const int shifts[3] = {14, 13, 12};

    for (int l = 0; l < 3; l++) {
        int n = ns[l], npg = npgs[l], k = ks[l];
        const ushort_t* cur = (l == 0) ? xb : bufC;
        const int* oidx = (l == 0) ? nullptr : (l == 1 ? oidxA : oidxB);
        int* oidxN = (l == 0) ? oidxA : oidxB;
        const int* eS = (l == 0) ? ei : srcA;
        const int* eD = (l == 0) ? ei + NEDGE : dstA;
        const unsigned char* eM = (l == 0) ? nullptr : emask;

        if (l == 0)
            k_alar<<<n / 4, 256, 0, stream>>>(x, att_l, att_r, al, ar, xb, n);

        int nblk = n / 2048;
        k_scan1<<<nblk, 256, 0, stream>>>(degI, rowptr, bsum);
        k_scan3s<<<n / 256, 256, 0, stream>>>(rowptr, cursor, bsum, degI, al, ar,
                                              dinv, selfco, keep, nmap, n);

        k_fill<<<(NEDGE + 255) / 256, 256, 0, stream>>>(eS, eD, eM, dinv, al, ar,
                                                        cursor, edges);
        k_msg_csr<<<n / 8, 256, 0, stream>>>(rowptr, degI, edges, cur, xb, oidx,
                                             selfco, bufH, pb, npg);
        k_poolred<<<dim3(G, 8), 128, 0, stream>>>(pb, pooled, n / 64, l);

        if (l < 2) {
            int nb = npg / 256;
            k_hist<<<G * nb, 256, 0, stream>>>(score, npg, nb, blockhist);
            k_binprefix<<<G * 8, 256, 0, stream>>>(blockhist, histT, nb);
            k_rank<<<G * nb, 256, 0, stream>>>(score, blockhist, histT, npg, nb, k,
                                               keep, nmap, perm);
            int m = G * k;
            k_gather_alar<<<(m * 32 + 255) / 256, 256, 0, stream>>>(
                bufH, perm, oidx, att_l + (l + 1) * C, att_r + (l + 1) * C,
                bufC, oidxN, al, ar, m);
            k_remap_hist<<<256, 256, 0, stream>>>(eS, eD, eM, srcA, dstA, emask,
                                                  keep, nmap, bh, k);
            k_sumdeg<<<(G * k + 255) / 256, 256, 0, stream>>>(bh, degI, score,
                                                              shifts[l + 1], 32, G * k);
        }
    }

    k_tail<<<G, 256, 0, stream>>>(pooled, w_ih, b_ih, b_hh, w_fin, b_fin,
                                  w_root, b_root, rootv, alphap, out);
}

// Round 8
// 563.364 us; speedup vs baseline: 1.3816x; 1.0538x over previous
//
#include <hip/hip_runtime.h>
#include <math.h>

#define G 8
#define N0 16384
#define NEDGE (G*N0*8)      // 1048576
#define C 128
#define EPS_FA 0.1f
#define SMAX 2048

typedef unsigned short ushort_t;
typedef unsigned int uint_t;

__device__ inline ushort_t f2bf(float f) {
    uint_t u = __float_as_uint(f);
    uint_t r = (u + 0x7FFFu + ((u >> 16) & 1u)) >> 16;
    return (ushort_t)r;
}
__device__ inline uint_t pack2bf(float a, float b) {
    return (uint_t)f2bf(a) | ((uint_t)f2bf(b) << 16);
}
__device__ inline float bflo(uint_t w) { return __uint_as_float(w << 16); }
__device__ inline float bfhi(uint_t w) { return __uint_as_float(w & 0xFFFF0000u); }

// ---------------- zero pooled ----------------
__global__ void k_zero_pooled(float* __restrict__ pooled) {
    int i = blockIdx.x * 256 + threadIdx.x;
    if (i < G * 384) pooled[i] = 0.0f;
}

// ---------------- layer-0 deg/score via LDS histogram ----------------
__global__ void __launch_bounds__(256) k_hist0(const int* __restrict__ ei,
                                               unsigned int* __restrict__ bh) {
    __shared__ unsigned int h[N0];
    int t = threadIdx.x;
    for (int i = t; i < N0; i += 256) h[i] = 0;
    __syncthreads();
    int base = blockIdx.x * 8192;
    int gbase = (blockIdx.x >> 4) * N0;
    for (int i = t; i < 8192; i += 256) {
        int s = ei[base + i] - gbase;
        int d = ei[NEDGE + base + i] - gbase;
        atomicAdd(&h[d], 1u);
        atomicAdd(&h[s], 0x10000u);
    }
    __syncthreads();
    unsigned int* o = bh + (size_t)blockIdx.x * N0;
    for (int i = t; i < N0; i += 256) o[i] = h[i];
}

__global__ void k_sumdeg(const unsigned int* __restrict__ bh, int* __restrict__ degI,
                         int* __restrict__ score, int shift, int nsub, int n) {
    int i = blockIdx.x * 256 + threadIdx.x;
    if (i >= n) return;
    int bins = 1 << shift;
    int g = i >> shift, u = i & (bins - 1);
    const unsigned int* p = bh + ((size_t)(g * nsub) << shift) + u;
    int ad = 0, as = 0;
    for (int b = 0; b < nsub; b++) {
        unsigned int w = p[(size_t)b * bins];
        ad += (int)(w & 0xFFFFu); as += (int)(w >> 16);
    }
    degI[i] = ad; score[i] = as;
}

// ---------------- layer-0 attention dots + x -> bf16 conversion ----------------
__global__ void k_alar(const float* __restrict__ x,
                       const float* __restrict__ attl, const float* __restrict__ attr,
                       float* __restrict__ al, float* __restrict__ ar,
                       ushort_t* __restrict__ xb, int n) {
    int wid  = (blockIdx.x * blockDim.x + threadIdx.x) >> 6;
    int lane = threadIdx.x & 63;
    if (wid >= n) return;
    float2 v  = ((const float2*)(x + (size_t)wid * C))[lane];
    ((uint_t*)(xb + (size_t)wid * C))[lane] = pack2bf(v.x, v.y);
    float2 l2 = ((const float2*)attl)[lane];
    float2 r2 = ((const float2*)attr)[lane];
    float sl = v.x * l2.x + v.y * l2.y;
    float sr = v.x * r2.x + v.y * r2.y;
    for (int o = 32; o >= 1; o >>= 1) { sl += __shfl_xor(sl, o); sr += __shfl_xor(sr, o); }
    if (lane == 0) { al[wid] = sl; ar[wid] = sr; }
}

// ---------------- prefix scan ----------------
__global__ void __launch_bounds__(256) k_scan1(const int* __restrict__ degI,
                                               int* __restrict__ rowptr,
                                               int* __restrict__ bsum) {
    __shared__ int part[256];
    int t = threadIdx.x;
    int base = blockIdx.x * 2048 + t * 8;
    int v[8]; int s = 0;
    for (int i = 0; i < 8; i++) { v[i] = degI[base + i]; s += v[i]; }
    part[t] = s; __syncthreads();
    for (int o = 1; o < 256; o <<= 1) {
        int val = part[t];
        int add = (t >= o) ? part[t - o] : 0;
        __syncthreads();
        part[t] = val + add;
        __syncthreads();
    }
    int run = (t == 0) ? 0 : part[t - 1];
    if (t == 255) bsum[blockIdx.x] = part[255];
    for (int i = 0; i < 8; i++) { rowptr[base + i] = run; run += v[i]; }
}

__global__ void k_scan3s(int* __restrict__ rowptr, int* __restrict__ cursor,
                         const int* __restrict__ bsum, const int* __restrict__ degI,
                         const float* __restrict__ al, const float* __restrict__ ar,
                         float* __restrict__ dinv, float* __restrict__ selfco,
                         unsigned char* __restrict__ keep, int* __restrict__ nmap, int n) {
    __shared__ int base_s;
    int t = threadIdx.x;
    if (t < 64) {
        int c = blockIdx.x >> 3;
        int vv = (t < c) ? bsum[t] : 0;
        for (int o = 32; o >= 1; o >>= 1) vv += __shfl_xor(vv, o);
        if (t == 0) base_s = vv;
    }
    __syncthreads();
    int i = blockIdx.x * 256 + t;
    if (i >= n) return;
    int v = rowptr[i] + base_s;
    rowptr[i] = v; cursor[i] = v;
    float d  = (float)degI[i] + 1.0f;
    float di = rsqrtf(d);
    dinv[i]   = di;
    selfco[i] = di * di * tanhf(al[i] + ar[i]);
    keep[i] = 0; nmap[i] = 0;
}

// ---------------- fill CSR ----------------
__global__ void k_fill(const int* __restrict__ src, const int* __restrict__ dst,
                       const unsigned char* __restrict__ em,
                       const float* __restrict__ dinv, const float* __restrict__ al,
                       const float* __restrict__ ar,
                       int* __restrict__ cursor, int2* __restrict__ edges) {
    int e = blockIdx.x * 256 + threadIdx.x;
    if (e >= NEDGE) return;
    if (em && !em[e]) return;
    int s = src[e], d = dst[e];
    float cf = dinv[s] * dinv[d] * tanhf(al[d] + ar[s]);
    int pos = atomicAdd(&cursor[d], 1);
    edges[pos] = make_int2(s, __float_as_int(cf));
}

// ---------------- CSR gather messages (bf16) + per-block pool partial ----------
__global__ void __launch_bounds__(256) k_msg_csr(
        const int* __restrict__ rowptr, const int* __restrict__ degI,
        const int2* __restrict__ edges,
        const ushort_t* __restrict__ cur, const ushort_t* __restrict__ xb,
        const int* __restrict__ oidx, const float* __restrict__ selfco,
        ushort_t* __restrict__ h, float* __restrict__ pb, int npg) {
    __shared__ float pm[8 * 128];
    int g    = blockIdx.x & 7;
    int ib   = blockIdx.x >> 3;
    int sub  = threadIdx.x >> 5;
    int lane = threadIdx.x & 31;
    int v = g * npg + ib * 8 + sub;
    int rs = rowptr[v], deg = degI[v];
    float a0 = 0.0f, a1 = 0.0f, a2 = 0.0f, a3 = 0.0f;
    for (int j0 = 0; j0 < deg; j0 += 32) {
        int cnt = deg - j0; if (cnt > 32) cnt = 32;
        int2 er = make_int2(0, 0);
        if (lane < cnt) er = edges[rs + j0 + lane];
        for (int j = 0; j < cnt; j++) {
            int sidx = __shfl(er.x, j, 32);
            float cf = __int_as_float(__shfl(er.y, j, 32));
            uint2 w = ((const uint2*)(cur + (size_t)sidx * C))[lane];
            a0 += cf * bflo(w.x); a1 += cf * bfhi(w.x);
            a2 += cf * bflo(w.y); a3 += cf * bfhi(w.y);
        }
    }
    int o = oidx ? oidx[v] : v;
    uint2 cw = ((const uint2*)(cur + (size_t)v * C))[lane];
    uint2 xw = ((const uint2*)(xb  + (size_t)o * C))[lane];
    float sc = selfco[v];
    float r0 = fmaxf(a0 + sc * bflo(cw.x) + EPS_FA * bflo(xw.x), 0.0f);
    float r1 = fmaxf(a1 + sc * bfhi(cw.x) + EPS_FA * bfhi(xw.x), 0.0f);
    float r2 = fmaxf(a2 + sc * bflo(cw.y) + EPS_FA * bflo(xw.y), 0.0f);
    float r3 = fmaxf(a3 + sc * bfhi(cw.y) + EPS_FA * bfhi(xw.y), 0.0f);
    uint2 hw; hw.x = pack2bf(r0, r1); hw.y = pack2bf(r2, r3);
    ((uint2*)(h + (size_t)v * C))[lane] = hw;
    float4 rr = make_float4(r0, r1, r2, r3);
    ((float4*)(pm + sub * 128))[lane] = rr;
    __syncthreads();
    int t = threadIdx.x;
    if (t < 128) {
        float m = pm[t];
        for (int s = 1; s < 8; s++) m = fmaxf(m, pm[s * 128 + t]);
        pb[(size_t)blockIdx.x * 128 + t] = m;
    }
}

__global__ void k_poolred(const float* __restrict__ pb, float* __restrict__ pooled,
                          int rowsPerGraph, int layer) {
    int g = blockIdx.x, ch = blockIdx.y, t = threadIdx.x;
    int R = rowsPerGraph / gridDim.y;
    float m = 0.0f;
    for (int r = ch * R; r < (ch + 1) * R; r++)
        m = fmaxf(m, pb[(size_t)(g + 8 * r) * 128 + t]);
    atomicMax((unsigned int*)&pooled[g * 384 + layer * 128 + t], __float_as_uint(m));
}

// ---------------- parallel exact stable top-k ----------------
__global__ void __launch_bounds__(256) k_hist(const int* __restrict__ score, int npg, int nb,
                                              int* __restrict__ blockhist) {
    __shared__ int lh[SMAX];
    int g = blockIdx.x / nb, b = blockIdx.x % nb, t = threadIdx.x;
    for (int s = t; s < SMAX; s += 256) lh[s] = 0;
    __syncthreads();
    int s = score[g * npg + b * 256 + t];
    if (s > SMAX - 1) s = SMAX - 1;
    atomicAdd(&lh[s], 1);
    __syncthreads();
    int* outp = blockhist + ((size_t)g * nb + b) * SMAX;
    for (int i = t; i < SMAX; i += 256) outp[i] = lh[i];
}

__global__ void __launch_bounds__(256) k_binprefix(int* __restrict__ blockhist,
                                                   int* __restrict__ hist, int nb) {
    __shared__ int tile[64 * 256];
    int g = blockIdx.x >> 3, ch = blockIdx.x & 7, t = threadIdx.x;
    int s0 = ch * 256;
    int* bg = blockhist + (size_t)g * nb * SMAX + s0;
    for (int b = 0; b < nb; b++) tile[b * 256 + t] = bg[(size_t)b * SMAX + t];
    __syncthreads();
    int acc = 0;
    for (int b = 0; b < nb; b++) {
        int v = tile[b * 256 + t];
        tile[b * 256 + t] = acc;
        acc += v;
    }
    __syncthreads();
    for (int b = 0; b < nb; b++) bg[(size_t)b * SMAX + t] = tile[b * 256 + t];
    hist[g * SMAX + s0 + t] = acc;
}

__global__ void __launch_bounds__(256) k_rank(const int* __restrict__ score,
                                              const int* __restrict__ blockhist,
                                              const int* __restrict__ hist,
                                              int npg, int nb, int k,
                                              unsigned char* __restrict__ keep,
                                              int* __restrict__ nmap, int* __restrict__ perm) {
    __shared__ int bp[SMAX];
    __shared__ int part[256];
    __shared__ int cs[256];
    int g = blockIdx.x / nb, b = blockIdx.x % nb, t = threadIdx.x;
    const int* hg = hist + g * SMAX;
    int v[8]; int sm = 0;
    for (int i = 0; i < 8; i++) { v[i] = hg[SMAX - 1 - (t * 8 + i)]; sm += v[i]; }
    part[t] = sm; __syncthreads();
    for (int o = 1; o < 256; o <<= 1) {
        int val = part[t];
        int add = (t >= o) ? part[t - o] : 0;
        __syncthreads();
        part[t] = val + add;
        __syncthreads();
    }
    int run = (t == 0) ? 0 : part[t - 1];
    for (int i = 0; i < 8; i++) { bp[SMAX - 1 - (t * 8 + i)] = run; run += v[i]; }
    int vv = b * 256 + t;
    int s = score[g * npg + vv];
    if (s > SMAX - 1) s = SMAX - 1;
    cs[t] = s;
    __syncthreads();
    int cnt = 0;
    for (int u = 0; u < t; u++) cnt += (cs[u] == s);
    int pos = bp[s] + blockhist[((size_t)g * nb + b) * SMAX + s] + cnt;
    if (pos < k) {
        int vg = g * npg + vv;
        int nid = g * k + pos;
        keep[vg] = 1; nmap[vg] = nid; perm[nid] = vg;
    }
}

// ---------------- gather kept nodes (bf16) + next-layer al/ar ----------------
__global__ void k_gather_alar(const ushort_t* __restrict__ h, const int* __restrict__ perm,
                              const int* __restrict__ oidx,
                              const float* __restrict__ attlN, const float* __restrict__ attrN,
                              ushort_t* __restrict__ curN, int* __restrict__ oidxN,
                              float* __restrict__ al, float* __restrict__ ar, int m) {
    int i = blockIdx.x * 256 + threadIdx.x;
    if (i >= m * 32) return;
    int j = i >> 5, c4 = i & 31;
    int p = perm[j];
    uint2 w = ((const uint2*)(h + (size_t)p * C))[c4];
    ((uint2*)(curN + (size_t)j * C))[c4] = w;
    float f0 = bflo(w.x), f1 = bfhi(w.x), f2 = bflo(w.y), f3 = bfhi(w.y);
    float4 l4 = ((const float4*)attlN)[c4];
    float4 r4 = ((const float4*)attrN)[c4];
    float sl = f0 * l4.x + f1 * l4.y + f2 * l4.z + f3 * l4.w;
    float sr = f0 * r4.x + f1 * r4.y + f2 * r4.z + f3 * r4.w;
    for (int o = 16; o >= 1; o >>= 1) { sl += __shfl_xor(sl, o); sr += __shfl_xor(sr, o); }
    if (c4 == 0) {
        al[j] = sl; ar[j] = sr;
        oidxN[j] = oidx ? oidx[p] : p;
    }
}

// ---------------- remap edges + next-layer deg/score LDS histogram ----------------
__global__ void __launch_bounds__(256) k_remap_hist(
        const int* __restrict__ inS, const int* __restrict__ inD,
        const unsigned char* __restrict__ inEm,
        int* __restrict__ src, int* __restrict__ dst, unsigned char* __restrict__ em,
        const unsigned char* __restrict__ keep, const int* __restrict__ nmap,
        unsigned int* __restrict__ bh, int kN) {
    __shared__ unsigned int h[8192];
    int t = threadIdx.x;
    for (int i = t; i < kN; i += 256) h[i] = 0;
    __syncthreads();
    int base = blockIdx.x * 4096;
    int gb = (blockIdx.x >> 5) * kN;
    for (int i = t; i < 4096; i += 256) {
        int e = base + i;
        int s = inS[e], d = inD[e];
        bool ok = (!inEm || inEm[e]) && keep[s] && keep[d];
        if (ok) {
            int ns = nmap[s], nd = nmap[d];
            src[e] = ns; dst[e] = nd; em[e] = 1;
            atomicAdd(&h[nd - gb], 1u);
            atomicAdd(&h[ns - gb], 0x10000u);
        } else { src[e] = 0; dst[e] = 0; em[e] = 0; }
    }
    __syncthreads();
    unsigned int* o = bh + (size_t)blockIdx.x * kN;
    for (int i = t; i < kN; i += 256) o[i] = h[i];
}

// ---------------- GRU head, stage A: gi = w_ih @ fused + b_ih ----------------
// one wave per (g,row); grid (192, G); 4 waves/block
__global__ void __launch_bounds__(256) k_gi(const float* __restrict__ pooled,
                                            const float* __restrict__ wih,
                                            const float* __restrict__ bih,
                                            float* __restrict__ gi) {
    int g = blockIdx.y;
    int row = blockIdx.x * 4 + (threadIdx.x >> 6);
    int lane = threadIdx.x & 63;
    const float* w = wih + (size_t)row * 384;
    const float* f = pooled + g * 384;
    float s = 0.0f;
    #pragma unroll
    for (int i = 0; i < 6; i++) s += w[i * 64 + lane] * f[i * 64 + lane];
    for (int o = 32; o >= 1; o >>= 1) s += __shfl_xor(s, o);
    if (lane == 0) gi[g * 768 + row] = s + bih[row];
}

// ---------------- GRU head, stage B: pointwise GRU + final linears ----------------
__global__ void __launch_bounds__(256) k_gru_fin(const float* __restrict__ gi,
        const float* __restrict__ bhh, const float* __restrict__ wfin,
        const float* __restrict__ bfin, const float* __restrict__ wroot,
        const float* __restrict__ broot, const float* __restrict__ rootv,
        const float* __restrict__ alphap, float* __restrict__ out) {
    int g = blockIdx.x, t = threadIdx.x;
    __shared__ float hg[256];
    {
        float r  = 1.0f / (1.0f + expf(-(gi[g * 768 + t]       + bhh[t])));
        float z  = 1.0f / (1.0f + expf(-(gi[g * 768 + 256 + t] + bhh[256 + t])));
        float nc = tanhf(gi[g * 768 + 512 + t] + r * bhh[512 + t]);
        hg[t] = (1.0f - z) * nc;
    }
    __syncthreads();
    float a = alphap[0];
    int wv = t >> 6, lane = t & 63;
    const float* rg = rootv + (size_t)g * 128;
    for (int oo = 0; oo < 32; oo++) {
        int o = wv * 32 + oo;
        const float* wf = wfin + (size_t)o * 256;
        float sf = wf[lane] * hg[lane] + wf[64 + lane] * hg[64 + lane]
                 + wf[128 + lane] * hg[128 + lane] + wf[192 + lane] * hg[192 + lane];
        const float* wr = wroot + (size_t)o * 128;
        float sr = wr[lane] * rg[lane] + wr[64 + lane] * rg[64 + lane];
        float s = a * sf + (1.0f - a) * sr;
        for (int sh = 32; sh >= 1; sh >>= 1) s += __shfl_xor(s, sh);
        if (lane == 0)
            out[g * 128 + o] = s + a * bfin[o] + (1.0f - a) * broot[o];
    }
}

extern "C" void kernel_launch(void* const* d_in, const int* in_sizes, int n_in,
                              void* d_out, int out_size, void* d_ws, size_t ws_size,
                              hipStream_t stream) {
    const float* x      = (const float*)d_in[0];
    const int*   ei     = (const int*)d_in[1];
    const float* rootv  = (const float*)d_in[3];
    const float* att_l  = (const float*)d_in[4];
    const float* att_r  = (const float*)d_in[5];
    const float* w_ih   = (const float*)d_in[6];
    const float* b_ih   = (const float*)d_in[8];
    const float* b_hh   = (const float*)d_in[9];
    const float* w_fin  = (const float*)d_in[10];
    const float* b_fin  = (const float*)d_in[11];
    const float* w_root = (const float*)d_in[12];
    const float* b_root = (const float*)d_in[13];
    const float* alphap = (const float*)d_in[14];
    float* out = (float*)d_out;

    char* wsb = (char*)d_ws;
    size_t off = 0;
    auto alloc = [&](size_t bytes) -> char* {
        char* p = wsb + off; off += (bytes + 255) & ~(size_t)255; return p;
    };
    ushort_t* xb   = (ushort_t*)alloc((size_t)131072 * C * 2);
    ushort_t* bufH = (ushort_t*)alloc((size_t)131072 * C * 2);
    ushort_t* bufC = (ushort_t*)alloc((size_t)65536  * C * 2);
    int*   srcA   = (int*)alloc((size_t)NEDGE * 4);
    int*   dstA   = (int*)alloc((size_t)NEDGE * 4);
    unsigned char* emask = (unsigned char*)alloc(NEDGE);
    int2*  edges  = (int2*)alloc((size_t)NEDGE * 8);
    float* al     = (float*)alloc(131072 * 4);
    float* ar     = (float*)alloc(131072 * 4);
    float* dinv   = (float*)alloc(131072 * 4);
    float* selfco = (float*)alloc(131072 * 4);
    int*   degI   = (int*)alloc(131072 * 4);
    int*   score  = (int*)alloc(131072 * 4);
    int*   rowptr = (int*)alloc(131072 * 4);
    int*   cursor = (int*)alloc(131072 * 4);
    int*   bsum   = (int*)alloc(256 * 4);
    unsigned char* keep = (unsigned char*)alloc(131072);
    int*   nmap   = (int*)alloc(131072 * 4);
    int*   perm   = (int*)alloc(65536 * 4);
    int*   oidxA  = (int*)alloc(65536 * 4);
    int*   oidxB  = (int*)alloc(32768 * 4);
    float* pooled = (float*)alloc(G * 384 * 4);
    float* giBuf  = (float*)alloc(G * 768 * 4);
    int*   blockhist = (int*)alloc((size_t)G * 64 * SMAX * 4);
    int*   histT  = (int*)alloc((size_t)G * SMAX * 4);
    unsigned int* bh = (unsigned int*)alloc((size_t)128 * N0 * 4);
    float* pb = (float*)bh;

    k_zero_pooled<<<12, 256, 0, stream>>>(pooled);
    k_hist0<<<128, 256, 0, stream>>>(ei, bh);
    k_sumdeg<<<131072 / 256, 256, 0, stream>>>(bh, degI, score, 14, 16, 131072);

    const int ns[3]   = {131072, 65536, 32768};
    const int npgs[3] = {16384, 8192, 4096};
    const int ks[3]   = {8192, 4096, 0};
    const int shifts[3] = {14, 13, 12};

    for (int l = 0; l < 3; l++) {
        int n = ns[l], npg = npgs[l], k = ks[l];
        const ushort_t* cur = (l == 0) ? xb : bufC;
        const int* oidx = (l == 0) ? nullptr : (l == 1 ? oidxA : oidxB);
        int* oidxN = (l == 0) ? oidxA : oidxB;
        const int* eS = (l == 0) ? ei : srcA;
        const int* eD = (l == 0) ? ei + NEDGE : dstA;
        const unsigned char* eM = (l == 0) ? nullptr : emask;

        if (l == 0)
            k_alar<<<n / 4, 256, 0, stream>>>(x, att_l, att_r, al, ar, xb, n);

        int nblk = n / 2048;
        k_scan1<<<nblk, 256, 0, stream>>>(degI, rowptr, bsum);
        k_scan3s<<<n / 256, 256, 0, stream>>>(rowptr, cursor, bsum, degI, al, ar,
                                              dinv, selfco, keep, nmap, n);

        k_fill<<<(NEDGE + 255) / 256, 256, 0, stream>>>(eS, eD, eM, dinv, al, ar,
                                                        cursor, edges);
        k_msg_csr<<<n / 8, 256, 0, stream>>>(rowptr, degI, edges, cur, xb, oidx,
                                             selfco, bufH, pb, npg);
        k_poolred<<<dim3(G, 8), 128, 0, stream>>>(pb, pooled, n / 64, l);

        if (l < 2) {
            int nb = npg / 256;
            k_hist<<<G * nb, 256, 0, stream>>>(score, npg, nb, blockhist);
            k_binprefix<<<G * 8, 256, 0, stream>>>(blockhist, histT, nb);
            k_rank<<<G * nb, 256, 0, stream>>>(score, blockhist, histT, npg, nb, k,
                                               keep, nmap, perm);
            int m = G * k;
            k_gather_alar<<<(m * 32 + 255) / 256, 256, 0, stream>>>(
                bufH, perm, oidx, att_l + (l + 1) * C, att_r + (l + 1) * C,
                bufC, oidxN, al, ar, m);
            k_remap_hist<<<256, 256, 0, stream>>>(eS, eD, eM, srcA, dstA, emask,
                                                  keep, nmap, bh, k);
            k_sumdeg<<<(G * k + 255) / 256, 256, 0, stream>>>(bh, degI, score,
                                                              shifts[l + 1], 32, G * k);
        }
    }

    k_gi<<<dim3(192, G), 256, 0, stream>>>(pooled, w_ih, b_ih, giBuf);
    k_gru_fin<<<G, 256, 0, stream>>>(giBuf, b_hh, w_fin, b_fin, w_root, b_root,
                                     rootv, alphap, out);
}

// Round 9
// 538.658 us; speedup vs baseline: 1.4450x; 1.0459x over previous
//
#include <hip/hip_runtime.h>
#include <math.h>

#define G 8
#define N0 16384
#define NEDGE (G*N0*8)      // 1048576
#define C 128
#define EPS_FA 0.1f
#define SMAX 2048

typedef unsigned short ushort_t;
typedef unsigned int uint_t;

__device__ inline ushort_t f2bf(float f) {
    uint_t u = __float_as_uint(f);
    uint_t r = (u + 0x7FFFu + ((u >> 16) & 1u)) >> 16;
    return (ushort_t)r;
}
__device__ inline uint_t pack2bf(float a, float b) {
    return (uint_t)f2bf(a) | ((uint_t)f2bf(b) << 16);
}
__device__ inline float bflo(uint_t w) { return __uint_as_float(w << 16); }
__device__ inline float bfhi(uint_t w) { return __uint_as_float(w & 0xFFFF0000u); }

// ---------------- layer-0 deg/score via LDS histogram ----------------
__global__ void __launch_bounds__(256) k_hist0(const int* __restrict__ ei,
                                               unsigned int* __restrict__ bh) {
    __shared__ unsigned int h[N0];
    int t = threadIdx.x;
    for (int i = t; i < N0; i += 256) h[i] = 0;
    __syncthreads();
    int base = blockIdx.x * 8192;
    int gbase = (blockIdx.x >> 4) * N0;
    for (int i = t; i < 8192; i += 256) {
        int s = ei[base + i] - gbase;
        int d = ei[NEDGE + base + i] - gbase;
        atomicAdd(&h[d], 1u);
        atomicAdd(&h[s], 0x10000u);
    }
    __syncthreads();
    unsigned int* o = bh + (size_t)blockIdx.x * N0;
    for (int i = t; i < N0; i += 256) o[i] = h[i];
}

// sum nsub per-graph block-histograms -> degI, score; optionally zero pooled
__global__ void k_sumdeg(const unsigned int* __restrict__ bh, int* __restrict__ degI,
                         int* __restrict__ score, int shift, int nsub, int n,
                         float* __restrict__ pooled) {
    int i = blockIdx.x * 256 + threadIdx.x;
    if (pooled && i < G * 384) pooled[i] = 0.0f;
    if (i >= n) return;
    int bins = 1 << shift;
    int g = i >> shift, u = i & (bins - 1);
    const unsigned int* p = bh + ((size_t)(g * nsub) << shift) + u;
    int ad = 0, as = 0;
    for (int b = 0; b < nsub; b++) {
        unsigned int w = p[(size_t)b * bins];
        ad += (int)(w & 0xFFFFu); as += (int)(w >> 16);
    }
    degI[i] = ad; score[i] = as;
}

// ---------------- layer-0 attention dots + x -> bf16 conversion ----------------
__global__ void k_alar(const float* __restrict__ x,
                       const float* __restrict__ attl, const float* __restrict__ attr,
                       float* __restrict__ al, float* __restrict__ ar,
                       ushort_t* __restrict__ xb, int n) {
    int wid  = (blockIdx.x * blockDim.x + threadIdx.x) >> 6;
    int lane = threadIdx.x & 63;
    if (wid >= n) return;
    float2 v  = ((const float2*)(x + (size_t)wid * C))[lane];
    ((uint_t*)(xb + (size_t)wid * C))[lane] = pack2bf(v.x, v.y);
    float2 l2 = ((const float2*)attl)[lane];
    float2 r2 = ((const float2*)attr)[lane];
    float sl = v.x * l2.x + v.y * l2.y;
    float sr = v.x * r2.x + v.y * r2.y;
    for (int o = 32; o >= 1; o >>= 1) { sl += __shfl_xor(sl, o); sr += __shfl_xor(sr, o); }
    if (lane == 0) { al[wid] = sl; ar[wid] = sr; }
}

// ---------------- prefix scan ----------------
__global__ void __launch_bounds__(256) k_scan1(const int* __restrict__ degI,
                                               int* __restrict__ rowptr,
                                               int* __restrict__ bsum) {
    __shared__ int part[256];
    int t = threadIdx.x;
    int base = blockIdx.x * 2048 + t * 8;
    int v[8]; int s = 0;
    for (int i = 0; i < 8; i++) { v[i] = degI[base + i]; s += v[i]; }
    part[t] = s; __syncthreads();
    for (int o = 1; o < 256; o <<= 1) {
        int val = part[t];
        int add = (t >= o) ? part[t - o] : 0;
        __syncthreads();
        part[t] = val + add;
        __syncthreads();
    }
    int run = (t == 0) ? 0 : part[t - 1];
    if (t == 255) bsum[blockIdx.x] = part[255];
    for (int i = 0; i < 8; i++) { rowptr[base + i] = run; run += v[i]; }
}

__global__ void k_scan3s(int* __restrict__ rowptr, int* __restrict__ cursor,
                         const int* __restrict__ bsum, const int* __restrict__ degI,
                         const float* __restrict__ al, const float* __restrict__ ar,
                         float* __restrict__ dinv, float* __restrict__ selfco,
                         unsigned char* __restrict__ keep, int* __restrict__ nmap, int n) {
    __shared__ int base_s;
    int t = threadIdx.x;
    if (t < 64) {
        int c = blockIdx.x >> 3;
        int vv = (t < c) ? bsum[t] : 0;
        for (int o = 32; o >= 1; o >>= 1) vv += __shfl_xor(vv, o);
        if (t == 0) base_s = vv;
    }
    __syncthreads();
    int i = blockIdx.x * 256 + t;
    if (i >= n) return;
    int v = rowptr[i] + base_s;
    rowptr[i] = v; cursor[i] = v;
    float d  = (float)degI[i] + 1.0f;
    float di = rsqrtf(d);
    dinv[i]   = di;
    selfco[i] = di * di * tanhf(al[i] + ar[i]);
    keep[i] = 0; nmap[i] = 0;
}

// ---------------- fill CSR ----------------
__global__ void k_fill(const int* __restrict__ src, const int* __restrict__ dst,
                       const unsigned char* __restrict__ em,
                       const float* __restrict__ dinv, const float* __restrict__ al,
                       const float* __restrict__ ar,
                       int* __restrict__ cursor, int2* __restrict__ edges) {
    int e = blockIdx.x * 256 + threadIdx.x;
    if (e >= NEDGE) return;
    if (em && !em[e]) return;
    int s = src[e], d = dst[e];
    float cf = dinv[s] * dinv[d] * tanhf(al[d] + ar[s]);
    int pos = atomicAdd(&cursor[d], 1);
    edges[pos] = make_int2(s, __float_as_int(cf));
}

// ---------------- CSR gather messages (bf16, depth-4 prefetch) + pool partial ----
#define ACC4(W, CF) { a0 += (CF) * bflo((W).x); a1 += (CF) * bfhi((W).x); \
                      a2 += (CF) * bflo((W).y); a3 += (CF) * bfhi((W).y); }
__global__ void __launch_bounds__(256) k_msg_csr(
        const int* __restrict__ rowptr, const int* __restrict__ degI,
        const int2* __restrict__ edges,
        const ushort_t* __restrict__ cur, const ushort_t* __restrict__ xb,
        const int* __restrict__ oidx, const float* __restrict__ selfco,
        ushort_t* __restrict__ h, float* __restrict__ pb, int npg) {
    __shared__ float pm[8 * 128];
    int g    = blockIdx.x & 7;
    int ib   = blockIdx.x >> 3;
    int sub  = threadIdx.x >> 5;
    int lane = threadIdx.x & 31;
    int v = g * npg + ib * 8 + sub;
    int rs = rowptr[v], deg = degI[v];
    // hoisted self-loop / x0 loads (overlap with edge gathers)
    int o = oidx ? oidx[v] : v;
    uint2 cw = ((const uint2*)(cur + (size_t)v * C))[lane];
    uint2 xw = ((const uint2*)(xb  + (size_t)o * C))[lane];
    float sc = selfco[v];
    float a0 = 0.0f, a1 = 0.0f, a2 = 0.0f, a3 = 0.0f;
    for (int j0 = 0; j0 < deg; j0 += 32) {
        int cnt = deg - j0; if (cnt > 32) cnt = 32;
        int2 er = make_int2(0, 0);
        if (lane < cnt) er = edges[rs + j0 + lane];
        uint2 w0 = make_uint2(0,0), w1 = w0, w2 = w0, w3 = w0;
        {
            int s0 = __shfl(er.x, 0, 32);
            if (0 < cnt) w0 = ((const uint2*)(cur + (size_t)s0 * C))[lane];
            int s1 = __shfl(er.x, 1, 32);
            if (1 < cnt) w1 = ((const uint2*)(cur + (size_t)s1 * C))[lane];
            int s2 = __shfl(er.x, 2, 32);
            if (2 < cnt) w2 = ((const uint2*)(cur + (size_t)s2 * C))[lane];
            int s3 = __shfl(er.x, 3, 32);
            if (3 < cnt) w3 = ((const uint2*)(cur + (size_t)s3 * C))[lane];
        }
        int j = 0;
        for (; j + 4 <= cnt; j += 4) {
            float cf0 = __int_as_float(__shfl(er.y, j, 32));
            ACC4(w0, cf0);
            int sn0 = __shfl(er.x, j + 4, 32);
            if (j + 4 < cnt) w0 = ((const uint2*)(cur + (size_t)sn0 * C))[lane];
            float cf1 = __int_as_float(__shfl(er.y, j + 1, 32));
            ACC4(w1, cf1);
            int sn1 = __shfl(er.x, j + 5, 32);
            if (j + 5 < cnt) w1 = ((const uint2*)(cur + (size_t)sn1 * C))[lane];
            float cf2 = __int_as_float(__shfl(er.y, j + 2, 32));
            ACC4(w2, cf2);
            int sn2 = __shfl(er.x, j + 6, 32);
            if (j + 6 < cnt) w2 = ((const uint2*)(cur + (size_t)sn2 * C))[lane];
            float cf3 = __int_as_float(__shfl(er.y, j + 3, 32));
            ACC4(w3, cf3);
            int sn3 = __shfl(er.x, j + 7, 32);
            if (j + 7 < cnt) w3 = ((const uint2*)(cur + (size_t)sn3 * C))[lane];
        }
        // tail (next to consume is always w0,w1,w2 since j % 4 == 0)
        if (j < cnt)     { float cf = __int_as_float(__shfl(er.y, j,     32)); ACC4(w0, cf); }
        if (j + 1 < cnt) { float cf = __int_as_float(__shfl(er.y, j + 1, 32)); ACC4(w1, cf); }
        if (j + 2 < cnt) { float cf = __int_as_float(__shfl(er.y, j + 2, 32)); ACC4(w2, cf); }
    }
    float r0 = fmaxf(a0 + sc * bflo(cw.x) + EPS_FA * bflo(xw.x), 0.0f);
    float r1 = fmaxf(a1 + sc * bfhi(cw.x) + EPS_FA * bfhi(xw.x), 0.0f);
    float r2 = fmaxf(a2 + sc * bflo(cw.y) + EPS_FA * bflo(xw.y), 0.0f);
    float r3 = fmaxf(a3 + sc * bfhi(cw.y) + EPS_FA * bfhi(xw.y), 0.0f);
    uint2 hw; hw.x = pack2bf(r0, r1); hw.y = pack2bf(r2, r3);
    ((uint2*)(h + (size_t)v * C))[lane] = hw;
    float4 rr = make_float4(r0, r1, r2, r3);
    ((float4*)(pm + sub * 128))[lane] = rr;
    __syncthreads();
    int t = threadIdx.x;
    if (t < 128) {
        float m = pm[t];
        for (int s = 1; s < 8; s++) m = fmaxf(m, pm[s * 128 + t]);
        pb[(size_t)blockIdx.x * 128 + t] = m;
    }
}

__global__ void k_poolred(const float* __restrict__ pb, float* __restrict__ pooled,
                          int rowsPerGraph, int layer) {
    int g = blockIdx.x, ch = blockIdx.y, t = threadIdx.x;
    int R = rowsPerGraph / gridDim.y;
    float m = 0.0f;
    for (int r = ch * R; r < (ch + 1) * R; r++)
        m = fmaxf(m, pb[(size_t)(g + 8 * r) * 128 + t]);
    atomicMax((unsigned int*)&pooled[g * 384 + layer * 128 + t], __float_as_uint(m));
}

// ---------------- parallel exact stable top-k ----------------
__global__ void __launch_bounds__(256) k_hist(const int* __restrict__ score, int npg, int nb,
                                              int* __restrict__ blockhist) {
    __shared__ int lh[SMAX];
    int g = blockIdx.x / nb, b = blockIdx.x % nb, t = threadIdx.x;
    for (int s = t; s < SMAX; s += 256) lh[s] = 0;
    __syncthreads();
    int s = score[g * npg + b * 256 + t];
    if (s > SMAX - 1) s = SMAX - 1;
    atomicAdd(&lh[s], 1);
    __syncthreads();
    int* outp = blockhist + ((size_t)g * nb + b) * SMAX;
    for (int i = t; i < SMAX; i += 256) outp[i] = lh[i];
}

__global__ void __launch_bounds__(256) k_binprefix(int* __restrict__ blockhist,
                                                   int* __restrict__ hist, int nb) {
    __shared__ int tile[64 * 256];
    int g = blockIdx.x >> 3, ch = blockIdx.x & 7, t = threadIdx.x;
    int s0 = ch * 256;
    int* bg = blockhist + (size_t)g * nb * SMAX + s0;
    for (int b = 0; b < nb; b++) tile[b * 256 + t] = bg[(size_t)b * SMAX + t];
    __syncthreads();
    int acc = 0;
    for (int b = 0; b < nb; b++) {
        int v = tile[b * 256 + t];
        tile[b * 256 + t] = acc;
        acc += v;
    }
    __syncthreads();
    for (int b = 0; b < nb; b++) bg[(size_t)b * SMAX + t] = tile[b * 256 + t];
    hist[g * SMAX + s0 + t] = acc;
}

__global__ void __launch_bounds__(256) k_rank(const int* __restrict__ score,
                                              const int* __restrict__ blockhist,
                                              const int* __restrict__ hist,
                                              int npg, int nb, int k,
                                              unsigned char* __restrict__ keep,
                                              int* __restrict__ nmap, int* __restrict__ perm) {
    __shared__ int bp[SMAX];
    __shared__ int part[256];
    __shared__ int cs[256];
    int g = blockIdx.x / nb, b = blockIdx.x % nb, t = threadIdx.x;
    const int* hg = hist + g * SMAX;
    int v[8]; int sm = 0;
    for (int i = 0; i < 8; i++) { v[i] = hg[SMAX - 1 - (t * 8 + i)]; sm += v[i]; }
    part[t] = sm; __syncthreads();
    for (int o = 1; o < 256; o <<= 1) {
        int val = part[t];
        int add = (t >= o) ? part[t - o] : 0;
        __syncthreads();
        part[t] = val + add;
        __syncthreads();
    }
    int run = (t == 0) ? 0 : part[t - 1];
    for (int i = 0; i < 8; i++) { bp[SMAX - 1 - (t * 8 + i)] = run; run += v[i]; }
    int vv = b * 256 + t;
    int s = score[g * npg + vv];
    if (s > SMAX - 1) s = SMAX - 1;
    cs[t] = s;
    __syncthreads();
    int cnt = 0;
    for (int u = 0; u < t; u++) cnt += (cs[u] == s);
    int pos = bp[s] + blockhist[((size_t)g * nb + b) * SMAX + s] + cnt;
    if (pos < k) {
        int vg = g * npg + vv;
        int nid = g * k + pos;
        keep[vg] = 1; nmap[vg] = nid; perm[nid] = vg;
    }
}

// ---------------- gather kept nodes (bf16) + next-layer al/ar ----------------
__global__ void k_gather_alar(const ushort_t* __restrict__ h, const int* __restrict__ perm,
                              const int* __restrict__ oidx,
                              const float* __restrict__ attlN, const float* __restrict__ attrN,
                              ushort_t* __restrict__ curN, int* __restrict__ oidxN,
                              float* __restrict__ al, float* __restrict__ ar, int m) {
    int i = blockIdx.x * 256 + threadIdx.x;
    if (i >= m * 32) return;
    int j = i >> 5, c4 = i & 31;
    int p = perm[j];
    uint2 w = ((const uint2*)(h + (size_t)p * C))[c4];
    ((uint2*)(curN + (size_t)j * C))[c4] = w;
    float f0 = bflo(w.x), f1 = bfhi(w.x), f2 = bflo(w.y), f3 = bfhi(w.y);
    float4 l4 = ((const float4*)attlN)[c4];
    float4 r4 = ((const float4*)attrN)[c4];
    float sl = f0 * l4.x + f1 * l4.y + f2 * l4.z + f3 * l4.w;
    float sr = f0 * r4.x + f1 * r4.y + f2 * r4.z + f3 * r4.w;
    for (int o = 16; o >= 1; o >>= 1) { sl += __shfl_xor(sl, o); sr += __shfl_xor(sr, o); }
    if (c4 == 0) {
        al[j] = sl; ar[j] = sr;
        oidxN[j] = oidx ? oidx[p] : p;
    }
}

// ---------------- remap edges + next-layer deg/score LDS histogram ----------------
__global__ void __launch_bounds__(256) k_remap_hist(
        const int* __restrict__ inS, const int* __restrict__ inD,
        const unsigned char* __restrict__ inEm,
        int* __restrict__ src, int* __restrict__ dst, unsigned char* __restrict__ em,
        const unsigned char* __restrict__ keep, const int* __restrict__ nmap,
        unsigned int* __restrict__ bh, int kN) {
    __shared__ unsigned int h[8192];
    int t = threadIdx.x;
    for (int i = t; i < kN; i += 256) h[i] = 0;
    __syncthreads();
    int base = blockIdx.x * 4096;
    int gb = (blockIdx.x >> 5) * kN;
    for (int i = t; i < 4096; i += 256) {
        int e = base + i;
        int s = inS[e], d = inD[e];
        bool ok = (!inEm || inEm[e]) && keep[s] && keep[d];
        if (ok) {
            int ns = nmap[s], nd = nmap[d];
            src[e] = ns; dst[e] = nd; em[e] = 1;
            atomicAdd(&h[nd - gb], 1u);
            atomicAdd(&h[ns - gb], 0x10000u);
        } else { src[e] = 0; dst[e] = 0; em[e] = 0; }
    }
    __syncthreads();
    unsigned int* o = bh + (size_t)blockIdx.x * kN;
    for (int i = t; i < kN; i += 256) o[i] = h[i];
}

// ---------------- GRU head, stage A ----------------
__global__ void __launch_bounds__(256) k_gi(const float* __restrict__ pooled,
                                            const float* __restrict__ wih,
                                            const float* __restrict__ bih,
                                            float* __restrict__ gi) {
    int g = blockIdx.y;
    int row = blockIdx.x * 4 + (threadIdx.x >> 6);
    int lane = threadIdx.x & 63;
    const float* w = wih + (size_t)row * 384;
    const float* f = pooled + g * 384;
    float s = 0.0f;
    #pragma unroll
    for (int i = 0; i < 6; i++) s += w[i * 64 + lane] * f[i * 64 + lane];
    for (int o = 32; o >= 1; o >>= 1) s += __shfl_xor(s, o);
    if (lane == 0) gi[g * 768 + row] = s + bih[row];
}

// ---------------- GRU head, stage B ----------------
__global__ void __launch_bounds__(256) k_gru_fin(const float* __restrict__ gi,
        const float* __restrict__ bhh, const float* __restrict__ wfin,
        const float* __restrict__ bfin, const float* __restrict__ wroot,
        const float* __restrict__ broot, const float* __restrict__ rootv,
        const float* __restrict__ alphap, float* __restrict__ out) {
    int g = blockIdx.x, t = threadIdx.x;
    __shared__ float hg[256];
    {
        float r  = 1.0f / (1.0f + expf(-(gi[g * 768 + t]       + bhh[t])));
        float z  = 1.0f / (1.0f + expf(-(gi[g * 768 + 256 + t] + bhh[256 + t])));
        float nc = tanhf(gi[g * 768 + 512 + t] + r * bhh[512 + t]);
        hg[t] = (1.0f - z) * nc;
    }
    __syncthreads();
    float a = alphap[0];
    int wv = t >> 6, lane = t & 63;
    const float* rg = rootv + (size_t)g * 128;
    for (int oo = 0; oo < 32; oo++) {
        int o = wv * 32 + oo;
        const float* wf = wfin + (size_t)o * 256;
        float sf = wf[lane] * hg[lane] + wf[64 + lane] * hg[64 + lane]
                 + wf[128 + lane] * hg[128 + lane] + wf[192 + lane] * hg[192 + lane];
        const float* wr = wroot + (size_t)o * 128;
        float sr = wr[lane] * rg[lane] + wr[64 + lane] * rg[64 + lane];
        float s = a * sf + (1.0f - a) * sr;
        for (int sh = 32; sh >= 1; sh >>= 1) s += __shfl_xor(s, sh);
        if (lane == 0)
            out[g * 128 + o] = s + a * bfin[o] + (1.0f - a) * broot[o];
    }
}

extern "C" void kernel_launch(void* const* d_in, const int* in_sizes, int n_in,
                              void* d_out, int out_size, void* d_ws, size_t ws_size,
                              hipStream_t stream) {
    const float* x      = (const float*)d_in[0];
    const int*   ei     = (const int*)d_in[1];
    const float* rootv  = (const float*)d_in[3];
    const float* att_l  = (const float*)d_in[4];
    const float* att_r  = (const float*)d_in[5];
    const float* w_ih   = (const float*)d_in[6];
    const float* b_ih   = (const float*)d_in[8];
    const float* b_hh   = (const float*)d_in[9];
    const float* w_fin  = (const float*)d_in[10];
    const float* b_fin  = (const float*)d_in[11];
    const float* w_root = (const float*)d_in[12];
    const float* b_root = (const float*)d_in[13];
    const float* alphap = (const float*)d_in[14];
    float* out = (float*)d_out;

    char* wsb = (char*)d_ws;
    size_t off = 0;
    auto alloc = [&](size_t bytes) -> char* {
        char* p = wsb + off; off += (bytes + 255) & ~(size_t)255; return p;
    };
    ushort_t* xb   = (ushort_t*)alloc((size_t)131072 * C * 2);
    ushort_t* bufH = (ushort_t*)alloc((size_t)131072 * C * 2);
    ushort_t* bufC = (ushort_t*)alloc((size_t)65536  * C * 2);
    int*   srcA   = (int*)alloc((size_t)NEDGE * 4);
    int*   dstA   = (int*)alloc((size_t)NEDGE * 4);
    unsigned char* emask = (unsigned char*)alloc(NEDGE);
    int2*  edges  = (int2*)alloc((size_t)NEDGE * 8);
    float* al     = (float*)alloc(131072 * 4);
    float* ar     = (float*)alloc(131072 * 4);
    float* dinv   = (float*)alloc(131072 * 4);
    float* selfco = (float*)alloc(131072 * 4);
    int*   degI   = (int*)alloc(131072 * 4);
    int*   score  = (int*)alloc(131072 * 4);
    int*   rowptr = (int*)alloc(131072 * 4);
    int*   cursor = (int*)alloc(131072 * 4);
    int*   bsum   = (int*)alloc(256 * 4);
    unsigned char* keep = (unsigned char*)alloc(131072);
    int*   nmap   = (int*)alloc(131072 * 4);
    int*   perm   = (int*)alloc(65536 * 4);
    int*   oidxA  = (int*)alloc(65536 * 4);
    int*   oidxB  = (int*)alloc(32768 * 4);
    float* pooled = (float*)alloc(G * 384 * 4);
    float* giBuf  = (float*)alloc(G * 768 * 4);
    int*   blockhist = (int*)alloc((size_t)G * 64 * SMAX * 4);
    int*   histT  = (int*)alloc((size_t)G * SMAX * 4);
    unsigned int* bh = (unsigned int*)alloc((size_t)128 * N0 * 4);
    float* pb = (float*)bh;

    k_hist0<<<128, 256, 0, stream>>>(ei, bh);
    k_sumdeg<<<131072 / 256, 256, 0, stream>>>(bh, degI, score, 14, 16, 131072, pooled);

    const int ns[3]   = {131072, 65536, 32768};
    const int npgs[3] = {16384, 8192, 4096};
    const int ks[3]   = {8192, 4096, 0};
    const int shifts[3] = {14, 13, 12};

    for (int l = 0; l < 3; l++) {
        int n = ns[l], npg = npgs[l], k = ks[l];
        const ushort_t* cur = (l == 0) ? xb : bufC;
        const int* oidx = (l == 0) ? nullptr : (l == 1 ? oidxA : oidxB);
        int* oidxN = (l == 0) ? oidxA : oidxB;
        const int* eS = (l == 0) ? ei : srcA;
        const int* eD = (l == 0) ? ei + NEDGE : dstA;
        const unsigned char* eM = (l == 0) ? nullptr : emask;

        if (l == 0)
            k_alar<<<n / 4, 256, 0, stream>>>(x, att_l, att_r, al, ar, xb, n);

        int nblk = n / 2048;
        k_scan1<<<nblk, 256, 0, stream>>>(degI, rowptr, bsum);
        k_scan3s<<<n / 256, 256, 0, stream>>>(rowptr, cursor, bsum, degI, al, ar,
                                              dinv, selfco, keep, nmap, n);

        k_fill<<<(NEDGE + 255) / 256, 256, 0, stream>>>(eS, eD, eM, dinv, al, ar,
                                                        cursor, edges);
        k_msg_csr<<<n / 8, 256, 0, stream>>>(rowptr, degI, edges, cur, xb, oidx,
                                             selfco, bufH, pb, npg);
        k_poolred<<<dim3(G, 8), 128, 0, stream>>>(pb, pooled, n / 64, l);

        if (l < 2) {
            int nb = npg / 256;
            k_hist<<<G * nb, 256, 0, stream>>>(score, npg, nb, blockhist);
            k_binprefix<<<G * 8, 256, 0, stream>>>(blockhist, histT, nb);
            k_rank<<<G * nb, 256, 0, stream>>>(score, blockhist, histT, npg, nb, k,
                                               keep, nmap, perm);
            int m = G * k;
            k_gather_alar<<<(m * 32 + 255) / 256, 256, 0, stream>>>(
                bufH, perm, oidx, att_l + (l + 1) * C, att_r + (l + 1) * C,
                bufC, oidxN, al, ar, m);
            k_remap_hist<<<256, 256, 0, stream>>>(eS, eD, eM, srcA, dstA, emask,
                                                  keep, nmap, bh, k);
            k_sumdeg<<<(G * k + 255) / 256, 256, 0, stream>>>(bh, degI, score,
                                                              shifts[l + 1], 32, G * k,
                                                              nullptr);
        }
    }

    k_gi<<<dim3(192, G), 256, 0, stream>>>(pooled, w_ih, b_ih, giBuf);
    k_gru_fin<<<G, 256, 0, stream>>>(giBuf, b_hh, w_fin, b_fin, w_root, b_root,
                                     rootv, alphap, out);
}

// Round 10
// 457.025 us; speedup vs baseline: 1.7031x; 1.1786x over previous
//
#include <hip/hip_runtime.h>
#include <math.h>

#define G 8
#define N0 16384
#define NEDGE (G*N0*8)      // 1048576
#define EPG (NEDGE/G)       // 131072 edges per graph
#define C 128
#define EPS_FA 0.1f
#define SMAX 2048

typedef unsigned short ushort_t;
typedef unsigned int uint_t;

__device__ inline ushort_t f2bf(float f) {
    uint_t u = __float_as_uint(f);
    uint_t r = (u + 0x7FFFu + ((u >> 16) & 1u)) >> 16;
    return (ushort_t)r;
}
__device__ inline uint_t pack2bf(float a, float b) {
    return (uint_t)f2bf(a) | ((uint_t)f2bf(b) << 16);
}
__device__ inline float bflo(uint_t w) { return __uint_as_float(w << 16); }
__device__ inline float bfhi(uint_t w) { return __uint_as_float(w & 0xFFFF0000u); }

// ---------------- layer-0 deg/score via LDS histogram ----------------
__global__ void __launch_bounds__(256) k_hist0(const int* __restrict__ ei,
                                               unsigned int* __restrict__ bh) {
    __shared__ unsigned int h[N0];
    int t = threadIdx.x;
    for (int i = t; i < N0; i += 256) h[i] = 0;
    __syncthreads();
    int base = blockIdx.x * 8192;
    int gbase = (blockIdx.x >> 4) * N0;
    for (int i = t; i < 8192; i += 256) {
        int s = ei[base + i] - gbase;
        int d = ei[NEDGE + base + i] - gbase;
        atomicAdd(&h[d], 1u);
        atomicAdd(&h[s], 0x10000u);
    }
    __syncthreads();
    unsigned int* o = bh + (size_t)blockIdx.x * N0;
    for (int i = t; i < N0; i += 256) o[i] = h[i];
}

// sum nsub per-graph block-histograms -> degI, score; optionally zero pooled
__global__ void k_sumdeg(const unsigned int* __restrict__ bh, int* __restrict__ degI,
                         int* __restrict__ score, int shift, int nsub, int n,
                         float* __restrict__ pooled) {
    int i = blockIdx.x * 256 + threadIdx.x;
    if (pooled && i < G * 384) pooled[i] = 0.0f;
    if (i >= n) return;
    int bins = 1 << shift;
    int g = i >> shift, u = i & (bins - 1);
    const unsigned int* p = bh + ((size_t)(g * nsub) << shift) + u;
    int ad = 0, as = 0;
    for (int b = 0; b < nsub; b++) {
        unsigned int w = p[(size_t)b * bins];
        ad += (int)(w & 0xFFFFu); as += (int)(w >> 16);
    }
    degI[i] = ad; score[i] = as;
}

// ---------------- layer-0 attention dots + x -> bf16 conversion ----------------
__global__ void k_alar(const float* __restrict__ x,
                       const float* __restrict__ attl, const float* __restrict__ attr,
                       float* __restrict__ al, float* __restrict__ ar,
                       ushort_t* __restrict__ xb, int n) {
    int wid  = (blockIdx.x * blockDim.x + threadIdx.x) >> 6;
    int lane = threadIdx.x & 63;
    if (wid >= n) return;
    float2 v  = ((const float2*)(x + (size_t)wid * C))[lane];
    ((uint_t*)(xb + (size_t)wid * C))[lane] = pack2bf(v.x, v.y);
    float2 l2 = ((const float2*)attl)[lane];
    float2 r2 = ((const float2*)attr)[lane];
    float sl = v.x * l2.x + v.y * l2.y;
    float sr = v.x * r2.x + v.y * r2.y;
    for (int o = 32; o >= 1; o >>= 1) { sl += __shfl_xor(sl, o); sr += __shfl_xor(sr, o); }
    if (lane == 0) { al[wid] = sl; ar[wid] = sr; }
}

// ---------------- prefix scan ----------------
__global__ void __launch_bounds__(256) k_scan1(const int* __restrict__ degI,
                                               int* __restrict__ rowptr,
                                               int* __restrict__ bsum) {
    __shared__ int part[256];
    int t = threadIdx.x;
    int base = blockIdx.x * 2048 + t * 8;
    int v[8]; int s = 0;
    for (int i = 0; i < 8; i++) { v[i] = degI[base + i]; s += v[i]; }
    part[t] = s; __syncthreads();
    for (int o = 1; o < 256; o <<= 1) {
        int val = part[t];
        int add = (t >= o) ? part[t - o] : 0;
        __syncthreads();
        part[t] = val + add;
        __syncthreads();
    }
    int run = (t == 0) ? 0 : part[t - 1];
    if (t == 255) bsum[blockIdx.x] = part[255];
    for (int i = 0; i < 8; i++) { rowptr[base + i] = run; run += v[i]; }
}

__global__ void k_scan3s(int* __restrict__ rowptr, int* __restrict__ cursor,
                         const int* __restrict__ bsum, const int* __restrict__ degI,
                         const float* __restrict__ al, const float* __restrict__ ar,
                         float* __restrict__ dinv, float* __restrict__ selfco,
                         unsigned char* __restrict__ keep, int* __restrict__ nmap, int n) {
    __shared__ int base_s;
    int t = threadIdx.x;
    if (t < 64) {
        int c = blockIdx.x >> 3;
        int vv = (t < c) ? bsum[t] : 0;
        for (int o = 32; o >= 1; o >>= 1) vv += __shfl_xor(vv, o);
        if (t == 0) base_s = vv;
    }
    __syncthreads();
    int i = blockIdx.x * 256 + t;
    if (i >= n) return;
    int v = rowptr[i] + base_s;
    rowptr[i] = v; cursor[i] = v;
    float d  = (float)degI[i] + 1.0f;
    float di = rsqrtf(d);
    dinv[i]   = di;
    selfco[i] = di * di * tanhf(al[i] + ar[i]);
    keep[i] = 0; nmap[i] = 0;
}

// ---------------- fill CSR (XCD-swizzled: graph = blockIdx&7) ----------------
__global__ void k_fill(const int* __restrict__ src, const int* __restrict__ dst,
                       const unsigned char* __restrict__ em,
                       const float* __restrict__ dinv, const float* __restrict__ al,
                       const float* __restrict__ ar,
                       int* __restrict__ cursor, int2* __restrict__ edges) {
    int gph = blockIdx.x & 7;
    int chunk = blockIdx.x >> 3;
    int e = gph * EPG + chunk * 256 + threadIdx.x;
    if (em && !em[e]) return;
    int s = src[e], d = dst[e];
    float cf = dinv[s] * dinv[d] * tanhf(al[d] + ar[s]);
    int pos = atomicAdd(&cursor[d], 1);
    edges[pos] = make_int2(s, __float_as_int(cf));
}

// ---------------- CSR gather messages (bf16, depth-4 prefetch) + pool partial ----
#define ACC4(W, CF) { a0 += (CF) * bflo((W).x); a1 += (CF) * bfhi((W).x); \
                      a2 += (CF) * bflo((W).y); a3 += (CF) * bfhi((W).y); }
__global__ void __launch_bounds__(256) k_msg_csr(
        const int* __restrict__ rowptr, const int* __restrict__ degI,
        const int2* __restrict__ edges,
        const ushort_t* __restrict__ cur, const ushort_t* __restrict__ xb,
        const int* __restrict__ oidx, const float* __restrict__ selfco,
        ushort_t* __restrict__ h, float* __restrict__ pb, int npg) {
    __shared__ float pm[8 * 128];
    int g    = blockIdx.x & 7;
    int ib   = blockIdx.x >> 3;
    int sub  = threadIdx.x >> 5;
    int lane = threadIdx.x & 31;
    int v = g * npg + ib * 8 + sub;
    int rs = rowptr[v], deg = degI[v];
    int o = oidx ? oidx[v] : v;
    uint2 cw = ((const uint2*)(cur + (size_t)v * C))[lane];
    uint2 xw = ((const uint2*)(xb  + (size_t)o * C))[lane];
    float sc = selfco[v];
    float a0 = 0.0f, a1 = 0.0f, a2 = 0.0f, a3 = 0.0f;
    for (int j0 = 0; j0 < deg; j0 += 32) {
        int cnt = deg - j0; if (cnt > 32) cnt = 32;
        int2 er = make_int2(0, 0);
        if (lane < cnt) er = edges[rs + j0 + lane];
        uint2 w0 = make_uint2(0,0), w1 = w0, w2 = w0, w3 = w0;
        {
            int s0 = __shfl(er.x, 0, 32);
            if (0 < cnt) w0 = ((const uint2*)(cur + (size_t)s0 * C))[lane];
            int s1 = __shfl(er.x, 1, 32);
            if (1 < cnt) w1 = ((const uint2*)(cur + (size_t)s1 * C))[lane];
            int s2 = __shfl(er.x, 2, 32);
            if (2 < cnt) w2 = ((const uint2*)(cur + (size_t)s2 * C))[lane];
            int s3 = __shfl(er.x, 3, 32);
            if (3 < cnt) w3 = ((const uint2*)(cur + (size_t)s3 * C))[lane];
        }
        int j = 0;
        for (; j + 4 <= cnt; j += 4) {
            float cf0 = __int_as_float(__shfl(er.y, j, 32));
            ACC4(w0, cf0);
            int sn0 = __shfl(er.x, j + 4, 32);
            if (j + 4 < cnt) w0 = ((const uint2*)(cur + (size_t)sn0 * C))[lane];
            float cf1 = __int_as_float(__shfl(er.y, j + 1, 32));
            ACC4(w1, cf1);
            int sn1 = __shfl(er.x, j + 5, 32);
            if (j + 5 < cnt) w1 = ((const uint2*)(cur + (size_t)sn1 * C))[lane];
            float cf2 = __int_as_float(__shfl(er.y, j + 2, 32));
            ACC4(w2, cf2);
            int sn2 = __shfl(er.x, j + 6, 32);
            if (j + 6 < cnt) w2 = ((const uint2*)(cur + (size_t)sn2 * C))[lane];
            float cf3 = __int_as_float(__shfl(er.y, j + 3, 32));
            ACC4(w3, cf3);
            int sn3 = __shfl(er.x, j + 7, 32);
            if (j + 7 < cnt) w3 = ((const uint2*)(cur + (size_t)sn3 * C))[lane];
        }
        if (j < cnt)     { float cf = __int_as_float(__shfl(er.y, j,     32)); ACC4(w0, cf); }
        if (j + 1 < cnt) { float cf = __int_as_float(__shfl(er.y, j + 1, 32)); ACC4(w1, cf); }
        if (j + 2 < cnt) { float cf = __int_as_float(__shfl(er.y, j + 2, 32)); ACC4(w2, cf); }
    }
    float r0 = fmaxf(a0 + sc * bflo(cw.x) + EPS_FA * bflo(xw.x), 0.0f);
    float r1 = fmaxf(a1 + sc * bfhi(cw.x) + EPS_FA * bfhi(xw.x), 0.0f);
    float r2 = fmaxf(a2 + sc * bflo(cw.y) + EPS_FA * bflo(xw.y), 0.0f);
    float r3 = fmaxf(a3 + sc * bfhi(cw.y) + EPS_FA * bfhi(xw.y), 0.0f);
    uint2 hw; hw.x = pack2bf(r0, r1); hw.y = pack2bf(r2, r3);
    ((uint2*)(h + (size_t)v * C))[lane] = hw;
    float4 rr = make_float4(r0, r1, r2, r3);
    ((float4*)(pm + sub * 128))[lane] = rr;
    __syncthreads();
    int t = threadIdx.x;
    if (t < 128) {
        float m = pm[t];
        for (int s = 1; s < 8; s++) m = fmaxf(m, pm[s * 128 + t]);
        pb[(size_t)blockIdx.x * 128 + t] = m;
    }
}

// ---------------- reduce pb -> pooled (parallel, XCD-matched) ----------------
// grid = npg/64 blocks; graph = blockIdx&7, chunk of 64 pb-rows per block
__global__ void __launch_bounds__(256) k_poolred(const float* __restrict__ pb,
                                                 float* __restrict__ pooled, int layer) {
    __shared__ float sm[256];
    int g = blockIdx.x & 7;
    int ch = blockIdx.x >> 3;
    int t = threadIdx.x;
    int c = t & 127, half = t >> 7;
    float m = 0.0f;
    for (int i = 0; i < 32; i++) {
        int r = ch * 64 + half * 32 + i;
        m = fmaxf(m, pb[(size_t)(g + 8 * r) * 128 + c]);
    }
    sm[t] = m;
    __syncthreads();
    if (t < 128) {
        float mm = fmaxf(sm[t], sm[t + 128]);
        atomicMax((unsigned int*)&pooled[g * 384 + layer * 128 + c], __float_as_uint(mm));
    }
}

// ---------------- parallel exact stable top-k ----------------
__global__ void __launch_bounds__(256) k_hist(const int* __restrict__ score, int npg, int nb,
                                              int* __restrict__ blockhist) {
    __shared__ int lh[SMAX];
    int g = blockIdx.x / nb, b = blockIdx.x % nb, t = threadIdx.x;
    for (int s = t; s < SMAX; s += 256) lh[s] = 0;
    __syncthreads();
    int s = score[g * npg + b * 256 + t];
    if (s > SMAX - 1) s = SMAX - 1;
    atomicAdd(&lh[s], 1);
    __syncthreads();
    int* outp = blockhist + ((size_t)g * nb + b) * SMAX;
    for (int i = t; i < SMAX; i += 256) outp[i] = lh[i];
}

__global__ void __launch_bounds__(256) k_binprefix(int* __restrict__ blockhist,
                                                   int* __restrict__ hist, int nb) {
    __shared__ int tile[64 * 256];
    int g = blockIdx.x >> 3, ch = blockIdx.x & 7, t = threadIdx.x;
    int s0 = ch * 256;
    int* bg = blockhist + (size_t)g * nb * SMAX + s0;
    for (int b = 0; b < nb; b++) tile[b * 256 + t] = bg[(size_t)b * SMAX + t];
    __syncthreads();
    int acc = 0;
    for (int b = 0; b < nb; b++) {
        int v = tile[b * 256 + t];
        tile[b * 256 + t] = acc;
        acc += v;
    }
    __syncthreads();
    for (int b = 0; b < nb; b++) bg[(size_t)b * SMAX + t] = tile[b * 256 + t];
    hist[g * SMAX + s0 + t] = acc;
}

__global__ void __launch_bounds__(256) k_rank(const int* __restrict__ score,
                                              const int* __restrict__ blockhist,
                                              const int* __restrict__ hist,
                                              int npg, int nb, int k,
                                              unsigned char* __restrict__ keep,
                                              int* __restrict__ nmap, int* __restrict__ perm) {
    __shared__ int bp[SMAX];
    __shared__ int part[256];
    __shared__ int cs[256];
    int g = blockIdx.x / nb, b = blockIdx.x % nb, t = threadIdx.x;
    const int* hg = hist + g * SMAX;
    int v[8]; int sm = 0;
    for (int i = 0; i < 8; i++) { v[i] = hg[SMAX - 1 - (t * 8 + i)]; sm += v[i]; }
    part[t] = sm; __syncthreads();
    for (int o = 1; o < 256; o <<= 1) {
        int val = part[t];
        int add = (t >= o) ? part[t - o] : 0;
        __syncthreads();
        part[t] = val + add;
        __syncthreads();
    }
    int run = (t == 0) ? 0 : part[t - 1];
    for (int i = 0; i < 8; i++) { bp[SMAX - 1 - (t * 8 + i)] = run; run += v[i]; }
    int vv = b * 256 + t;
    int s = score[g * npg + vv];
    if (s > SMAX - 1) s = SMAX - 1;
    cs[t] = s;
    __syncthreads();
    int cnt = 0;
    for (int u = 0; u < t; u++) cnt += (cs[u] == s);
    int pos = bp[s] + blockhist[((size_t)g * nb + b) * SMAX + s] + cnt;
    if (pos < k) {
        int vg = g * npg + vv;
        int nid = g * k + pos;
        keep[vg] = 1; nmap[vg] = nid; perm[nid] = vg;
    }
}

// ---------------- gather kept nodes (bf16) + next-layer al/ar ----------------
__global__ void k_gather_alar(const ushort_t* __restrict__ h, const int* __restrict__ perm,
                              const int* __restrict__ oidx,
                              const float* __restrict__ attlN, const float* __restrict__ attrN,
                              ushort_t* __restrict__ curN, int* __restrict__ oidxN,
                              float* __restrict__ al, float* __restrict__ ar, int m) {
    int i = blockIdx.x * 256 + threadIdx.x;
    if (i >= m * 32) return;
    int j = i >> 5, c4 = i & 31;
    int p = perm[j];
    uint2 w = ((const uint2*)(h + (size_t)p * C))[c4];
    ((uint2*)(curN + (size_t)j * C))[c4] = w;
    float f0 = bflo(w.x), f1 = bfhi(w.x), f2 = bflo(w.y), f3 = bfhi(w.y);
    float4 l4 = ((const float4*)attlN)[c4];
    float4 r4 = ((const float4*)attrN)[c4];
    float sl = f0 * l4.x + f1 * l4.y + f2 * l4.z + f3 * l4.w;
    float sr = f0 * r4.x + f1 * r4.y + f2 * r4.z + f3 * r4.w;
    for (int o = 16; o >= 1; o >>= 1) { sl += __shfl_xor(sl, o); sr += __shfl_xor(sr, o); }
    if (c4 == 0) {
        al[j] = sl; ar[j] = sr;
        oidxN[j] = oidx ? oidx[p] : p;
    }
}

// ---------------- remap edges + next-layer deg/score LDS histogram ----------------
__global__ void __launch_bounds__(256) k_remap_hist(
        const int* __restrict__ inS, const int* __restrict__ inD,
        const unsigned char* __restrict__ inEm,
        int* __restrict__ src, int* __restrict__ dst, unsigned char* __restrict__ em,
        const unsigned char* __restrict__ keep, const int* __restrict__ nmap,
        unsigned int* __restrict__ bh, int kN) {
    __shared__ unsigned int h[8192];
    int t = threadIdx.x;
    for (int i = t; i < kN; i += 256) h[i] = 0;
    __syncthreads();
    int base = blockIdx.x * 4096;
    int gb = (blockIdx.x >> 5) * kN;
    for (int i = t; i < 4096; i += 256) {
        int e = base + i;
        int s = inS[e], d = inD[e];
        bool ok = (!inEm || inEm[e]) && keep[s] && keep[d];
        if (ok) {
            int ns = nmap[s], nd = nmap[d];
            src[e] = ns; dst[e] = nd; em[e] = 1;
            atomicAdd(&h[nd - gb], 1u);
            atomicAdd(&h[ns - gb], 0x10000u);
        } else { src[e] = 0; dst[e] = 0; em[e] = 0; }
    }
    __syncthreads();
    unsigned int* o = bh + (size_t)blockIdx.x * kN;
    for (int i = t; i < kN; i += 256) o[i] = h[i];
}

// ---------------- GRU head, stage A ----------------
__global__ void __launch_bounds__(256) k_gi(const float* __restrict__ pooled,
                                            const float* __restrict__ wih,
                                            const float* __restrict__ bih,
                                            float* __restrict__ gi) {
    int g = blockIdx.y;
    int row = blockIdx.x * 4 + (threadIdx.x >> 6);
    int lane = threadIdx.x & 63;
    const float* w = wih + (size_t)row * 384;
    const float* f = pooled + g * 384;
    float s = 0.0f;
    #pragma unroll
    for (int i = 0; i < 6; i++) s += w[i * 64 + lane] * f[i * 64 + lane];
    for (int o = 32; o >= 1; o >>= 1) s += __shfl_xor(s, o);
    if (lane == 0) gi[g * 768 + row] = s + bih[row];
}

// ---------------- GRU head, stage B ----------------
__global__ void __launch_bounds__(256) k_gru_fin(const float* __restrict__ gi,
        const float* __restrict__ bhh, const float* __restrict__ wfin,
        const float* __restrict__ bfin, const float* __restrict__ wroot,
        const float* __restrict__ broot, const float* __restrict__ rootv,
        const float* __restrict__ alphap, float* __restrict__ out) {
    int g = blockIdx.x, t = threadIdx.x;
    __shared__ float hg[256];
    {
        float r  = 1.0f / (1.0f + expf(-(gi[g * 768 + t]       + bhh[t])));
        float z  = 1.0f / (1.0f + expf(-(gi[g * 768 + 256 + t] + bhh[256 + t])));
        float nc = tanhf(gi[g * 768 + 512 + t] + r * bhh[512 + t]);
        hg[t] = (1.0f - z) * nc;
    }
    __syncthreads();
    float a = alphap[0];
    int wv = t >> 6, lane = t & 63;
    const float* rg = rootv + (size_t)g * 128;
    for (int oo = 0; oo < 32; oo++) {
        int o = wv * 32 + oo;
        const float* wf = wfin + (size_t)o * 256;
        float sf = wf[lane] * hg[lane] + wf[64 + lane] * hg[64 + lane]
                 + wf[128 + lane] * hg[128 + lane] + wf[192 + lane] * hg[192 + lane];
        const float* wr = wroot + (size_t)o * 128;
        float sr = wr[lane] * rg[lane] + wr[64 + lane] * rg[64 + lane];
        float s = a * sf + (1.0f - a) * sr;
        for (int sh = 32; sh >= 1; sh >>= 1) s += __shfl_xor(s, sh);
        if (lane == 0)
            out[g * 128 + o] = s + a * bfin[o] + (1.0f - a) * broot[o];
    }
}

extern "C" void kernel_launch(void* const* d_in, const int* in_sizes, int n_in,
                              void* d_out, int out_size, void* d_ws, size_t ws_size,
                              hipStream_t stream) {
    const float* x      = (const float*)d_in[0];
    const int*   ei     = (const int*)d_in[1];
    const float* rootv  = (const float*)d_in[3];
    const float* att_l  = (const float*)d_in[4];
    const float* att_r  = (const float*)d_in[5];
    const float* w_ih   = (const float*)d_in[6];
    const float* b_ih   = (const float*)d_in[8];
    const float* b_hh   = (const float*)d_in[9];
    const float* w_fin  = (const float*)d_in[10];
    const float* b_fin  = (const float*)d_in[11];
    const float* w_root = (const float*)d_in[12];
    const float* b_root = (const float*)d_in[13];
    const float* alphap = (const float*)d_in[14];
    float* out = (float*)d_out;

    char* wsb = (char*)d_ws;
    size_t off = 0;
    auto alloc = [&](size_t bytes) -> char* {
        char* p = wsb + off; off += (bytes + 255) & ~(size_t)255; return p;
    };
    ushort_t* xb   = (ushort_t*)alloc((size_t)131072 * C * 2);
    ushort_t* bufH = (ushort_t*)alloc((size_t)131072 * C * 2);
    ushort_t* bufC = (ushort_t*)alloc((size_t)65536  * C * 2);
    int*   srcA   = (int*)alloc((size_t)NEDGE * 4);
    int*   dstA   = (int*)alloc((size_t)NEDGE * 4);
    unsigned char* emask = (unsigned char*)alloc(NEDGE);
    int2*  edges  = (int2*)alloc((size_t)NEDGE * 8);
    float* al     = (float*)alloc(131072 * 4);
    float* ar     = (float*)alloc(131072 * 4);
    float* dinv   = (float*)alloc(131072 * 4);
    float* selfco = (float*)alloc(131072 * 4);
    int*   degI   = (int*)alloc(131072 * 4);
    int*   score  = (int*)alloc(131072 * 4);
    int*   rowptr = (int*)alloc(131072 * 4);
    int*   cursor = (int*)alloc(131072 * 4);
    int*   bsum   = (int*)alloc(256 * 4);
    unsigned char* keep = (unsigned char*)alloc(131072);
    int*   nmap   = (int*)alloc(131072 * 4);
    int*   perm   = (int*)alloc(65536 * 4);
    int*   oidxA  = (int*)alloc(65536 * 4);
    int*   oidxB  = (int*)alloc(32768 * 4);
    float* pooled = (float*)alloc(G * 384 * 4);
    float* giBuf  = (float*)alloc(G * 768 * 4);
    int*   blockhist = (int*)alloc((size_t)G * 64 * SMAX * 4);
    int*   histT  = (int*)alloc((size_t)G * SMAX * 4);
    unsigned int* bh = (unsigned int*)alloc((size_t)128 * N0 * 4);
    float* pb = (float*)bh;

    k_hist0<<<128, 256, 0, stream>>>(ei, bh);
    k_sumdeg<<<131072 / 256, 256, 0, stream>>>(bh, degI, score, 14, 16, 131072, pooled);

    const int ns[3]   = {131072, 65536, 32768};
    const int npgs[3] = {16384, 8192, 4096};
    const int ks[3]   = {8192, 4096, 0};
    const int shifts[3] = {14, 13, 12};

    for (int l = 0; l < 3; l++) {
        int n = ns[l], npg = npgs[l], k = ks[l];
        const ushort_t* cur = (l == 0) ? xb : bufC;
        const int* oidx = (l == 0) ? nullptr : (l == 1 ? oidxA : oidxB);
        int* oidxN = (l == 0) ? oidxA : oidxB;
        const int* eS = (l == 0) ? ei : srcA;
        const int* eD = (l == 0) ? ei + NEDGE : dstA;
        const unsigned char* eM = (l == 0) ? nullptr : emask;

        if (l == 0)
            k_alar<<<n / 4, 256, 0, stream>>>(x, att_l, att_r, al, ar, xb, n);

        int nblk = n / 2048;
        k_scan1<<<nblk, 256, 0, stream>>>(degI, rowptr, bsum);
        k_scan3s<<<n / 256, 256, 0, stream>>>(rowptr, cursor, bsum, degI, al, ar,
                                              dinv, selfco, keep, nmap, n);

        k_fill<<<NEDGE / 256, 256, 0, stream>>>(eS, eD, eM, dinv, al, ar,
                                                cursor, edges);
        k_msg_csr<<<n / 8, 256, 0, stream>>>(rowptr, degI, edges, cur, xb, oidx,
                                             selfco, bufH, pb, npg);
        k_poolred<<<npg / 64, 256, 0, stream>>>(pb, pooled, l);

        if (l < 2) {
            int nb = npg / 256;
            k_hist<<<G * nb, 256, 0, stream>>>(score, npg, nb, blockhist);
            k_binprefix<<<G * 8, 256, 0, stream>>>(blockhist, histT, nb);
            k_rank<<<G * nb, 256, 0, stream>>>(score, blockhist, histT, npg, nb, k,
                                               keep, nmap, perm);
            int m = G * k;
            k_gather_alar<<<(m * 32 + 255) / 256, 256, 0, stream>>>(
                bufH, perm, oidx, att_l + (l + 1) * C, att_r + (l + 1) * C,
                bufC, oidxN, al, ar, m);
            k_remap_hist<<<256, 256, 0, stream>>>(eS, eD, eM, srcA, dstA, emask,
                                                  keep, nmap, bh, k);
            k_sumdeg<<<(G * k + 255) / 256, 256, 0, stream>>>(bh, degI, score,
                                                              shifts[l + 1], 32, G * k,
                                                              nullptr);
        }
    }

    k_gi<<<dim3(192, G), 256, 0, stream>>>(pooled, w_ih, b_ih, giBuf);
    k_gru_fin<<<G, 256, 0, stream>>>(giBuf, b_hh, w_fin, b_fin, w_root, b_root,
                                     rootv, alphap, out);
}

// Round 11
// 438.931 us; speedup vs baseline: 1.7733x; 1.0412x over previous
//
#include <hip/hip_runtime.h>
#include <math.h>

#define G 8
#define N0 16384
#define NEDGE (G*N0*8)      // 1048576
#define EPG (NEDGE/G)       // 131072 edges per graph
#define C 128
#define EPS_FA 0.1f
#define SMAX 2048

typedef unsigned short ushort_t;
typedef unsigned int uint_t;

__device__ inline ushort_t f2bf(float f) {
    uint_t u = __float_as_uint(f);
    uint_t r = (u + 0x7FFFu + ((u >> 16) & 1u)) >> 16;
    return (ushort_t)r;
}
__device__ inline uint_t pack2bf(float a, float b) {
    return (uint_t)f2bf(a) | ((uint_t)f2bf(b) << 16);
}
__device__ inline float bflo(uint_t w) { return __uint_as_float(w << 16); }
__device__ inline float bfhi(uint_t w) { return __uint_as_float(w & 0xFFFF0000u); }

// ---------------- layer-0 deg/score LDS histogram + edge local rank ----------------
// 128 blocks; block b: edges [b*8192,(b+1)*8192), graph b>>4.
__global__ void __launch_bounds__(256) k_hist0(const int* __restrict__ ei,
                                               unsigned int* __restrict__ bh,
                                               ushort_t* __restrict__ lrank) {
    __shared__ unsigned int h[N0];
    int t = threadIdx.x;
    for (int i = t; i < N0; i += 256) h[i] = 0;
    __syncthreads();
    int base = blockIdx.x * 8192;
    int gbase = (blockIdx.x >> 4) * N0;
    for (int i = t; i < 8192; i += 256) {
        int s = ei[base + i] - gbase;
        int d = ei[NEDGE + base + i] - gbase;
        unsigned int old = atomicAdd(&h[d], 1u);
        lrank[base + i] = (ushort_t)(old & 0xFFFFu);
        atomicAdd(&h[s], 0x10000u);
    }
    __syncthreads();
    unsigned int* o = bh + (size_t)blockIdx.x * N0;
    for (int i = t; i < N0; i += 256) o[i] = h[i];
}

// sum nsub per-graph block-histograms -> degI, score; convert bh to per-block
// exclusive deg-prefix in place; optionally zero pooled
__global__ void k_sumdeg(unsigned int* __restrict__ bh, int* __restrict__ degI,
                         int* __restrict__ score, int shift, int nsub, int n,
                         float* __restrict__ pooled) {
    int i = blockIdx.x * 256 + threadIdx.x;
    if (pooled && i < G * 384) pooled[i] = 0.0f;
    if (i >= n) return;
    int bins = 1 << shift;
    int g = i >> shift, u = i & (bins - 1);
    unsigned int* p = bh + ((size_t)(g * nsub) << shift) + u;
    unsigned int run = 0; int as = 0;
    for (int b = 0; b < nsub; b++) {
        unsigned int w = p[(size_t)b * bins];
        p[(size_t)b * bins] = run;
        run += w & 0xFFFFu; as += (int)(w >> 16);
    }
    degI[i] = (int)run; score[i] = as;
}

// ---------------- layer-0 attention dots + x -> bf16 conversion ----------------
__global__ void k_alar(const float* __restrict__ x,
                       const float* __restrict__ attl, const float* __restrict__ attr,
                       float* __restrict__ al, float* __restrict__ ar,
                       ushort_t* __restrict__ xb, int n) {
    int wid  = (blockIdx.x * blockDim.x + threadIdx.x) >> 6;
    int lane = threadIdx.x & 63;
    if (wid >= n) return;
    float2 v  = ((const float2*)(x + (size_t)wid * C))[lane];
    ((uint_t*)(xb + (size_t)wid * C))[lane] = pack2bf(v.x, v.y);
    float2 l2 = ((const float2*)attl)[lane];
    float2 r2 = ((const float2*)attr)[lane];
    float sl = v.x * l2.x + v.y * l2.y;
    float sr = v.x * r2.x + v.y * r2.y;
    for (int o = 32; o >= 1; o >>= 1) { sl += __shfl_xor(sl, o); sr += __shfl_xor(sr, o); }
    if (lane == 0) { al[wid] = sl; ar[wid] = sr; }
}

// ---------------- prefix scan ----------------
__global__ void __launch_bounds__(256) k_scan1(const int* __restrict__ degI,
                                               int* __restrict__ rowptr,
                                               int* __restrict__ bsum) {
    __shared__ int part[256];
    int t = threadIdx.x;
    int base = blockIdx.x * 2048 + t * 8;
    int v[8]; int s = 0;
    for (int i = 0; i < 8; i++) { v[i] = degI[base + i]; s += v[i]; }
    part[t] = s; __syncthreads();
    for (int o = 1; o < 256; o <<= 1) {
        int val = part[t];
        int add = (t >= o) ? part[t - o] : 0;
        __syncthreads();
        part[t] = val + add;
        __syncthreads();
    }
    int run = (t == 0) ? 0 : part[t - 1];
    if (t == 255) bsum[blockIdx.x] = part[255];
    for (int i = 0; i < 8; i++) { rowptr[base + i] = run; run += v[i]; }
}

__global__ void k_scan3s(int* __restrict__ rowptr,
                         const int* __restrict__ bsum, const int* __restrict__ degI,
                         const float* __restrict__ al, const float* __restrict__ ar,
                         float* __restrict__ dinv, float* __restrict__ selfco,
                         unsigned char* __restrict__ keep, int* __restrict__ nmap, int n) {
    __shared__ int base_s;
    int t = threadIdx.x;
    if (t < 64) {
        int c = blockIdx.x >> 3;
        int vv = (t < c) ? bsum[t] : 0;
        for (int o = 32; o >= 1; o >>= 1) vv += __shfl_xor(vv, o);
        if (t == 0) base_s = vv;
    }
    __syncthreads();
    int i = blockIdx.x * 256 + t;
    if (i >= n) return;
    rowptr[i] += base_s;
    float d  = (float)degI[i] + 1.0f;
    float di = rsqrtf(d);
    dinv[i]   = di;
    selfco[i] = di * di * tanhf(al[i] + ar[i]);
    keep[i] = 0; nmap[i] = 0;
}

// ---------------- fill CSR: deterministic slot, no atomics ----------------
// slot = rowptr[d] + blockprefix[b][d] + lrank[e]; graph = blockIdx&7 (XCD affinity)
__global__ void k_fill(const int* __restrict__ src, const int* __restrict__ dst,
                       const unsigned char* __restrict__ em,
                       const float* __restrict__ dinv, const float* __restrict__ al,
                       const float* __restrict__ ar,
                       const int* __restrict__ rowptr,
                       const unsigned int* __restrict__ bpre,
                       const ushort_t* __restrict__ lrank,
                       int2* __restrict__ edges,
                       int ebShift, int nsubShift, int binShift) {
    int gph = blockIdx.x & 7;
    int chunk = blockIdx.x >> 3;
    int e = gph * EPG + chunk * 256 + threadIdx.x;
    if (em && !em[e]) return;
    int s = src[e], d = dst[e];
    float cf = dinv[s] * dinv[d] * tanhf(al[d] + ar[s]);
    int b = e >> ebShift;
    int gb = (b >> nsubShift) << binShift;
    int slot = rowptr[d] + (int)bpre[((size_t)b << binShift) + (d - gb)] + (int)lrank[e];
    edges[slot] = make_int2(s, __float_as_int(cf));
}

// ---------------- CSR gather messages (bf16, depth-4 prefetch) + pool partial ----
#define ACC4(W, CF) { a0 += (CF) * bflo((W).x); a1 += (CF) * bfhi((W).x); \
                      a2 += (CF) * bflo((W).y); a3 += (CF) * bfhi((W).y); }
__global__ void __launch_bounds__(256) k_msg_csr(
        const int* __restrict__ rowptr, const int* __restrict__ degI,
        const int2* __restrict__ edges,
        const ushort_t* __restrict__ cur, const ushort_t* __restrict__ xb,
        const int* __restrict__ oidx, const float* __restrict__ selfco,
        ushort_t* __restrict__ h, float* __restrict__ pb, int npg) {
    __shared__ float pm[8 * 128];
    int g    = blockIdx.x & 7;
    int ib   = blockIdx.x >> 3;
    int sub  = threadIdx.x >> 5;
    int lane = threadIdx.x & 31;
    int v = g * npg + ib * 8 + sub;
    int rs = rowptr[v], deg = degI[v];
    int o = oidx ? oidx[v] : v;
    uint2 cw = ((const uint2*)(cur + (size_t)v * C))[lane];
    uint2 xw = ((const uint2*)(xb  + (size_t)o * C))[lane];
    float sc = selfco[v];
    float a0 = 0.0f, a1 = 0.0f, a2 = 0.0f, a3 = 0.0f;
    for (int j0 = 0; j0 < deg; j0 += 32) {
        int cnt = deg - j0; if (cnt > 32) cnt = 32;
        int2 er = make_int2(0, 0);
        if (lane < cnt) er = edges[rs + j0 + lane];
        uint2 w0 = make_uint2(0,0), w1 = w0, w2 = w0, w3 = w0;
        {
            int s0 = __shfl(er.x, 0, 32);
            if (0 < cnt) w0 = ((const uint2*)(cur + (size_t)s0 * C))[lane];
            int s1 = __shfl(er.x, 1, 32);
            if (1 < cnt) w1 = ((const uint2*)(cur + (size_t)s1 * C))[lane];
            int s2 = __shfl(er.x, 2, 32);
            if (2 < cnt) w2 = ((const uint2*)(cur + (size_t)s2 * C))[lane];
            int s3 = __shfl(er.x, 3, 32);
            if (3 < cnt) w3 = ((const uint2*)(cur + (size_t)s3 * C))[lane];
        }
        int j = 0;
        for (; j + 4 <= cnt; j += 4) {
            float cf0 = __int_as_float(__shfl(er.y, j, 32));
            ACC4(w0, cf0);
            int sn0 = __shfl(er.x, j + 4, 32);
            if (j + 4 < cnt) w0 = ((const uint2*)(cur + (size_t)sn0 * C))[lane];
            float cf1 = __int_as_float(__shfl(er.y, j + 1, 32));
            ACC4(w1, cf1);
            int sn1 = __shfl(er.x, j + 5, 32);
            if (j + 5 < cnt) w1 = ((const uint2*)(cur + (size_t)sn1 * C))[lane];
            float cf2 = __int_as_float(__shfl(er.y, j + 2, 32));
            ACC4(w2, cf2);
            int sn2 = __shfl(er.x, j + 6, 32);
            if (j + 6 < cnt) w2 = ((const uint2*)(cur + (size_t)sn2 * C))[lane];
            float cf3 = __int_as_float(__shfl(er.y, j + 3, 32));
            ACC4(w3, cf3);
            int sn3 = __shfl(er.x, j + 7, 32);
            if (j + 7 < cnt) w3 = ((const uint2*)(cur + (size_t)sn3 * C))[lane];
        }
        if (j < cnt)     { float cf = __int_as_float(__shfl(er.y, j,     32)); ACC4(w0, cf); }
        if (j + 1 < cnt) { float cf = __int_as_float(__shfl(er.y, j + 1, 32)); ACC4(w1, cf); }
        if (j + 2 < cnt) { float cf = __int_as_float(__shfl(er.y, j + 2, 32)); ACC4(w2, cf); }
    }
    float r0 = fmaxf(a0 + sc * bflo(cw.x) + EPS_FA * bflo(xw.x), 0.0f);
    float r1 = fmaxf(a1 + sc * bfhi(cw.x) + EPS_FA * bfhi(xw.x), 0.0f);
    float r2 = fmaxf(a2 + sc * bflo(cw.y) + EPS_FA * bflo(xw.y), 0.0f);
    float r3 = fmaxf(a3 + sc * bfhi(cw.y) + EPS_FA * bfhi(xw.y), 0.0f);
    uint2 hw; hw.x = pack2bf(r0, r1); hw.y = pack2bf(r2, r3);
    ((uint2*)(h + (size_t)v * C))[lane] = hw;
    float4 rr = make_float4(r0, r1, r2, r3);
    ((float4*)(pm + sub * 128))[lane] = rr;
    __syncthreads();
    int t = threadIdx.x;
    if (t < 128) {
        float m = pm[t];
        for (int s = 1; s < 8; s++) m = fmaxf(m, pm[s * 128 + t]);
        pb[(size_t)blockIdx.x * 128 + t] = m;
    }
}

// ---------------- reduce pb -> pooled (parallel, XCD-matched) ----------------
__global__ void __launch_bounds__(256) k_poolred(const float* __restrict__ pb,
                                                 float* __restrict__ pooled, int layer) {
    __shared__ float sm[256];
    int g = blockIdx.x & 7;
    int ch = blockIdx.x >> 3;
    int t = threadIdx.x;
    int c = t & 127, half = t >> 7;
    float m = 0.0f;
    for (int i = 0; i < 32; i++) {
        int r = ch * 64 + half * 32 + i;
        m = fmaxf(m, pb[(size_t)(g + 8 * r) * 128 + c]);
    }
    sm[t] = m;
    __syncthreads();
    if (t < 128) {
        float mm = fmaxf(sm[t], sm[t + 128]);
        atomicMax((unsigned int*)&pooled[g * 384 + layer * 128 + c], __float_as_uint(mm));
    }
}

// ---------------- parallel exact stable top-k ----------------
__global__ void __launch_bounds__(256) k_hist(const int* __restrict__ score, int npg, int nb,
                                              int* __restrict__ blockhist) {
    __shared__ int lh[SMAX];
    int g = blockIdx.x / nb, b = blockIdx.x % nb, t = threadIdx.x;
    for (int s = t; s < SMAX; s += 256) lh[s] = 0;
    __syncthreads();
    int s = score[g * npg + b * 256 + t];
    if (s > SMAX - 1) s = SMAX - 1;
    atomicAdd(&lh[s], 1);
    __syncthreads();
    int* outp = blockhist + ((size_t)g * nb + b) * SMAX;
    for (int i = t; i < SMAX; i += 256) outp[i] = lh[i];
}

__global__ void __launch_bounds__(256) k_binprefix(int* __restrict__ blockhist,
                                                   int* __restrict__ hist, int nb) {
    __shared__ int tile[64 * 256];
    int g = blockIdx.x >> 3, ch = blockIdx.x & 7, t = threadIdx.x;
    int s0 = ch * 256;
    int* bg = blockhist + (size_t)g * nb * SMAX + s0;
    for (int b = 0; b < nb; b++) tile[b * 256 + t] = bg[(size_t)b * SMAX + t];
    __syncthreads();
    int acc = 0;
    for (int b = 0; b < nb; b++) {
        int v = tile[b * 256 + t];
        tile[b * 256 + t] = acc;
        acc += v;
    }
    __syncthreads();
    for (int b = 0; b < nb; b++) bg[(size_t)b * SMAX + t] = tile[b * 256 + t];
    hist[g * SMAX + s0 + t] = acc;
}

__global__ void __launch_bounds__(256) k_rank(const int* __restrict__ score,
                                              const int* __restrict__ blockhist,
                                              const int* __restrict__ hist,
                                              int npg, int nb, int k,
                                              unsigned char* __restrict__ keep,
                                              int* __restrict__ nmap, int* __restrict__ perm) {
    __shared__ int bp[SMAX];
    __shared__ int part[256];
    __shared__ int cs[256];
    int g = blockIdx.x / nb, b = blockIdx.x % nb, t = threadIdx.x;
    const int* hg = hist + g * SMAX;
    int v[8]; int sm = 0;
    for (int i = 0; i < 8; i++) { v[i] = hg[SMAX - 1 - (t * 8 + i)]; sm += v[i]; }
    part[t] = sm; __syncthreads();
    for (int o = 1; o < 256; o <<= 1) {
        int val = part[t];
        int add = (t >= o) ? part[t - o] : 0;
        __syncthreads();
        part[t] = val + add;
        __syncthreads();
    }
    int run = (t == 0) ? 0 : part[t - 1];
    for (int i = 0; i < 8; i++) { bp[SMAX - 1 - (t * 8 + i)] = run; run += v[i]; }
    int vv = b * 256 + t;
    int s = score[g * npg + vv];
    if (s > SMAX - 1) s = SMAX - 1;
    cs[t] = s;
    __syncthreads();
    int cnt = 0;
    for (int u = 0; u < t; u++) cnt += (cs[u] == s);
    int pos = bp[s] + blockhist[((size_t)g * nb + b) * SMAX + s] + cnt;
    if (pos < k) {
        int vg = g * npg + vv;
        int nid = g * k + pos;
        keep[vg] = 1; nmap[vg] = nid; perm[nid] = vg;
    }
}

// ---------------- gather kept nodes (bf16) + next-layer al/ar ----------------
__global__ void k_gather_alar(const ushort_t* __restrict__ h, const int* __restrict__ perm,
                              const int* __restrict__ oidx,
                              const float* __restrict__ attlN, const float* __restrict__ attrN,
                              ushort_t* __restrict__ curN, int* __restrict__ oidxN,
                              float* __restrict__ al, float* __restrict__ ar, int m) {
    int i = blockIdx.x * 256 + threadIdx.x;
    if (i >= m * 32) return;
    int j = i >> 5, c4 = i & 31;
    int p = perm[j];
    uint2 w = ((const uint2*)(h + (size_t)p * C))[c4];
    ((uint2*)(curN + (size_t)j * C))[c4] = w;
    float f0 = bflo(w.x), f1 = bfhi(w.x), f2 = bflo(w.y), f3 = bfhi(w.y);
    float4 l4 = ((const float4*)attlN)[c4];
    float4 r4 = ((const float4*)attrN)[c4];
    float sl = f0 * l4.x + f1 * l4.y + f2 * l4.z + f3 * l4.w;
    float sr = f0 * r4.x + f1 * r4.y + f2 * r4.z + f3 * r4.w;
    for (int o = 16; o >= 1; o >>= 1) { sl += __shfl_xor(sl, o); sr += __shfl_xor(sr, o); }
    if (c4 == 0) {
        al[j] = sl; ar[j] = sr;
        oidxN[j] = oidx ? oidx[p] : p;
    }
}

// ---------------- remap edges + next-layer deg/score LDS histogram + lrank ------
__global__ void __launch_bounds__(256) k_remap_hist(
        const int* __restrict__ inS, const int* __restrict__ inD,
        const unsigned char* __restrict__ inEm,
        int* __restrict__ src, int* __restrict__ dst, unsigned char* __restrict__ em,
        const unsigned char* __restrict__ keep, const int* __restrict__ nmap,
        unsigned int* __restrict__ bh, ushort_t* __restrict__ lrank, int kN) {
    __shared__ unsigned int h[8192];
    int t = threadIdx.x;
    for (int i = t; i < kN; i += 256) h[i] = 0;
    __syncthreads();
    int base = blockIdx.x * 4096;
    int gb = (blockIdx.x >> 5) * kN;
    for (int i = t; i < 4096; i += 256) {
        int e = base + i;
        int s = inS[e], d = inD[e];
        bool ok = (!inEm || inEm[e]) && keep[s] && keep[d];
        if (ok) {
            int ns = nmap[s], nd = nmap[d];
            src[e] = ns; dst[e] = nd; em[e] = 1;
            unsigned int old = atomicAdd(&h[nd - gb], 1u);
            lrank[e] = (ushort_t)(old & 0xFFFFu);
            atomicAdd(&h[ns - gb], 0x10000u);
        } else { src[e] = 0; dst[e] = 0; em[e] = 0; }
    }
    __syncthreads();
    unsigned int* o = bh + (size_t)blockIdx.x * kN;
    for (int i = t; i < kN; i += 256) o[i] = h[i];
}

// ---------------- GRU head, stage A ----------------
__global__ void __launch_bounds__(256) k_gi(const float* __restrict__ pooled,
                                            const float* __restrict__ wih,
                                            const float* __restrict__ bih,
                                            float* __restrict__ gi) {
    int g = blockIdx.y;
    int row = blockIdx.x * 4 + (threadIdx.x >> 6);
    int lane = threadIdx.x & 63;
    const float* w = wih + (size_t)row * 384;
    const float* f = pooled + g * 384;
    float s = 0.0f;
    #pragma unroll
    for (int i = 0; i < 6; i++) s += w[i * 64 + lane] * f[i * 64 + lane];
    for (int o = 32; o >= 1; o >>= 1) s += __shfl_xor(s, o);
    if (lane == 0) gi[g * 768 + row] = s + bih[row];
}

// ---------------- GRU head, stage B ----------------
__global__ void __launch_bounds__(256) k_gru_fin(const float* __restrict__ gi,
        const float* __restrict__ bhh, const float* __restrict__ wfin,
        const float* __restrict__ bfin, const float* __restrict__ wroot,
        const float* __restrict__ broot, const float* __restrict__ rootv,
        const float* __restrict__ alphap, float* __restrict__ out) {
    int g = blockIdx.x, t = threadIdx.x;
    __shared__ float hg[256];
    {
        float r  = 1.0f / (1.0f + expf(-(gi[g * 768 + t]       + bhh[t])));
        float z  = 1.0f / (1.0f + expf(-(gi[g * 768 + 256 + t] + bhh[256 + t])));
        float nc = tanhf(gi[g * 768 + 512 + t] + r * bhh[512 + t]);
        hg[t] = (1.0f - z) * nc;
    }
    __syncthreads();
    float a = alphap[0];
    int wv = t >> 6, lane = t & 63;
    const float* rg = rootv + (size_t)g * 128;
    for (int oo = 0; oo < 32; oo++) {
        int o = wv * 32 + oo;
        const float* wf = wfin + (size_t)o * 256;
        float sf = wf[lane] * hg[lane] + wf[64 + lane] * hg[64 + lane]
                 + wf[128 + lane] * hg[128 + lane] + wf[192 + lane] * hg[192 + lane];
        const float* wr = wroot + (size_t)o * 128;
        float sr = wr[lane] * rg[lane] + wr[64 + lane] * rg[64 + lane];
        float s = a * sf + (1.0f - a) * sr;
        for (int sh = 32; sh >= 1; sh >>= 1) s += __shfl_xor(s, sh);
        if (lane == 0)
            out[g * 128 + o] = s + a * bfin[o] + (1.0f - a) * broot[o];
    }
}

extern "C" void kernel_launch(void* const* d_in, const int* in_sizes, int n_in,
                              void* d_out, int out_size, void* d_ws, size_t ws_size,
                              hipStream_t stream) {
    const float* x      = (const float*)d_in[0];
    const int*   ei     = (const int*)d_in[1];
    const float* rootv  = (const float*)d_in[3];
    const float* att_l  = (const float*)d_in[4];
    const float* att_r  = (const float*)d_in[5];
    const float* w_ih   = (const float*)d_in[6];
    const float* b_ih   = (const float*)d_in[8];
    const float* b_hh   = (const float*)d_in[9];
    const float* w_fin  = (const float*)d_in[10];
    const float* b_fin  = (const float*)d_in[11];
    const float* w_root = (const float*)d_in[12];
    const float* b_root = (const float*)d_in[13];
    const float* alphap = (const float*)d_in[14];
    float* out = (float*)d_out;

    char* wsb = (char*)d_ws;
    size_t off = 0;
    auto alloc = [&](size_t bytes) -> char* {
        char* p = wsb + off; off += (bytes + 255) & ~(size_t)255; return p;
    };
    ushort_t* xb   = (ushort_t*)alloc((size_t)131072 * C * 2);
    ushort_t* bufH = (ushort_t*)alloc((size_t)131072 * C * 2);
    ushort_t* bufC = (ushort_t*)alloc((size_t)65536  * C * 2);
    int*   srcA   = (int*)alloc((size_t)NEDGE * 4);
    int*   dstA   = (int*)alloc((size_t)NEDGE * 4);
    unsigned char* emask = (unsigned char*)alloc(NEDGE);
    int2*  edges  = (int2*)alloc((size_t)NEDGE * 8);
    ushort_t* lrank = (ushort_t*)alloc((size_t)NEDGE * 2);
    float* al     = (float*)alloc(131072 * 4);
    float* ar     = (float*)alloc(131072 * 4);
    float* dinv   = (float*)alloc(131072 * 4);
    float* selfco = (float*)alloc(131072 * 4);
    int*   degI   = (int*)alloc(131072 * 4);
    int*   score  = (int*)alloc(131072 * 4);
    int*   rowptr = (int*)alloc(131072 * 4);
    int*   bsum   = (int*)alloc(256 * 4);
    unsigned char* keep = (unsigned char*)alloc(131072);
    int*   nmap   = (int*)alloc(131072 * 4);
    int*   perm   = (int*)alloc(65536 * 4);
    int*   oidxA  = (int*)alloc(65536 * 4);
    int*   oidxB  = (int*)alloc(32768 * 4);
    float* pooled = (float*)alloc(G * 384 * 4);
    float* giBuf  = (float*)alloc(G * 768 * 4);
    int*   blockhist = (int*)alloc((size_t)G * 64 * SMAX * 4);
    int*   histT  = (int*)alloc((size_t)G * SMAX * 4);
    unsigned int* bh = (unsigned int*)alloc((size_t)128 * N0 * 4);
    float* pb = (float*)bh;   // pool partials alias bh (disjoint lifetimes within layer)

    k_hist0<<<128, 256, 0, stream>>>(ei, bh, lrank);
    k_sumdeg<<<131072 / 256, 256, 0, stream>>>(bh, degI, score, 14, 16, 131072, pooled);

    const int ns[3]   = {131072, 65536, 32768};
    const int npgs[3] = {16384, 8192, 4096};
    const int ks[3]   = {8192, 4096, 0};
    const int shifts[3] = {14, 13, 12};

    for (int l = 0; l < 3; l++) {
        int n = ns[l], npg = npgs[l], k = ks[l];
        const ushort_t* cur = (l == 0) ? xb : bufC;
        const int* oidx = (l == 0) ? nullptr : (l == 1 ? oidxA : oidxB);
        int* oidxN = (l == 0) ? oidxA : oidxB;
        const int* eS = (l == 0) ? ei : srcA;
        const int* eD = (l == 0) ? ei + NEDGE : dstA;
        const unsigned char* eM = (l == 0) ? nullptr : emask;
        int ebShift   = (l == 0) ? 13 : 12;   // edges per hist block
        int nsubShift = (l == 0) ? 4  : 5;    // hist blocks per graph
        int binShift  = shifts[l];            // bins per graph

        if (l == 0)
            k_alar<<<n / 4, 256, 0, stream>>>(x, att_l, att_r, al, ar, xb, n);

        int nblk = n / 2048;
        k_scan1<<<nblk, 256, 0, stream>>>(degI, rowptr, bsum);
        k_scan3s<<<n / 256, 256, 0, stream>>>(rowptr, bsum, degI, al, ar,
                                              dinv, selfco, keep, nmap, n);

        k_fill<<<NEDGE / 256, 256, 0, stream>>>(eS, eD, eM, dinv, al, ar,
                                                rowptr, bh, lrank, edges,
                                                ebShift, nsubShift, binShift);
        k_msg_csr<<<n / 8, 256, 0, stream>>>(rowptr, degI, edges, cur, xb, oidx,
                                             selfco, bufH, pb, npg);
        k_poolred<<<npg / 64, 256, 0, stream>>>(pb, pooled, l);

        if (l < 2) {
            int nb = npg / 256;
            k_hist<<<G * nb, 256, 0, stream>>>(score, npg, nb, blockhist);
            k_binprefix<<<G * 8, 256, 0, stream>>>(blockhist, histT, nb);
            k_rank<<<G * nb, 256, 0, stream>>>(score, blockhist, histT, npg, nb, k,
                                               keep, nmap, perm);
            int m = G * k;
            k_gather_alar<<<(m * 32 + 255) / 256, 256, 0, stream>>>(
                bufH, perm, oidx, att_l + (l + 1) * C, att_r + (l + 1) * C,
                bufC, oidxN, al, ar, m);
            k_remap_hist<<<256, 256, 0, stream>>>(eS, eD, eM, srcA, dstA, emask,
                                                  keep, nmap, bh, lrank, k);
            k_sumdeg<<<(G * k + 255) / 256, 256, 0, stream>>>(bh, degI, score,
                                                              shifts[l + 1], 32, G * k,
                                                              nullptr);
        }
    }

    k_gi<<<dim3(192, G), 256, 0, stream>>>(pooled, w_ih, b_ih, giBuf);
    k_gru_fin<<<G, 256, 0, stream>>>(giBuf, b_hh, w_fin, b_fin, w_root, b_root,
                                     rootv, alphap, out);
}

// Round 12
// 402.785 us; speedup vs baseline: 1.9325x; 1.0897x over previous
//
#include <hip/hip_runtime.h>
#include <math.h>

#define G 8
#define N0 16384
#define NEDGE (G*N0*8)      // 1048576
#define EPG (NEDGE/G)       // 131072 edges per graph
#define C 128
#define EPS_FA 0.1f
#define SMAX 2048

typedef unsigned short ushort_t;
typedef unsigned int uint_t;

__device__ inline ushort_t f2bf(float f) {
    uint_t u = __float_as_uint(f);
    uint_t r = (u + 0x7FFFu + ((u >> 16) & 1u)) >> 16;
    return (ushort_t)r;
}
__device__ inline uint_t pack2bf(float a, float b) {
    return (uint_t)f2bf(a) | ((uint_t)f2bf(b) << 16);
}
__device__ inline float bflo(uint_t w) { return __uint_as_float(w << 16); }
__device__ inline float bfhi(uint_t w) { return __uint_as_float(w & 0xFFFF0000u); }

// ---------------- layer-0 deg/score LDS histogram + edge local rank ----------------
__global__ void __launch_bounds__(256) k_hist0(const int* __restrict__ ei,
                                               unsigned int* __restrict__ bh,
                                               ushort_t* __restrict__ lrank) {
    __shared__ unsigned int h[N0];
    int t = threadIdx.x;
    for (int i = t; i < N0; i += 256) h[i] = 0;
    __syncthreads();
    int base = blockIdx.x * 8192;
    int gbase = (blockIdx.x >> 4) * N0;
    for (int i = t; i < 8192; i += 256) {
        int s = ei[base + i] - gbase;
        int d = ei[NEDGE + base + i] - gbase;
        unsigned int old = atomicAdd(&h[d], 1u);
        lrank[base + i] = (ushort_t)(old & 0xFFFFu);
        atomicAdd(&h[s], 0x10000u);
    }
    __syncthreads();
    unsigned int* o = bh + (size_t)blockIdx.x * N0;
    for (int i = t; i < N0; i += 256) o[i] = h[i];
}

// ---------------- fused: layer-0 sumdeg (blocks 0..511) + alar/bf16-convert --------
__global__ void __launch_bounds__(256) k_sumdeg_alar(
        unsigned int* __restrict__ bh, int* __restrict__ degI, int* __restrict__ score,
        float* __restrict__ pooled,
        const float* __restrict__ x, const float* __restrict__ attl,
        const float* __restrict__ attr, float* __restrict__ al, float* __restrict__ ar,
        ushort_t* __restrict__ xb) {
    int t = threadIdx.x;
    if ((int)blockIdx.x < 512) {
        int i = blockIdx.x * 256 + t;
        if (i < G * 384) pooled[i] = 0.0f;
        unsigned int* p = bh + ((size_t)((i >> 14) * 16) << 14) + (i & 16383);
        unsigned int run = 0; int as = 0;
        for (int b = 0; b < 16; b++) {
            unsigned int w = p[(size_t)b << 14];
            p[(size_t)b << 14] = run;
            run += w & 0xFFFFu; as += (int)(w >> 16);
        }
        degI[i] = (int)run; score[i] = as;
    } else {
        int idx = (blockIdx.x - 512) * 256 + t;
        int wid = idx >> 6, lane = idx & 63;
        float2 v  = ((const float2*)(x + (size_t)wid * C))[lane];
        ((uint_t*)(xb + (size_t)wid * C))[lane] = pack2bf(v.x, v.y);
        float2 l2 = ((const float2*)attl)[lane];
        float2 r2 = ((const float2*)attr)[lane];
        float sl = v.x * l2.x + v.y * l2.y;
        float sr = v.x * r2.x + v.y * r2.y;
        for (int o = 32; o >= 1; o >>= 1) { sl += __shfl_xor(sl, o); sr += __shfl_xor(sr, o); }
        if (lane == 0) { al[wid] = sl; ar[wid] = sr; }
    }
}

// ---------------- boundary sumdeg (standalone) ----------------
__global__ void k_sumdeg(unsigned int* __restrict__ bh, int* __restrict__ degI,
                         int* __restrict__ score, int shift, int nsub, int n) {
    int i = blockIdx.x * 256 + threadIdx.x;
    if (i >= n) return;
    int bins = 1 << shift;
    int g = i >> shift, u = i & (bins - 1);
    unsigned int* p = bh + ((size_t)(g * nsub) << shift) + u;
    unsigned int run = 0; int as = 0;
    for (int b = 0; b < nsub; b++) {
        unsigned int w = p[(size_t)b * bins];
        p[(size_t)b * bins] = run;
        run += w & 0xFFFFu; as += (int)(w >> 16);
    }
    degI[i] = (int)run; score[i] = as;
}

// ---------------- prefix scan ----------------
__global__ void __launch_bounds__(256) k_scan1(const int* __restrict__ degI,
                                               int* __restrict__ rowptr,
                                               int* __restrict__ bsum) {
    __shared__ int part[256];
    int t = threadIdx.x;
    int base = blockIdx.x * 2048 + t * 8;
    int v[8]; int s = 0;
    for (int i = 0; i < 8; i++) { v[i] = degI[base + i]; s += v[i]; }
    part[t] = s; __syncthreads();
    for (int o = 1; o < 256; o <<= 1) {
        int val = part[t];
        int add = (t >= o) ? part[t - o] : 0;
        __syncthreads();
        part[t] = val + add;
        __syncthreads();
    }
    int run = (t == 0) ? 0 : part[t - 1];
    if (t == 255) bsum[blockIdx.x] = part[255];
    for (int i = 0; i < 8; i++) { rowptr[base + i] = run; run += v[i]; }
}

__global__ void k_scan3s(int* __restrict__ rowptr,
                         const int* __restrict__ bsum, const int* __restrict__ degI,
                         const float* __restrict__ al, const float* __restrict__ ar,
                         float* __restrict__ dinv, float* __restrict__ selfco,
                         unsigned char* __restrict__ keep, int* __restrict__ nmap, int n) {
    __shared__ int base_s;
    int t = threadIdx.x;
    if (t < 64) {
        int c = blockIdx.x >> 3;
        int vv = (t < c) ? bsum[t] : 0;
        for (int o = 32; o >= 1; o >>= 1) vv += __shfl_xor(vv, o);
        if (t == 0) base_s = vv;
    }
    __syncthreads();
    int i = blockIdx.x * 256 + t;
    if (i >= n) return;
    rowptr[i] += base_s;
    float d  = (float)degI[i] + 1.0f;
    float di = rsqrtf(d);
    dinv[i]   = di;
    selfco[i] = di * di * tanhf(al[i] + ar[i]);
    keep[i] = 0; nmap[i] = 0;
}

// ---------------- fused: topk score hist (blocks < histBlocks) + CSR fill ---------
__global__ void __launch_bounds__(256) k_fill_hist(
        const int* __restrict__ src, const int* __restrict__ dst,
        const unsigned char* __restrict__ em,
        const float* __restrict__ dinv, const float* __restrict__ al,
        const float* __restrict__ ar,
        const int* __restrict__ rowptr, const unsigned int* __restrict__ bpre,
        const ushort_t* __restrict__ lrank, int2* __restrict__ edges,
        int ebShift, int nsubShift, int binShift,
        const int* __restrict__ score, int npg, int nb,
        int* __restrict__ blockhist, int histBlocks) {
    __shared__ int lh[SMAX];
    int t = threadIdx.x;
    if ((int)blockIdx.x < histBlocks) {
        int g = blockIdx.x / nb, b = blockIdx.x % nb;
        for (int s = t; s < SMAX; s += 256) lh[s] = 0;
        __syncthreads();
        int s = score[g * npg + b * 256 + t];
        if (s > SMAX - 1) s = SMAX - 1;
        atomicAdd(&lh[s], 1);
        __syncthreads();
        int* outp = blockhist + ((size_t)g * nb + b) * SMAX;
        for (int i = t; i < SMAX; i += 256) outp[i] = lh[i];
    } else {
        int fb = blockIdx.x - histBlocks;
        int gph = fb & 7, chunk = fb >> 3;
        int e = gph * EPG + chunk * 256 + t;
        if (em && !em[e]) return;
        int s = src[e], d = dst[e];
        float cf = dinv[s] * dinv[d] * tanhf(al[d] + ar[s]);
        int b = e >> ebShift;
        int gb = (b >> nsubShift) << binShift;
        int slot = rowptr[d] + (int)bpre[((size_t)b << binShift) + (d - gb)] + (int)lrank[e];
        edges[slot] = make_int2(s, __float_as_int(cf));
    }
}

// ---------------- fused: binprefix (blocks < bpBlocks) + CSR gather messages ------
#define ACC4(W, CF) { a0 += (CF) * bflo((W).x); a1 += (CF) * bfhi((W).x); \
                      a2 += (CF) * bflo((W).y); a3 += (CF) * bfhi((W).y); }
__global__ void __launch_bounds__(256) k_msg_bp(
        const int* __restrict__ rowptr, const int* __restrict__ degI,
        const int2* __restrict__ edges,
        const ushort_t* __restrict__ cur, const ushort_t* __restrict__ xb,
        const int* __restrict__ oidx, const float* __restrict__ selfco,
        ushort_t* __restrict__ h, float* __restrict__ pb, int npg,
        int* __restrict__ blockhist, int* __restrict__ histT, int nb, int bpBlocks) {
    __shared__ float pm[8 * 128];
    __shared__ int tile[4096];
    int t = threadIdx.x;
    if ((int)blockIdx.x < bpBlocks) {
        int g = blockIdx.x >> 5, ch = blockIdx.x & 31;
        int s0 = ch * 64;
        int* bg = blockhist + (size_t)g * nb * SMAX;
        int tot = nb * 64;
        for (int i = t; i < tot; i += 256)
            tile[i] = bg[(size_t)(i >> 6) * SMAX + s0 + (i & 63)];
        __syncthreads();
        if (t < 64) {
            int acc = 0;
            for (int b = 0; b < nb; b++) {
                int idx = b * 64 + t;
                int v = tile[idx]; tile[idx] = acc; acc += v;
            }
            histT[g * SMAX + s0 + t] = acc;
        }
        __syncthreads();
        for (int i = t; i < tot; i += 256)
            bg[(size_t)(i >> 6) * SMAX + s0 + (i & 63)] = tile[i];
        return;
    }
    int mb   = blockIdx.x - bpBlocks;
    int g    = mb & 7;
    int ib   = mb >> 3;
    int sub  = t >> 5;
    int lane = t & 31;
    int v = g * npg + ib * 8 + sub;
    int rs = rowptr[v], deg = degI[v];
    int o = oidx ? oidx[v] : v;
    uint2 cw = ((const uint2*)(cur + (size_t)v * C))[lane];
    uint2 xw = ((const uint2*)(xb  + (size_t)o * C))[lane];
    float sc = selfco[v];
    float a0 = 0.0f, a1 = 0.0f, a2 = 0.0f, a3 = 0.0f;
    for (int j0 = 0; j0 < deg; j0 += 32) {
        int cnt = deg - j0; if (cnt > 32) cnt = 32;
        int2 er = make_int2(0, 0);
        if (lane < cnt) er = edges[rs + j0 + lane];
        uint2 w0 = make_uint2(0,0), w1 = w0, w2 = w0, w3 = w0;
        {
            int s0 = __shfl(er.x, 0, 32);
            if (0 < cnt) w0 = ((const uint2*)(cur + (size_t)s0 * C))[lane];
            int s1 = __shfl(er.x, 1, 32);
            if (1 < cnt) w1 = ((const uint2*)(cur + (size_t)s1 * C))[lane];
            int s2 = __shfl(er.x, 2, 32);
            if (2 < cnt) w2 = ((const uint2*)(cur + (size_t)s2 * C))[lane];
            int s3 = __shfl(er.x, 3, 32);
            if (3 < cnt) w3 = ((const uint2*)(cur + (size_t)s3 * C))[lane];
        }
        int j = 0;
        for (; j + 4 <= cnt; j += 4) {
            float cf0 = __int_as_float(__shfl(er.y, j, 32));
            ACC4(w0, cf0);
            int sn0 = __shfl(er.x, j + 4, 32);
            if (j + 4 < cnt) w0 = ((const uint2*)(cur + (size_t)sn0 * C))[lane];
            float cf1 = __int_as_float(__shfl(er.y, j + 1, 32));
            ACC4(w1, cf1);
            int sn1 = __shfl(er.x, j + 5, 32);
            if (j + 5 < cnt) w1 = ((const uint2*)(cur + (size_t)sn1 * C))[lane];
            float cf2 = __int_as_float(__shfl(er.y, j + 2, 32));
            ACC4(w2, cf2);
            int sn2 = __shfl(er.x, j + 6, 32);
            if (j + 6 < cnt) w2 = ((const uint2*)(cur + (size_t)sn2 * C))[lane];
            float cf3 = __int_as_float(__shfl(er.y, j + 3, 32));
            ACC4(w3, cf3);
            int sn3 = __shfl(er.x, j + 7, 32);
            if (j + 7 < cnt) w3 = ((const uint2*)(cur + (size_t)sn3 * C))[lane];
        }
        if (j < cnt)     { float cf = __int_as_float(__shfl(er.y, j,     32)); ACC4(w0, cf); }
        if (j + 1 < cnt) { float cf = __int_as_float(__shfl(er.y, j + 1, 32)); ACC4(w1, cf); }
        if (j + 2 < cnt) { float cf = __int_as_float(__shfl(er.y, j + 2, 32)); ACC4(w2, cf); }
    }
    float r0 = fmaxf(a0 + sc * bflo(cw.x) + EPS_FA * bflo(xw.x), 0.0f);
    float r1 = fmaxf(a1 + sc * bfhi(cw.x) + EPS_FA * bfhi(xw.x), 0.0f);
    float r2 = fmaxf(a2 + sc * bflo(cw.y) + EPS_FA * bflo(xw.y), 0.0f);
    float r3 = fmaxf(a3 + sc * bfhi(cw.y) + EPS_FA * bfhi(xw.y), 0.0f);
    uint2 hw; hw.x = pack2bf(r0, r1); hw.y = pack2bf(r2, r3);
    ((uint2*)(h + (size_t)v * C))[lane] = hw;
    float4 rr = make_float4(r0, r1, r2, r3);
    ((float4*)(pm + sub * 128))[lane] = rr;
    __syncthreads();
    if (t < 128) {
        float m = pm[t];
        for (int s = 1; s < 8; s++) m = fmaxf(m, pm[s * 128 + t]);
        pb[(size_t)mb * 128 + t] = m;
    }
}

// ---------------- fused: rank (blocks < rankBlocks) + pool partial reduce ---------
__global__ void __launch_bounds__(256) k_pool_rank(
        const float* __restrict__ pb, float* __restrict__ pooled, int layer,
        const int* __restrict__ score, const int* __restrict__ blockhist,
        const int* __restrict__ hist, int npg, int nb, int k,
        unsigned char* __restrict__ keep, int* __restrict__ nmap,
        int* __restrict__ perm, int rankBlocks) {
    __shared__ int bp[SMAX];
    __shared__ int part[256];
    __shared__ int cs[256];
    __shared__ float sm[256];
    int t = threadIdx.x;
    if ((int)blockIdx.x < rankBlocks) {
        int g = blockIdx.x / nb, b = blockIdx.x % nb;
        const int* hg = hist + g * SMAX;
        int v[8]; int smv = 0;
        for (int i = 0; i < 8; i++) { v[i] = hg[SMAX - 1 - (t * 8 + i)]; smv += v[i]; }
        part[t] = smv; __syncthreads();
        for (int o = 1; o < 256; o <<= 1) {
            int val = part[t];
            int add = (t >= o) ? part[t - o] : 0;
            __syncthreads();
            part[t] = val + add;
            __syncthreads();
        }
        int run = (t == 0) ? 0 : part[t - 1];
        for (int i = 0; i < 8; i++) { bp[SMAX - 1 - (t * 8 + i)] = run; run += v[i]; }
        int vv = b * 256 + t;
        int s = score[g * npg + vv];
        if (s > SMAX - 1) s = SMAX - 1;
        cs[t] = s;
        __syncthreads();
        int cnt = 0;
        for (int u = 0; u < t; u++) cnt += (cs[u] == s);
        int pos = bp[s] + blockhist[((size_t)g * nb + b) * SMAX + s] + cnt;
        if (pos < k) {
            int vg = g * npg + vv;
            int nid = g * k + pos;
            keep[vg] = 1; nmap[vg] = nid; perm[nid] = vg;
        }
    } else {
        int pr = blockIdx.x - rankBlocks;
        int g = pr & 7, ch = pr >> 3;
        int c = t & 127, half = t >> 7;
        float m = 0.0f;
        for (int i = 0; i < 32; i++) {
            int r = ch * 64 + half * 32 + i;
            m = fmaxf(m, pb[(size_t)(g + 8 * r) * 128 + c]);
        }
        sm[t] = m;
        __syncthreads();
        if (t < 128) {
            float mm = fmaxf(sm[t], sm[t + 128]);
            atomicMax((unsigned int*)&pooled[g * 384 + layer * 128 + c], __float_as_uint(mm));
        }
    }
}

// ---------------- fused: remap+hist (blocks 0..255) + gather kept nodes -----------
__global__ void __launch_bounds__(256) k_gather_remap(
        const ushort_t* __restrict__ h, const int* __restrict__ perm,
        const int* __restrict__ oidx,
        const float* __restrict__ attlN, const float* __restrict__ attrN,
        ushort_t* __restrict__ curN, int* __restrict__ oidxN,
        float* __restrict__ al, float* __restrict__ ar, int m,
        const int* __restrict__ inS, const int* __restrict__ inD,
        const unsigned char* __restrict__ inEm,
        int* __restrict__ src, int* __restrict__ dst, unsigned char* __restrict__ em,
        const unsigned char* __restrict__ keep, const int* __restrict__ nmap,
        unsigned int* __restrict__ bh, ushort_t* __restrict__ lrank, int kN) {
    __shared__ unsigned int hh[8192];
    int t = threadIdx.x;
    if ((int)blockIdx.x < 256) {
        for (int i = t; i < kN; i += 256) hh[i] = 0;
        __syncthreads();
        int base = blockIdx.x * 4096;
        int gb = (blockIdx.x >> 5) * kN;
        for (int i = t; i < 4096; i += 256) {
            int e = base + i;
            int s = inS[e], d = inD[e];
            bool ok = (!inEm || inEm[e]) && keep[s] && keep[d];
            if (ok) {
                int ns = nmap[s], nd = nmap[d];
                src[e] = ns; dst[e] = nd; em[e] = 1;
                unsigned int old = atomicAdd(&hh[nd - gb], 1u);
                lrank[e] = (ushort_t)(old & 0xFFFFu);
                atomicAdd(&hh[ns - gb], 0x10000u);
            } else { src[e] = 0; dst[e] = 0; em[e] = 0; }
        }
        __syncthreads();
        unsigned int* o = bh + (size_t)blockIdx.x * kN;
        for (int i = t; i < kN; i += 256) o[i] = hh[i];
    } else {
        int i = (blockIdx.x - 256) * 256 + t;
        int j = i >> 5, c4 = i & 31;
        int p = perm[j];
        uint2 w = ((const uint2*)(h + (size_t)p * C))[c4];
        ((uint2*)(curN + (size_t)j * C))[c4] = w;
        float f0 = bflo(w.x), f1 = bfhi(w.x), f2 = bflo(w.y), f3 = bfhi(w.y);
        float4 l4 = ((const float4*)attlN)[c4];
        float4 r4 = ((const float4*)attrN)[c4];
        float sl = f0 * l4.x + f1 * l4.y + f2 * l4.z + f3 * l4.w;
        float sr = f0 * r4.x + f1 * r4.y + f2 * r4.z + f3 * r4.w;
        for (int o = 16; o >= 1; o >>= 1) { sl += __shfl_xor(sl, o); sr += __shfl_xor(sr, o); }
        if (c4 == 0) {
            al[j] = sl; ar[j] = sr;
            oidxN[j] = oidx ? oidx[p] : p;
        }
    }
}

// ---------------- GRU head, stage A ----------------
__global__ void __launch_bounds__(256) k_gi(const float* __restrict__ pooled,
                                            const float* __restrict__ wih,
                                            const float* __restrict__ bih,
                                            float* __restrict__ gi) {
    int g = blockIdx.y;
    int row = blockIdx.x * 4 + (threadIdx.x >> 6);
    int lane = threadIdx.x & 63;
    const float* w = wih + (size_t)row * 384;
    const float* f = pooled + g * 384;
    float s = 0.0f;
    #pragma unroll
    for (int i = 0; i < 6; i++) s += w[i * 64 + lane] * f[i * 64 + lane];
    for (int o = 32; o >= 1; o >>= 1) s += __shfl_xor(s, o);
    if (lane == 0) gi[g * 768 + row] = s + bih[row];
}

// ---------------- GRU head, stage B ----------------
__global__ void __launch_bounds__(256) k_gru_fin(const float* __restrict__ gi,
        const float* __restrict__ bhh, const float* __restrict__ wfin,
        const float* __restrict__ bfin, const float* __restrict__ wroot,
        const float* __restrict__ broot, const float* __restrict__ rootv,
        const float* __restrict__ alphap, float* __restrict__ out) {
    int g = blockIdx.x, t = threadIdx.x;
    __shared__ float hg[256];
    {
        float r  = 1.0f / (1.0f + expf(-(gi[g * 768 + t]       + bhh[t])));
        float z  = 1.0f / (1.0f + expf(-(gi[g * 768 + 256 + t] + bhh[256 + t])));
        float nc = tanhf(gi[g * 768 + 512 + t] + r * bhh[512 + t]);
        hg[t] = (1.0f - z) * nc;
    }
    __syncthreads();
    float a = alphap[0];
    int wv = t >> 6, lane = t & 63;
    const float* rg = rootv + (size_t)g * 128;
    for (int oo = 0; oo < 32; oo++) {
        int o = wv * 32 + oo;
        const float* wf = wfin + (size_t)o * 256;
        float sf = wf[lane] * hg[lane] + wf[64 + lane] * hg[64 + lane]
                 + wf[128 + lane] * hg[128 + lane] + wf[192 + lane] * hg[192 + lane];
        const float* wr = wroot + (size_t)o * 128;
        float sr = wr[lane] * rg[lane] + wr[64 + lane] * rg[64 + lane];
        float s = a * sf + (1.0f - a) * sr;
        for (int sh = 32; sh >= 1; sh >>= 1) s += __shfl_xor(s, sh);
        if (lane == 0)
            out[g * 128 + o] = s + a * bfin[o] + (1.0f - a) * broot[o];
    }
}

extern "C" void kernel_launch(void* const* d_in, const int* in_sizes, int n_in,
                              void* d_out, int out_size, void* d_ws, size_t ws_size,
                              hipStream_t stream) {
    const float* x      = (const float*)d_in[0];
    const int*   ei     = (const int*)d_in[1];
    const float* rootv  = (const float*)d_in[3];
    const float* att_l  = (const float*)d_in[4];
    const float* att_r  = (const float*)d_in[5];
    const float* w_ih   = (const float*)d_in[6];
    const float* b_ih   = (const float*)d_in[8];
    const float* b_hh   = (const float*)d_in[9];
    const float* w_fin  = (const float*)d_in[10];
    const float* b_fin  = (const float*)d_in[11];
    const float* w_root = (const float*)d_in[12];
    const float* b_root = (const float*)d_in[13];
    const float* alphap = (const float*)d_in[14];
    float* out = (float*)d_out;

    char* wsb = (char*)d_ws;
    size_t off = 0;
    auto alloc = [&](size_t bytes) -> char* {
        char* p = wsb + off; off += (bytes + 255) & ~(size_t)255; return p;
    };
    ushort_t* xb   = (ushort_t*)alloc((size_t)131072 * C * 2);
    ushort_t* bufH = (ushort_t*)alloc((size_t)131072 * C * 2);
    ushort_t* bufC = (ushort_t*)alloc((size_t)65536  * C * 2);
    int*   srcA   = (int*)alloc((size_t)NEDGE * 4);
    int*   dstA   = (int*)alloc((size_t)NEDGE * 4);
    unsigned char* emask = (unsigned char*)alloc(NEDGE);
    int2*  edges  = (int2*)alloc((size_t)NEDGE * 8);
    ushort_t* lrank = (ushort_t*)alloc((size_t)NEDGE * 2);
    float* al     = (float*)alloc(131072 * 4);
    float* ar     = (float*)alloc(131072 * 4);
    float* dinv   = (float*)alloc(131072 * 4);
    float* selfco = (float*)alloc(131072 * 4);
    int*   degI   = (int*)alloc(131072 * 4);
    int*   score  = (int*)alloc(131072 * 4);
    int*   rowptr = (int*)alloc(131072 * 4);
    int*   bsum   = (int*)alloc(256 * 4);
    unsigned char* keep = (unsigned char*)alloc(131072);
    int*   nmap   = (int*)alloc(131072 * 4);
    int*   perm   = (int*)alloc(65536 * 4);
    int*   oidxA  = (int*)alloc(65536 * 4);
    int*   oidxB  = (int*)alloc(32768 * 4);
    float* pooled = (float*)alloc(G * 384 * 4);
    float* giBuf  = (float*)alloc(G * 768 * 4);
    int*   blockhist = (int*)alloc((size_t)G * 64 * SMAX * 4);
    int*   histT  = (int*)alloc((size_t)G * SMAX * 4);
    unsigned int* bh = (unsigned int*)alloc((size_t)128 * N0 * 4);
    float* pb = (float*)bh;   // pool partials alias bh (disjoint lifetimes)

    k_hist0<<<128, 256, 0, stream>>>(ei, bh, lrank);
    k_sumdeg_alar<<<512 + 32768, 256, 0, stream>>>(bh, degI, score, pooled,
                                                   x, att_l, att_r, al, ar, xb);

    const int ns[3]   = {131072, 65536, 32768};
    const int npgs[3] = {16384, 8192, 4096};
    const int ks[3]   = {8192, 4096, 0};
    const int shifts[3] = {14, 13, 12};

    for (int l = 0; l < 3; l++) {
        int n = ns[l], npg = npgs[l], k = ks[l];
        const ushort_t* cur = (l == 0) ? xb : bufC;
        const int* oidx = (l == 0) ? nullptr : (l == 1 ? oidxA : oidxB);
        int* oidxN = (l == 0) ? oidxA : oidxB;
        const int* eS = (l == 0) ? ei : srcA;
        const int* eD = (l == 0) ? ei + NEDGE : dstA;
        const unsigned char* eM = (l == 0) ? nullptr : emask;
        int ebShift   = (l == 0) ? 13 : 12;
        int nsubShift = (l == 0) ? 4  : 5;
        int binShift  = shifts[l];
        int nb = npg / 256;

        k_scan1<<<n / 2048, 256, 0, stream>>>(degI, rowptr, bsum);
        k_scan3s<<<n / 256, 256, 0, stream>>>(rowptr, bsum, degI, al, ar,
                                              dinv, selfco, keep, nmap, n);

        int histBlocks = (l < 2) ? G * nb : 0;
        k_fill_hist<<<histBlocks + NEDGE / 256, 256, 0, stream>>>(
            eS, eD, eM, dinv, al, ar, rowptr, bh, lrank, edges,
            ebShift, nsubShift, binShift, score, npg, nb, blockhist, histBlocks);

        int bpBlocks = (l < 2) ? 256 : 0;
        k_msg_bp<<<bpBlocks + n / 8, 256, 0, stream>>>(
            rowptr, degI, edges, cur, xb, oidx, selfco, bufH, pb, npg,
            blockhist, histT, nb, bpBlocks);

        int rankBlocks = (l < 2) ? G * nb : 0;
        k_pool_rank<<<rankBlocks + npg / 64, 256, 0, stream>>>(
            pb, pooled, l, score, blockhist, histT, npg, nb, k,
            keep, nmap, perm, rankBlocks);

        if (l < 2) {
            int m = G * k;
            k_gather_remap<<<256 + m / 8, 256, 0, stream>>>(
                bufH, perm, oidx, att_l + (l + 1) * C, att_r + (l + 1) * C,
                bufC, oidxN, al, ar, m,
                eS, eD, eM, srcA, dstA, emask, keep, nmap, bh, lrank, k);
            k_sumdeg<<<(G * k + 255) / 256, 256, 0, stream>>>(bh, degI, score,
                                                              shifts[l + 1], 32, G * k);
        }
    }

    k_gi<<<dim3(192, G), 256, 0, stream>>>(pooled, w_ih, b_ih, giBuf);
    k_gru_fin<<<G, 256, 0, stream>>>(giBuf, b_hh, w_fin, b_fin, w_root, b_root,
                                     rootv, alphap, out);
}